// Round 5
// baseline (252.246 us; speedup 1.0000x reference)
//
#include <hip/hip_runtime.h>
#include <hip/hip_bf16.h>

// Problem constants (reference: B,T,C = 4,2048,1024; H=16; D=64)
#define Bdim 4
#define Tdim 2048
#define Cdim 1024
#define Hdim 16
#define Ddim 64
// D^-0.5 * log2(e) = 0.125 * 1.4426950408889634, folded into Q at QKV-GEMM
// epilogue so the attn softmax can use exp2 directly.
#define SCALE_Q 0.18033688011112042f

using f32x4  = __attribute__((ext_vector_type(4))) float;
using short8 = __attribute__((ext_vector_type(8))) short;   // 8 bf16 in 4 VGPRs

union U8 { uint4 v; unsigned short s[8]; };

__device__ __forceinline__ unsigned short f2bf(float f) {  // RNE
  union { float f; unsigned int i; } x; x.f = f;
  unsigned int lsb = (x.i >> 16) & 1u;
  unsigned int r = x.i + 0x7fffu + lsb;
  return (unsigned short)(r >> 16);
}

// 2x f32 -> packed 2x bf16 (RNE). Lowers to v_cvt_pk_bf16_f32 on gfx950.
__device__ __forceinline__ unsigned int pk_bf16(float lo, float hi) {
  union { __hip_bfloat162 h; unsigned int u; } c;
  c.h = __float22bfloat162_rn(make_float2(lo, hi));
  return c.u;
}

__device__ __forceinline__ float fexp2(float x) {
#if __has_builtin(__builtin_amdgcn_exp2f)
  return __builtin_amdgcn_exp2f(x);
#else
  return exp2f(x);
#endif
}

// async global->LDS, 16B per lane. LDS dest is wave-uniform base + lane*16
// (m104/m108): dest layout must be lane-linear. Global source is per-lane,
// so swizzled LDS layouts are achieved by pre-swizzling the global address.
__device__ __forceinline__ void glds16(const unsigned short* g, unsigned short* l) {
  __builtin_amdgcn_global_load_lds(
      (const __attribute__((address_space(1))) void*)g,
      (__attribute__((address_space(3))) void*)l,
      16, 0, 0);
}

__device__ __forceinline__ int detect_fmt(const unsigned int* xw) {
  int cnt = 0;
  for (int i = 0; i < 64; i++) {
    unsigned int e = (xw[i] >> 7) & 0xFFu;
    if (e >= 100u && e <= 140u) cnt++;
  }
  return (cnt >= 40) ? 1 : 0;   // 1 = bf16, 0 = fp32
}

// ---------------------------------------------------------------------------
// detect (kept for MONO / per-batch tiers)
// ---------------------------------------------------------------------------
__global__ void detect_kernel(const unsigned int* __restrict__ x, int* __restrict__ flag) {
  if (threadIdx.x == 0) *flag = detect_fmt(x);
}

// ---------------------------------------------------------------------------
// prep (R8): one launch = detect + cvt_x + cvtT(w_qkv) + cvtT(w_proj).
// ---------------------------------------------------------------------------
__global__ __launch_bounds__(256) void prep_kernel(
    const void* __restrict__ x, const void* __restrict__ wq, const void* __restrict__ wp,
    unsigned short* __restrict__ X16, unsigned short* __restrict__ WqT,
    unsigned short* __restrict__ WpT, int* __restrict__ flag)
{
  __shared__ __align__(16) unsigned short Ts[64][72];
  __shared__ int sfmt;
  if (threadIdx.x == 0) {
    const int f = detect_fmt((const unsigned int*)x);
    sfmt = f;
    if (blockIdx.x == 0) *flag = f;
  }
  __syncthreads();
  const int fmt = sfmt;
  const unsigned bid = blockIdx.x;
  const int tid = threadIdx.x;

  if (bid < 4096u) {                     // ---- cvt_x
    const size_t i = (size_t)bid * 256 + tid;     // < 1,048,576 groups of 8
    if (fmt == 1) {
      *(uint4*)(X16 + i * 8) = *(const uint4*)((const unsigned short*)x + i * 8);
    } else {
      const float* s = (const float*)x + i * 8;
      float4 a = *(const float4*)(s);
      float4 b = *(const float4*)(s + 4);
      U8 o;
      o.s[0]=f2bf(a.x); o.s[1]=f2bf(a.y); o.s[2]=f2bf(a.z); o.s[3]=f2bf(a.w);
      o.s[4]=f2bf(b.x); o.s[5]=f2bf(b.y); o.s[6]=f2bf(b.z); o.s[7]=f2bf(b.w);
      *(uint4*)(X16 + i * 8) = o.v;
    }
    return;
  }

  // ---- cvtT tiles
  const void* W; unsigned short* WT; int N, K, n0, k0;
  if (bid < 4864u) {
    const int t = bid - 4096;
    W = wq; WT = WqT; N = 3072; K = 1024;
    n0 = (t % 48) * 64; k0 = (t / 48) * 64;
  } else {
    const int t = bid - 4864;
    W = wp; WT = WpT; N = 1024; K = 1024;
    n0 = (t & 15) * 64; k0 = (t >> 4) * 64;
  }
  const int r = tid >> 2, c0 = (tid & 3) * 16;

  if (fmt == 0) {
    const float* Wf = (const float*)W + (size_t)(k0 + r) * N + n0 + c0;
    #pragma unroll
    for (int j4 = 0; j4 < 4; j4++) {
      float4 v = *(const float4*)(Wf + j4 * 4);
      Ts[r][c0 + j4*4 + 0] = f2bf(v.x);
      Ts[r][c0 + j4*4 + 1] = f2bf(v.y);
      Ts[r][c0 + j4*4 + 2] = f2bf(v.z);
      Ts[r][c0 + j4*4 + 3] = f2bf(v.w);
    }
  } else {
    const unsigned short* Wh = (const unsigned short*)W + (size_t)(k0 + r) * N + n0 + c0;
    uint4 v0 = *(const uint4*)(Wh);
    uint4 v1 = *(const uint4*)(Wh + 8);
    *(uint4*)&Ts[r][c0] = v0;
    *(uint4*)&Ts[r][c0 + 8] = v1;
  }
  __syncthreads();

  U8 o0, o1;
  #pragma unroll
  for (int j = 0; j < 8; j++) { o0.s[j] = Ts[c0 + j][r]; o1.s[j] = Ts[c0 + 8 + j][r]; }
  unsigned short* dst = WT + (size_t)(n0 + r) * K + k0 + c0;
  *(uint4*)(dst)     = o0.v;
  *(uint4*)(dst + 8) = o1.v;
}

// ---------------------------------------------------------------------------
// gemm128d (R12-proven): 128x128 tile, prefetch pipeline with raw s_barrier +
// counted vmcnt(4). XOR LDS swizzle (conflicts = 0). Unchanged.
// ---------------------------------------------------------------------------
__global__ __launch_bounds__(256) void gemm128d_kernel(
    const unsigned short* __restrict__ A16,
    const unsigned short* __restrict__ BT16,
    void* __restrict__ Cout,
    unsigned short* __restrict__ Qb,
    unsigned short* __restrict__ Kb,
    unsigned short* __restrict__ Vb,     // V dest: [t][d] (vT=0) or [d][t] (vT=1)
    const int* __restrict__ flag,
    int M, int N, int K, int mode, int vT)
{
  __shared__ __align__(16) unsigned short As[2][128 * 32];
  __shared__ __align__(16) unsigned short Bs[2][128 * 32];

  const int fmt = *flag;
  const int tid  = threadIdx.x;
  const int wave = tid >> 6;
  const int lane = tid & 63;
  const int col  = lane & 15;
  const int quad = lane >> 4;
  const int m0 = blockIdx.x * 128;
  const int n0 = blockIdx.y * 128;
  const int wm = (wave >> 1) * 64;
  const int wn = (wave & 1) * 64;

  const int r4 = lane >> 2;                                   // row in 16-group
  const int schunk = ((lane & 3) ^ ((lane >> 3) & 3)) * 8;    // pre-swizzled src chunk
  const int rsw = (quad ^ ((col >> 1) & 3)) * 8;              // frag-read swizzle

  f32x4 acc[4][4];
  #pragma unroll
  for (int i = 0; i < 4; i++)
    #pragma unroll
    for (int j = 0; j < 4; j++) acc[i][j] = (f32x4){0.f, 0.f, 0.f, 0.f};

  const unsigned short* ApA = A16  + (size_t)(m0 + wave * 32 + r4) * K + schunk;
  const unsigned short* ApB = ApA + (size_t)16 * K;
  const unsigned short* BpA = BT16 + (size_t)(n0 + wave * 32 + r4) * K + schunk;
  const unsigned short* BpB = BpA + (size_t)16 * K;

#define STAGE(BUF, KS) do { \
    glds16(ApA + (KS) * 32, &As[BUF][wave * 32 * 32]);        \
    glds16(ApB + (KS) * 32, &As[BUF][(wave * 32 + 16) * 32]); \
    glds16(BpA + (KS) * 32, &Bs[BUF][wave * 32 * 32]);        \
    glds16(BpB + (KS) * 32, &Bs[BUF][(wave * 32 + 16) * 32]); \
  } while (0)

#define COMPUTE(BUF) do { \
    short8 afr[4], bfr[4]; \
    _Pragma("unroll") \
    for (int mi = 0; mi < 4; mi++) \
      afr[mi] = *(const short8*)&As[BUF][(wm + mi * 16 + col) * 32 + rsw]; \
    _Pragma("unroll") \
    for (int ni = 0; ni < 4; ni++) \
      bfr[ni] = *(const short8*)&Bs[BUF][(wn + ni * 16 + col) * 32 + rsw]; \
    _Pragma("unroll") \
    for (int mi = 0; mi < 4; mi++) \
      _Pragma("unroll") \
      for (int ni = 0; ni < 4; ni++) \
        acc[mi][ni] = __builtin_amdgcn_mfma_f32_16x16x32_bf16(afr[mi], bfr[ni], acc[mi][ni], 0, 0, 0); \
  } while (0)

  const int NK = K >> 5;          // 32-k tiles (K=1024 -> 32)
  STAGE(0, 0);
  for (int ks = 0; ks < NK - 1; ++ks) {
    STAGE((ks + 1) & 1, ks + 1);                       // prefetch next tile
    asm volatile("s_waitcnt vmcnt(4)" ::: "memory");   // drain CURRENT tile only
    __builtin_amdgcn_s_barrier();
    __builtin_amdgcn_sched_barrier(0);
    COMPUTE(ks & 1);
    __builtin_amdgcn_sched_barrier(0);
    __builtin_amdgcn_s_barrier();                      // readers done before re-stage
  }
  asm volatile("s_waitcnt vmcnt(0)" ::: "memory");     // last tile: drain all
  __builtin_amdgcn_s_barrier();
  __builtin_amdgcn_sched_barrier(0);
  COMPUTE((NK - 1) & 1);
#undef STAGE
#undef COMPUTE

  if (mode == 1) {       // QKV scatter, hoisted per-subtile
    const int bb = m0 >> 11;          // batch (block never straddles)
    const int tBase = (m0 & 2047) + wm;
    #pragma unroll
    for (int ni = 0; ni < 4; ni++) {
      const int n = n0 + wn + ni * 16 + col;
      const int which = n >> 10;      // N=3072: 0=q 1=k 2=v
      const int rem = n & 1023;
      const int h = rem >> 6;
      const int d = rem & 63;
      if (which == 2 && vT) {
        // transposed V: [h][d][t], t = tBase+mi*16+quad*4+i contiguous -> 8B packed
        unsigned short* base = Vb + (size_t)(bb * Hdim + h) * Tdim * Ddim
                                  + (size_t)d * Tdim + tBase;
        #pragma unroll
        for (int mi = 0; mi < 4; mi++) {
          const int t0 = mi * 16 + quad * 4;
          *(uint2*)(base + t0) = make_uint2(pk_bf16(acc[mi][ni][0], acc[mi][ni][1]),
                                            pk_bf16(acc[mi][ni][2], acc[mi][ni][3]));
        }
      } else {
        unsigned short* dstBase = (which == 0) ? Qb : (which == 1 ? Kb : Vb);
        const float scale = (which == 0) ? SCALE_Q : 1.f;
        dstBase += (size_t)(bb * Hdim + h) * Tdim * Ddim + d;
        #pragma unroll
        for (int mi = 0; mi < 4; mi++)
          #pragma unroll
          for (int i = 0; i < 4; i++) {
            const int t = tBase + mi * 16 + quad * 4 + i;
            dstBase[(size_t)t * Ddim] = f2bf(acc[mi][ni][i] * scale);
          }
      }
    }
  } else {
    #pragma unroll
    for (int mi = 0; mi < 4; mi++)
      #pragma unroll
      for (int ni = 0; ni < 4; ni++)
        #pragma unroll
        for (int i = 0; i < 4; i++) {
          const int m = m0 + wm + mi * 16 + quad * 4 + i;
          const int n = n0 + wn + ni * 16 + col;
          const float v = acc[mi][ni][i];
          if (fmt == 0) ((float*)Cout)[(size_t)m * N + n] = v;
          else ((unsigned short*)Cout)[(size_t)m * N + n] = f2bf(v);
        }
  }
}

// ---------------------------------------------------------------------------
// gemm64 (R3-proven) — small-ws per-batch fallback only.
// ---------------------------------------------------------------------------
#define BM 64
#define BN 64
#define BK 32
#define LDK 40

__global__ __launch_bounds__(256) void gemm64_kernel(
    const void* __restrict__ A,
    const void* __restrict__ Bw,
    void* __restrict__ Cout,
    unsigned short* __restrict__ Qb,
    unsigned short* __restrict__ Kb,
    unsigned short* __restrict__ Vb,
    const int* __restrict__ flag,
    int M, int N, int K, int mode, int aFmt, int outFmt, int aOff, int mOff)
{
  __shared__ __align__(16) unsigned short As[BM * LDK];
  __shared__ __align__(16) unsigned short Bs[BN * LDK];

  const int fmt = *flag;
  const int af  = (aFmt  == 2) ? fmt : aFmt;
  const int of  = (outFmt == 2) ? fmt : outFmt;

  const int tid  = threadIdx.x;
  const int wave = tid >> 6;
  const int lane = tid & 63;
  const int m0 = blockIdx.x * BM;
  const int n0 = blockIdx.y * BN;

  const int ar = tid >> 2;
  const int ak = (tid & 3) * 8;
  const int bk = tid >> 3;
  const int bn = (tid & 7) * 8;

  const int lr = lane & 15;
  const int lq = lane >> 4;

  f32x4 acc[4] = {{0,0,0,0},{0,0,0,0},{0,0,0,0},{0,0,0,0}};

  for (int k0 = 0; k0 < K; k0 += BK) {
    U8 a8;
    if (af == 1) {
      a8.v = *(const uint4*)((const unsigned short*)A + (size_t)(aOff + m0 + ar) * K + (k0 + ak));
    } else {
      const float* Af = (const float*)A + (size_t)(aOff + m0 + ar) * K + (k0 + ak);
      float4 x0 = *(const float4*)(Af);
      float4 x1 = *(const float4*)(Af + 4);
      a8.s[0] = f2bf(x0.x); a8.s[1] = f2bf(x0.y); a8.s[2] = f2bf(x0.z); a8.s[3] = f2bf(x0.w);
      a8.s[4] = f2bf(x1.x); a8.s[5] = f2bf(x1.y); a8.s[6] = f2bf(x1.z); a8.s[7] = f2bf(x1.w);
    }
    *(uint4*)(&As[ar * LDK + ak]) = a8.v;

    U8 b8;
    if (fmt == 1) {
      b8.v = *(const uint4*)((const unsigned short*)Bw + (size_t)(k0 + bk) * N + (n0 + bn));
    } else {
      const float* Bf = (const float*)Bw + (size_t)(k0 + bk) * N + (n0 + bn);
      float4 x0 = *(const float4*)(Bf);
      float4 x1 = *(const float4*)(Bf + 4);
      b8.s[0] = f2bf(x0.x); b8.s[1] = f2bf(x0.y); b8.s[2] = f2bf(x0.z); b8.s[3] = f2bf(x0.w);
      b8.s[4] = f2bf(x1.x); b8.s[5] = f2bf(x1.y); b8.s[6] = f2bf(x1.z); b8.s[7] = f2bf(x1.w);
    }
    #pragma unroll
    for (int i = 0; i < 8; i++) Bs[(bn + i) * LDK + bk] = b8.s[i];
    __syncthreads();

    short8 afrag = *(const short8*)(&As[(wave * 16 + lr) * LDK + lq * 8]);
    #pragma unroll
    for (int c = 0; c < 4; c++) {
      short8 bfrag = *(const short8*)(&Bs[(c * 16 + lr) * LDK + lq * 8]);
      acc[c] = __builtin_amdgcn_mfma_f32_16x16x32_bf16(afrag, bfrag, acc[c], 0, 0, 0);
    }
    __syncthreads();
  }

  #pragma unroll
  for (int c = 0; c < 4; c++) {
    #pragma unroll
    for (int i = 0; i < 4; i++) {
      const int m = m0 + wave * 16 + lq * 4 + i;
      const int n = n0 + c * 16 + lr;
      const float v = acc[c][i];
      if (mode == 0) {
        if (of == 0) ((float*)Cout)[(size_t)(mOff + m) * N + n] = v;
        else ((unsigned short*)Cout)[(size_t)(mOff + m) * N + n] = f2bf(v);
      } else {
        const int which = n >> 10;
        const int rem = n & 1023;
        const int h = rem >> 6;
        const int d = rem & 63;
        const int b = m >> 11;
        const int t = m & 2047;
        const size_t idx = ((size_t)(b * Hdim + h) * Tdim + t) * Ddim + d;
        if      (which == 0) Qb[idx] = f2bf(v * SCALE_Q);
        else if (which == 1) Kb[idx] = f2bf(v);
        else                 Vb[idx] = f2bf(v);
      }
    }
  }
}

// ---------------------------------------------------------------------------
// attn128 (R13): FULL2 tier only (requires VbT [head][D][T]).
// vs R11/R12:
//  - s_setprio REMOVED (m190: null/negative on barrier-lockstep waves; attn
//    regressed 78->90 when it was added).
//  - K/V staged by glds16 (no VGPR round-trip, no ds_write), double-buffered
//    with counted vmcnt(4) + raw s_barrier (gemm128d-proven pattern).
//    Ledger: STAGE(kt+1)->buf^1, last reader = iter kt-1 COMPUTE, protected
//    by iter kt-1's trailing barrier. vmcnt exact: 4 glds16/wave/kt.
//  - All LDS tiles 64-short rows (unpadded) + XOR 16B-chunk swizzle
//    (phys = logical ^ (row&7)); K/V swizzle applied on the GLOBAL source
//    (dest lane-linear per m104), P applied on the per-lane store address.
//    Read side uses the same XOR. Old 72-pad layout was 8-way conflicted on
//    every frag ds_read_b128 (7.57M conflict cycles).
// ---------------------------------------------------------------------------
__global__ __launch_bounds__(256) void attn128_kernel(
    const unsigned short* __restrict__ Qb,
    const unsigned short* __restrict__ Kb,
    const unsigned short* __restrict__ VbT,   // [head][D][T], required
    unsigned short* __restrict__ Y)
{
  __shared__ __align__(16) unsigned short Ks[2][64 * 64];    // [key][d] swizzled
  __shared__ __align__(16) unsigned short Vt[2][64 * 64];    // [d][key] swizzled
  __shared__ __align__(16) unsigned short Pw[4][32 * 64];    // per-wave P [row][key] swizzled

  const int tid  = threadIdx.x;
  const int wave = tid >> 6;
  const int lane = tid & 63;
  const int col  = lane & 15;
  const int quad = lane >> 4;
  const int cx   = col & 7;
  const int ch0  = (quad ^ cx) * 8;    // physical shorts-offset of logical chunk 'quad'
  const int ch1  = ch0 ^ 32;           // logical chunk quad+4

  // staging lane geometry: one glds16 = 8 rows x 64 shorts; srow = row-in-call
  const int srow = lane >> 3;                       // 0..7
  const int sx   = ((lane & 7) ^ (srow & 7)) * 8;   // pre-swizzled source chunk

  const int pair = blockIdx.x & 7;
  const int bh   = blockIdx.x >> 3;
  const size_t headOff = (size_t)bh * Tdim * Ddim;
  const int b = bh >> 4;
  const int h = bh & 15;

  const short8 onesf = {16256, 16256, 16256, 16256, 16256, 16256, 16256, 16256}; // bf16 1.0 x8

#define ASTAGE(BUF, KB) do { \
    const unsigned short* Ksrc = Kb + headOff + (size_t)((KB) + wave * 16 + srow) * Ddim + sx; \
    glds16(Ksrc,            &Ks[BUF][(wave * 16) * 64]);      \
    glds16(Ksrc + 8 * Ddim, &Ks[BUF][(wave * 16 + 8) * 64]);  \
    const unsigned short* Vsrc = VbT + headOff + (size_t)(wave * 16 + srow) * Tdim + (KB) + sx; \
    glds16(Vsrc,            &Vt[BUF][(wave * 16) * 64]);      \
    glds16(Vsrc + 8 * Tdim, &Vt[BUF][(wave * 16 + 8) * 64]);  \
  } while (0)

  #pragma unroll
  for (int half = 0; half < 2; half++) {
    const int qt = half ? (15 - pair) : pair;
    const int qb = qt * 128;
    const int nkt = (qb >> 6) + 2;
    const int rMin = qb + wave * 32;
    const int rMax = rMin + 31;

    short8 qf[2][2];
    #pragma unroll
    for (int mi = 0; mi < 2; mi++) {
      const unsigned short* Qr = Qb + headOff + (size_t)(rMin + mi * 16 + col) * Ddim;
      qf[mi][0] = *(const short8*)(Qr + quad * 8);
      qf[mi][1] = *(const short8*)(Qr + 32 + quad * 8);
    }

    f32x4 o_acc[2][4];
    f32x4 l_acc[2];
    #pragma unroll
    for (int mi = 0; mi < 2; mi++) {
      l_acc[mi] = (f32x4){0.f, 0.f, 0.f, 0.f};
      #pragma unroll
      for (int n = 0; n < 4; n++) o_acc[mi][n] = (f32x4){0.f, 0.f, 0.f, 0.f};
    }

    ASTAGE(0, 0);
    for (int kt = 0; kt < nkt; kt++) {
      const int cur = kt & 1;
      if (kt + 1 < nkt) {
        ASTAGE(cur ^ 1, (kt + 1) * 64);                  // prefetch next tile
        asm volatile("s_waitcnt vmcnt(4)" ::: "memory"); // drain current tile only
      } else {
        asm volatile("s_waitcnt vmcnt(0)" ::: "memory"); // last tile: drain all
      }
      __builtin_amdgcn_s_barrier();
      __builtin_amdgcn_sched_barrier(0);

      const int ktb = kt * 64;
      if (ktb <= rMax) {
        // --- S^T = K @ Q^T : s_acc[c][mi], register idx = key, lane col = qrow
        f32x4 s_acc[4][2];
        #pragma unroll
        for (int c = 0; c < 4; c++) {
          const unsigned short* Kl = &Ks[cur][(c * 16 + col) * 64];
          short8 kf0 = *(const short8*)(Kl + ch0);
          short8 kf1 = *(const short8*)(Kl + ch1);
          #pragma unroll
          for (int mi = 0; mi < 2; mi++) {
            f32x4 z = {0.f, 0.f, 0.f, 0.f};
            z = __builtin_amdgcn_mfma_f32_16x16x32_bf16(kf0, qf[mi][0], z, 0, 0, 0);
            s_acc[c][mi] = __builtin_amdgcn_mfma_f32_16x16x32_bf16(kf1, qf[mi][1], z, 0, 0, 0);
          }
        }

        // causal mask: key > qrow -> -inf  (key = ktb+c*16+quad*4+i, qrow = rMin+mi*16+col)
        if (ktb + 63 > rMin) {
          #pragma unroll
          for (int c = 0; c < 4; c++)
            #pragma unroll
            for (int mi = 0; mi < 2; mi++)
              #pragma unroll
              for (int i = 0; i < 4; i++)
                if (ktb + c * 16 + quad * 4 + i > rMin + mi * 16 + col)
                  s_acc[c][mi][i] = -1e30f;
        }

        // --- softmax (exp2 domain) + packed b64 P stores (swizzled [row][key])
        #pragma unroll
        for (int mi = 0; mi < 2; mi++)
          #pragma unroll
          for (int c = 0; c < 4; c++) {
            const float p0 = fexp2(fminf(s_acc[c][mi][0], 80.f));
            const float p1 = fexp2(fminf(s_acc[c][mi][1], 80.f));
            const float p2 = fexp2(fminf(s_acc[c][mi][2], 80.f));
            const float p3 = fexp2(fminf(s_acc[c][mi][3], 80.f));
            const unsigned int u0 = pk_bf16(p0, p1);
            const unsigned int u1 = pk_bf16(p2, p3);
            // logical 16B-chunk (2c + quad>>1), physical = logical ^ cx; 8B half = quad&1
            const int po = (((c * 2 + (quad >> 1)) ^ cx) * 8) + (quad & 1) * 4;
            *(uint2*)&Pw[wave][(mi * 16 + col) * 64 + po] = make_uint2(u0, u1);
          }

        short8 pf[2][2];
        #pragma unroll
        for (int mi = 0; mi < 2; mi++) {
          pf[mi][0] = *(const short8*)(&Pw[wave][(mi * 16 + col) * 64 + ch0]);
          pf[mi][1] = *(const short8*)(&Pw[wave][(mi * 16 + col) * 64 + ch1]);
          // row-sum via ones-MFMA: lands in o_acc-compatible C layout
          l_acc[mi] = __builtin_amdgcn_mfma_f32_16x16x32_bf16(pf[mi][0], onesf, l_acc[mi], 0, 0, 0);
          l_acc[mi] = __builtin_amdgcn_mfma_f32_16x16x32_bf16(pf[mi][1], onesf, l_acc[mi], 0, 0, 0);
        }
        #pragma unroll
        for (int n = 0; n < 4; n++) {
          const unsigned short* Vl = &Vt[cur][(n * 16 + col) * 64];
          short8 vf0 = *(const short8*)(Vl + ch0);
          short8 vf1 = *(const short8*)(Vl + ch1);
          #pragma unroll
          for (int mi = 0; mi < 2; mi++) {
            o_acc[mi][n] = __builtin_amdgcn_mfma_f32_16x16x32_bf16(pf[mi][0], vf0, o_acc[mi][n], 0, 0, 0);
            o_acc[mi][n] = __builtin_amdgcn_mfma_f32_16x16x32_bf16(pf[mi][1], vf1, o_acc[mi][n], 0, 0, 0);
          }
        }
      }
      __builtin_amdgcn_sched_barrier(0);
      __builtin_amdgcn_s_barrier();     // readers done before next STAGE overwrites
    }

    #pragma unroll
    for (int mi = 0; mi < 2; mi++)
      #pragma unroll
      for (int i = 0; i < 4; i++) {
        const float inv = 1.f / l_acc[mi][i];
        const int qrow = rMin + mi * 16 + quad * 4 + i;
        unsigned short* dst = Y + (size_t)(b * Tdim + qrow) * Cdim + h * Ddim;
        #pragma unroll
        for (int n = 0; n < 4; n++)
          dst[n * 16 + col] = f2bf(o_acc[mi][n][i] * inv);
      }
  }
#undef ASTAGE
}

// ---------------------------------------------------------------------------
// attn128_legacy (R10-proven): used by fallback tiers (no VbT workspace).
// ---------------------------------------------------------------------------
__global__ __launch_bounds__(256) void attn128_legacy_kernel(
    const unsigned short* __restrict__ Qb,
    const unsigned short* __restrict__ Kb,
    const unsigned short* __restrict__ Vb,
    const unsigned short* __restrict__ VbT,   // [head][D][T] or nullptr
    unsigned short* __restrict__ Y)
{
  __shared__ __align__(16) unsigned short Ks[64 * 72];       // [key][d]
  __shared__ __align__(16) unsigned short Vt[64 * 72];       // [d][key]
  __shared__ __align__(16) unsigned short Pw[4][32 * 72];    // per-wave P [row][key]

  const int tid  = threadIdx.x;
  const int wave = tid >> 6;
  const int lane = tid & 63;
  const int col  = lane & 15;
  const int quad = lane >> 4;

  const int pair = blockIdx.x & 7;
  const int bh   = blockIdx.x >> 3;
  const size_t headOff = (size_t)bh * Tdim * Ddim;

  const int sr = tid >> 2;
  const int sc = (tid & 3) * 16;

  const int b = bh >> 4;
  const int h = bh & 15;

  const short8 onesf = {16256, 16256, 16256, 16256, 16256, 16256, 16256, 16256};

  #pragma unroll
  for (int half = 0; half < 2; half++) {
    const int qt = half ? (15 - pair) : pair;
    const int qb = qt * 128;
    const int nkt = (qb >> 6) + 2;
    const int rMin = qb + wave * 32;
    const int rMax = rMin + 31;

    short8 qf[2][2];
    #pragma unroll
    for (int mi = 0; mi < 2; mi++) {
      const unsigned short* Qr = Qb + headOff + (size_t)(rMin + mi * 16 + col) * Ddim;
      qf[mi][0] = *(const short8*)(Qr + quad * 8);
      qf[mi][1] = *(const short8*)(Qr + 32 + quad * 8);
    }

    f32x4 o_acc[2][4];
    f32x4 l_acc[2];
    #pragma unroll
    for (int mi = 0; mi < 2; mi++) {
      l_acc[mi] = (f32x4){0.f, 0.f, 0.f, 0.f};
      #pragma unroll
      for (int n = 0; n < 4; n++) o_acc[mi][n] = (f32x4){0.f, 0.f, 0.f, 0.f};
    }

    uint4 kr0, kr1, vr0, vr1;
    {
      const unsigned short* Kr = Kb + headOff + (size_t)sr * Ddim + sc;
      kr0 = *(const uint4*)(Kr);
      kr1 = *(const uint4*)(Kr + 8);
      if (VbT) {
        const unsigned short* Vr = VbT + headOff + (size_t)sr * Tdim + sc;
        vr0 = *(const uint4*)(Vr);
        vr1 = *(const uint4*)(Vr + 8);
      } else {
        const unsigned short* Vr = Vb + headOff + (size_t)sr * Ddim + sc;
        vr0 = *(const uint4*)(Vr);
        vr1 = *(const uint4*)(Vr + 8);
      }
    }

    for (int kt = 0; kt < nkt; kt++) {
      __syncthreads();
      *(uint4*)&Ks[sr * 72 + sc]     = kr0;
      *(uint4*)&Ks[sr * 72 + sc + 8] = kr1;
      if (VbT) {
        *(uint4*)&Vt[sr * 72 + sc]     = vr0;
        *(uint4*)&Vt[sr * 72 + sc + 8] = vr1;
      } else {
        U8 v0, v1; v0.v = vr0; v1.v = vr1;
        #pragma unroll
        for (int j = 0; j < 8; j++) {
          Vt[(sc + j) * 72 + sr]     = v0.s[j];
          Vt[(sc + 8 + j) * 72 + sr] = v1.s[j];
        }
      }
      __syncthreads();

      if (kt + 1 < nkt) {
        const int kb = (kt + 1) * 64;
        const unsigned short* Kr = Kb + headOff + (size_t)(kb + sr) * Ddim + sc;
        kr0 = *(const uint4*)(Kr);
        kr1 = *(const uint4*)(Kr + 8);
        if (VbT) {
          const unsigned short* Vr = VbT + headOff + (size_t)sr * Tdim + kb + sc;
          vr0 = *(const uint4*)(Vr);
          vr1 = *(const uint4*)(Vr + 8);
        } else {
          const unsigned short* Vr = Vb + headOff + (size_t)(kb + sr) * Ddim + sc;
          vr0 = *(const uint4*)(Vr);
          vr1 = *(const uint4*)(Vr + 8);
        }
      }

      const int ktb = kt * 64;
      if (ktb <= rMax) {
        f32x4 s_acc[4][2];
        #pragma unroll
        for (int c = 0; c < 4; c++) {
          const unsigned short* Kl = &Ks[(c * 16 + col) * 72];
          short8 kf0 = *(const short8*)(Kl + quad * 8);
          short8 kf1 = *(const short8*)(Kl + 32 + quad * 8);
          #pragma unroll
          for (int mi = 0; mi < 2; mi++) {
            f32x4 z = {0.f, 0.f, 0.f, 0.f};
            z = __builtin_amdgcn_mfma_f32_16x16x32_bf16(kf0, qf[mi][0], z, 0, 0, 0);
            s_acc[c][mi] = __builtin_amdgcn_mfma_f32_16x16x32_bf16(kf1, qf[mi][1], z, 0, 0, 0);
          }
        }

        if (ktb + 63 > rMin) {
          #pragma unroll
          for (int c = 0; c < 4; c++)
            #pragma unroll
            for (int mi = 0; mi < 2; mi++)
              #pragma unroll
              for (int i = 0; i < 4; i++)
                if (ktb + c * 16 + quad * 4 + i > rMin + mi * 16 + col)
                  s_acc[c][mi][i] = -1e30f;
        }

        #pragma unroll
        for (int mi = 0; mi < 2; mi++)
          #pragma unroll
          for (int c = 0; c < 4; c++) {
            const float p0 = fexp2(fminf(s_acc[c][mi][0], 80.f));
            const float p1 = fexp2(fminf(s_acc[c][mi][1], 80.f));
            const float p2 = fexp2(fminf(s_acc[c][mi][2], 80.f));
            const float p3 = fexp2(fminf(s_acc[c][mi][3], 80.f));
            const unsigned int u0 = pk_bf16(p0, p1);
            const unsigned int u1 = pk_bf16(p2, p3);
            uint2* dst = (uint2*)&Pw[wave][(mi * 16 + col) * 72 + c * 16 + quad * 4];
            *dst = make_uint2(u0, u1);
          }

        short8 pf[2][2];
        #pragma unroll
        for (int mi = 0; mi < 2; mi++) {
          pf[mi][0] = *(const short8*)(&Pw[wave][(mi * 16 + col) * 72 + quad * 8]);
          pf[mi][1] = *(const short8*)(&Pw[wave][(mi * 16 + col) * 72 + 32 + quad * 8]);
          l_acc[mi] = __builtin_amdgcn_mfma_f32_16x16x32_bf16(pf[mi][0], onesf, l_acc[mi], 0, 0, 0);
          l_acc[mi] = __builtin_amdgcn_mfma_f32_16x16x32_bf16(pf[mi][1], onesf, l_acc[mi], 0, 0, 0);
        }
        #pragma unroll
        for (int n = 0; n < 4; n++) {
          const unsigned short* Vl = &Vt[(n * 16 + col) * 72];
          short8 vf0 = *(const short8*)(Vl + quad * 8);
          short8 vf1 = *(const short8*)(Vl + 32 + quad * 8);
          #pragma unroll
          for (int mi = 0; mi < 2; mi++) {
            o_acc[mi][n] = __builtin_amdgcn_mfma_f32_16x16x32_bf16(pf[mi][0], vf0, o_acc[mi][n], 0, 0, 0);
            o_acc[mi][n] = __builtin_amdgcn_mfma_f32_16x16x32_bf16(pf[mi][1], vf1, o_acc[mi][n], 0, 0, 0);
          }
        }
      }
    }

    #pragma unroll
    for (int mi = 0; mi < 2; mi++)
      #pragma unroll
      for (int i = 0; i < 4; i++) {
        const float inv = 1.f / l_acc[mi][i];
        const int qrow = rMin + mi * 16 + quad * 4 + i;
        unsigned short* dst = Y + (size_t)(b * Tdim + qrow) * Cdim + h * Ddim;
        #pragma unroll
        for (int n = 0; n < 4; n++)
          dst[n * 16 + col] = f2bf(o_acc[mi][n][i] * inv);
      }
  }
}

// ---------------------------------------------------------------------------
// launch. ws layout unchanged.
// FULL2 tier: prep -> gemm128d(qkv, V->VbT transposed) -> attn128 -> gemm128d.
// ---------------------------------------------------------------------------
extern "C" void kernel_launch(void* const* d_in, const int* in_sizes, int n_in,
                              void* d_out, int out_size, void* d_ws, size_t ws_size,
                              hipStream_t stream) {
  const void* x      = d_in[0];
  const void* w_qkv  = d_in[1];
  const void* w_proj = d_in[2];

  int* flag = (int*)d_ws;
  unsigned short* wsb = (unsigned short*)((char*)d_ws + 1024);

  const size_t HS = (size_t)Bdim * Hdim * Tdim * Ddim;   // 8,388,608 elems
  const size_t FULL  = 1024 + 2 * (4 * HS + (size_t)3072 * 1024 + (size_t)1024 * 1024);
  const size_t FULL2 = FULL + 2 * HS;
  const size_t MONO  = 1024 + 2 * (4 * HS);

  dim3 blk(256);

  if (ws_size >= FULL) {
    unsigned short* Qb  = wsb;
    unsigned short* Kb  = Qb + HS;
    unsigned short* Vb  = Kb + HS;
    unsigned short* XY  = Vb + HS;            // X16 then Y2 (bf16 [B*T, C])
    unsigned short* WqT = XY + HS;
    unsigned short* WpT = WqT + (size_t)3072 * 1024;
    unsigned short* VbT = WpT + (size_t)1024 * 1024;
    const int M = Bdim * Tdim;                // 8192

    prep_kernel<<<dim3(5120), blk, 0, stream>>>(x, w_qkv, w_proj, XY, WqT, WpT, flag);

    if (ws_size >= FULL2) {
      // V written directly transposed into VbT by the GEMM epilogue
      gemm128d_kernel<<<dim3(M / 128, 3072 / 128), blk, 0, stream>>>(
          XY, WqT, nullptr, Qb, Kb, VbT, flag, M, 3072, Cdim, 1, 1);
      attn128_kernel<<<dim3(Bdim * Hdim * 8), blk, 0, stream>>>(Qb, Kb, VbT, XY);
    } else {
      gemm128d_kernel<<<dim3(M / 128, 3072 / 128), blk, 0, stream>>>(
          XY, WqT, nullptr, Qb, Kb, Vb, flag, M, 3072, Cdim, 1, 0);
      attn128_legacy_kernel<<<dim3(Bdim * Hdim * 8), blk, 0, stream>>>(Qb, Kb, Vb, nullptr, XY);
    }

    gemm128d_kernel<<<dim3(M / 128, Cdim / 128), blk, 0, stream>>>(
        XY, WpT, d_out, nullptr, nullptr, nullptr, flag, M, Cdim, Cdim, 0, 0);
  } else if (ws_size >= MONO) {
    // MONO: R3-proven per-batch flow (gemm64 converts A inline).
    detect_kernel<<<1, 64, 0, stream>>>((const unsigned int*)x, flag);
    const size_t HSb = (size_t)Hdim * Tdim * Ddim;
    unsigned short* Qb2 = wsb;
    unsigned short* Kb2 = Qb2 + HSb;
    unsigned short* Vb2 = Kb2 + HSb;
    unsigned short* Y2  = Vb2 + HSb;
    for (int b = 0; b < Bdim; b++) {
      gemm64_kernel<<<dim3(Tdim / BM, 3072 / BN), blk, 0, stream>>>(
          x, w_qkv, nullptr, Qb2, Kb2, Vb2, flag,
          Tdim, 3072, Cdim, 1, 2, 2, b * Tdim, 0);
      attn128_legacy_kernel<<<dim3(Hdim * 8), blk, 0, stream>>>(Qb2, Kb2, Vb2, nullptr, Y2);
      gemm64_kernel<<<dim3(Tdim / BM, Cdim / BN), blk, 0, stream>>>(
          Y2, w_proj, d_out, nullptr, nullptr, nullptr, flag,
          Tdim, Cdim, Cdim, 0, 1, 2, 0, b * Tdim);
    }
  } else {   // per-batch fallback (16 MiB + 1 KiB), R3-proven
    detect_kernel<<<1, 64, 0, stream>>>((const unsigned int*)x, flag);
    const size_t HSb = (size_t)Hdim * Tdim * Ddim;
    unsigned short* Qb = wsb;
    unsigned short* Kb = Qb + HSb;
    unsigned short* Vb = Kb + HSb;
    unsigned short* Y2 = Vb + HSb;

    for (int b = 0; b < Bdim; b++) {
      gemm64_kernel<<<dim3(Tdim / BM, 3072 / BN), blk, 0, stream>>>(
          x, w_qkv, nullptr, Qb, Kb, Vb, flag,
          Tdim, 3072, Cdim, 1, 2, 2, b * Tdim, 0);

      attn128_legacy_kernel<<<dim3(Hdim * 8), blk, 0, stream>>>(Qb, Kb, Vb, nullptr, Y2);

      gemm64_kernel<<<dim3(Tdim / BM, Cdim / BN), blk, 0, stream>>>(
          Y2, w_proj, d_out, nullptr, nullptr, nullptr, flag,
          Tdim, Cdim, Cdim, 0, 1, 2, 0, b * Tdim);
    }
  }
}

// Round 6
// 250.014 us; speedup vs baseline: 1.0089x; 1.0089x over previous
//
#include <hip/hip_runtime.h>
#include <hip/hip_bf16.h>

// Problem constants (reference: B,T,C = 4,2048,1024; H=16; D=64)
#define Bdim 4
#define Tdim 2048
#define Cdim 1024
#define Hdim 16
#define Ddim 64
// D^-0.5 * log2(e) = 0.125 * 1.4426950408889634, folded into Q at QKV-GEMM
// epilogue so the attn softmax can use exp2 directly.
#define SCALE_Q 0.18033688011112042f

using f32x4  = __attribute__((ext_vector_type(4))) float;
using short8 = __attribute__((ext_vector_type(8))) short;   // 8 bf16 in 4 VGPRs

union U8 { uint4 v; unsigned short s[8]; };

__device__ __forceinline__ unsigned short f2bf(float f) {  // RNE
  union { float f; unsigned int i; } x; x.f = f;
  unsigned int lsb = (x.i >> 16) & 1u;
  unsigned int r = x.i + 0x7fffu + lsb;
  return (unsigned short)(r >> 16);
}

// 2x f32 -> packed 2x bf16 (RNE). Lowers to v_cvt_pk_bf16_f32 on gfx950.
__device__ __forceinline__ unsigned int pk_bf16(float lo, float hi) {
  union { __hip_bfloat162 h; unsigned int u; } c;
  c.h = __float22bfloat162_rn(make_float2(lo, hi));
  return c.u;
}

__device__ __forceinline__ float fexp2(float x) {
#if __has_builtin(__builtin_amdgcn_exp2f)
  return __builtin_amdgcn_exp2f(x);
#else
  return exp2f(x);
#endif
}

// async global->LDS, 16B per lane. LDS dest is wave-uniform base + lane*16
// (m104/m108): dest layout must be lane-linear. Global source is per-lane,
// so swizzled LDS layouts are achieved by pre-swizzling the global address.
__device__ __forceinline__ void glds16(const unsigned short* g, unsigned short* l) {
  __builtin_amdgcn_global_load_lds(
      (const __attribute__((address_space(1))) void*)g,
      (__attribute__((address_space(3))) void*)l,
      16, 0, 0);
}

__device__ __forceinline__ int detect_fmt(const unsigned int* xw) {
  int cnt = 0;
  for (int i = 0; i < 64; i++) {
    unsigned int e = (xw[i] >> 7) & 0xFFu;
    if (e >= 100u && e <= 140u) cnt++;
  }
  return (cnt >= 40) ? 1 : 0;   // 1 = bf16, 0 = fp32
}

// ---------------------------------------------------------------------------
// detect (kept for MONO / per-batch tiers)
// ---------------------------------------------------------------------------
__global__ void detect_kernel(const unsigned int* __restrict__ x, int* __restrict__ flag) {
  if (threadIdx.x == 0) *flag = detect_fmt(x);
}

// ---------------------------------------------------------------------------
// prep (R8): one launch = detect + cvt_x + cvtT(w_qkv) + cvtT(w_proj).
// ---------------------------------------------------------------------------
__global__ __launch_bounds__(256) void prep_kernel(
    const void* __restrict__ x, const void* __restrict__ wq, const void* __restrict__ wp,
    unsigned short* __restrict__ X16, unsigned short* __restrict__ WqT,
    unsigned short* __restrict__ WpT, int* __restrict__ flag)
{
  __shared__ __align__(16) unsigned short Ts[64][72];
  __shared__ int sfmt;
  if (threadIdx.x == 0) {
    const int f = detect_fmt((const unsigned int*)x);
    sfmt = f;
    if (blockIdx.x == 0) *flag = f;
  }
  __syncthreads();
  const int fmt = sfmt;
  const unsigned bid = blockIdx.x;
  const int tid = threadIdx.x;

  if (bid < 4096u) {                     // ---- cvt_x
    const size_t i = (size_t)bid * 256 + tid;     // < 1,048,576 groups of 8
    if (fmt == 1) {
      *(uint4*)(X16 + i * 8) = *(const uint4*)((const unsigned short*)x + i * 8);
    } else {
      const float* s = (const float*)x + i * 8;
      float4 a = *(const float4*)(s);
      float4 b = *(const float4*)(s + 4);
      U8 o;
      o.s[0]=f2bf(a.x); o.s[1]=f2bf(a.y); o.s[2]=f2bf(a.z); o.s[3]=f2bf(a.w);
      o.s[4]=f2bf(b.x); o.s[5]=f2bf(b.y); o.s[6]=f2bf(b.z); o.s[7]=f2bf(b.w);
      *(uint4*)(X16 + i * 8) = o.v;
    }
    return;
  }

  // ---- cvtT tiles
  const void* W; unsigned short* WT; int N, K, n0, k0;
  if (bid < 4864u) {
    const int t = bid - 4096;
    W = wq; WT = WqT; N = 3072; K = 1024;
    n0 = (t % 48) * 64; k0 = (t / 48) * 64;
  } else {
    const int t = bid - 4864;
    W = wp; WT = WpT; N = 1024; K = 1024;
    n0 = (t & 15) * 64; k0 = (t >> 4) * 64;
  }
  const int r = tid >> 2, c0 = (tid & 3) * 16;

  if (fmt == 0) {
    const float* Wf = (const float*)W + (size_t)(k0 + r) * N + n0 + c0;
    #pragma unroll
    for (int j4 = 0; j4 < 4; j4++) {
      float4 v = *(const float4*)(Wf + j4 * 4);
      Ts[r][c0 + j4*4 + 0] = f2bf(v.x);
      Ts[r][c0 + j4*4 + 1] = f2bf(v.y);
      Ts[r][c0 + j4*4 + 2] = f2bf(v.z);
      Ts[r][c0 + j4*4 + 3] = f2bf(v.w);
    }
  } else {
    const unsigned short* Wh = (const unsigned short*)W + (size_t)(k0 + r) * N + n0 + c0;
    uint4 v0 = *(const uint4*)(Wh);
    uint4 v1 = *(const uint4*)(Wh + 8);
    *(uint4*)&Ts[r][c0] = v0;
    *(uint4*)&Ts[r][c0 + 8] = v1;
  }
  __syncthreads();

  U8 o0, o1;
  #pragma unroll
  for (int j = 0; j < 8; j++) { o0.s[j] = Ts[c0 + j][r]; o1.s[j] = Ts[c0 + 8 + j][r]; }
  unsigned short* dst = WT + (size_t)(n0 + r) * K + k0 + c0;
  *(uint4*)(dst)     = o0.v;
  *(uint4*)(dst + 8) = o1.v;
}

// ---------------------------------------------------------------------------
// gemm128d (R12-proven): 128x128 tile, prefetch pipeline with raw s_barrier +
// counted vmcnt(4). XOR LDS swizzle (conflicts = 0). Unchanged.
// ---------------------------------------------------------------------------
__global__ __launch_bounds__(256) void gemm128d_kernel(
    const unsigned short* __restrict__ A16,
    const unsigned short* __restrict__ BT16,
    void* __restrict__ Cout,
    unsigned short* __restrict__ Qb,
    unsigned short* __restrict__ Kb,
    unsigned short* __restrict__ Vb,     // V dest: [t][d] (vT=0) or [d][t] (vT=1)
    const int* __restrict__ flag,
    int M, int N, int K, int mode, int vT)
{
  __shared__ __align__(16) unsigned short As[2][128 * 32];
  __shared__ __align__(16) unsigned short Bs[2][128 * 32];

  const int fmt = *flag;
  const int tid  = threadIdx.x;
  const int wave = tid >> 6;
  const int lane = tid & 63;
  const int col  = lane & 15;
  const int quad = lane >> 4;
  const int m0 = blockIdx.x * 128;
  const int n0 = blockIdx.y * 128;
  const int wm = (wave >> 1) * 64;
  const int wn = (wave & 1) * 64;

  const int r4 = lane >> 2;                                   // row in 16-group
  const int schunk = ((lane & 3) ^ ((lane >> 3) & 3)) * 8;    // pre-swizzled src chunk
  const int rsw = (quad ^ ((col >> 1) & 3)) * 8;              // frag-read swizzle

  f32x4 acc[4][4];
  #pragma unroll
  for (int i = 0; i < 4; i++)
    #pragma unroll
    for (int j = 0; j < 4; j++) acc[i][j] = (f32x4){0.f, 0.f, 0.f, 0.f};

  const unsigned short* ApA = A16  + (size_t)(m0 + wave * 32 + r4) * K + schunk;
  const unsigned short* ApB = ApA + (size_t)16 * K;
  const unsigned short* BpA = BT16 + (size_t)(n0 + wave * 32 + r4) * K + schunk;
  const unsigned short* BpB = BpA + (size_t)16 * K;

#define STAGE(BUF, KS) do { \
    glds16(ApA + (KS) * 32, &As[BUF][wave * 32 * 32]);        \
    glds16(ApB + (KS) * 32, &As[BUF][(wave * 32 + 16) * 32]); \
    glds16(BpA + (KS) * 32, &Bs[BUF][wave * 32 * 32]);        \
    glds16(BpB + (KS) * 32, &Bs[BUF][(wave * 32 + 16) * 32]); \
  } while (0)

#define COMPUTE(BUF) do { \
    short8 afr[4], bfr[4]; \
    _Pragma("unroll") \
    for (int mi = 0; mi < 4; mi++) \
      afr[mi] = *(const short8*)&As[BUF][(wm + mi * 16 + col) * 32 + rsw]; \
    _Pragma("unroll") \
    for (int ni = 0; ni < 4; ni++) \
      bfr[ni] = *(const short8*)&Bs[BUF][(wn + ni * 16 + col) * 32 + rsw]; \
    _Pragma("unroll") \
    for (int mi = 0; mi < 4; mi++) \
      _Pragma("unroll") \
      for (int ni = 0; ni < 4; ni++) \
        acc[mi][ni] = __builtin_amdgcn_mfma_f32_16x16x32_bf16(afr[mi], bfr[ni], acc[mi][ni], 0, 0, 0); \
  } while (0)

  const int NK = K >> 5;          // 32-k tiles (K=1024 -> 32)
  STAGE(0, 0);
  for (int ks = 0; ks < NK - 1; ++ks) {
    STAGE((ks + 1) & 1, ks + 1);                       // prefetch next tile
    asm volatile("s_waitcnt vmcnt(4)" ::: "memory");   // drain CURRENT tile only
    __builtin_amdgcn_s_barrier();
    __builtin_amdgcn_sched_barrier(0);
    COMPUTE(ks & 1);
    __builtin_amdgcn_sched_barrier(0);
    __builtin_amdgcn_s_barrier();                      // readers done before re-stage
  }
  asm volatile("s_waitcnt vmcnt(0)" ::: "memory");     // last tile: drain all
  __builtin_amdgcn_s_barrier();
  __builtin_amdgcn_sched_barrier(0);
  COMPUTE((NK - 1) & 1);
#undef STAGE
#undef COMPUTE

  if (mode == 1) {       // QKV scatter, hoisted per-subtile
    const int bb = m0 >> 11;          // batch (block never straddles)
    const int tBase = (m0 & 2047) + wm;
    #pragma unroll
    for (int ni = 0; ni < 4; ni++) {
      const int n = n0 + wn + ni * 16 + col;
      const int which = n >> 10;      // N=3072: 0=q 1=k 2=v
      const int rem = n & 1023;
      const int h = rem >> 6;
      const int d = rem & 63;
      if (which == 2 && vT) {
        // transposed V: [h][d][t], t = tBase+mi*16+quad*4+i contiguous -> 8B packed
        unsigned short* base = Vb + (size_t)(bb * Hdim + h) * Tdim * Ddim
                                  + (size_t)d * Tdim + tBase;
        #pragma unroll
        for (int mi = 0; mi < 4; mi++) {
          const int t0 = mi * 16 + quad * 4;
          *(uint2*)(base + t0) = make_uint2(pk_bf16(acc[mi][ni][0], acc[mi][ni][1]),
                                            pk_bf16(acc[mi][ni][2], acc[mi][ni][3]));
        }
      } else {
        unsigned short* dstBase = (which == 0) ? Qb : (which == 1 ? Kb : Vb);
        const float scale = (which == 0) ? SCALE_Q : 1.f;
        dstBase += (size_t)(bb * Hdim + h) * Tdim * Ddim + d;
        #pragma unroll
        for (int mi = 0; mi < 4; mi++)
          #pragma unroll
          for (int i = 0; i < 4; i++) {
            const int t = tBase + mi * 16 + quad * 4 + i;
            dstBase[(size_t)t * Ddim] = f2bf(acc[mi][ni][i] * scale);
          }
      }
    }
  } else {
    #pragma unroll
    for (int mi = 0; mi < 4; mi++)
      #pragma unroll
      for (int ni = 0; ni < 4; ni++)
        #pragma unroll
        for (int i = 0; i < 4; i++) {
          const int m = m0 + wm + mi * 16 + quad * 4 + i;
          const int n = n0 + wn + ni * 16 + col;
          const float v = acc[mi][ni][i];
          if (fmt == 0) ((float*)Cout)[(size_t)m * N + n] = v;
          else ((unsigned short*)Cout)[(size_t)m * N + n] = f2bf(v);
        }
  }
}

// ---------------------------------------------------------------------------
// gemm64 (R3-proven) — small-ws per-batch fallback only.
// ---------------------------------------------------------------------------
#define BM 64
#define BN 64
#define BK 32
#define LDK 40

__global__ __launch_bounds__(256) void gemm64_kernel(
    const void* __restrict__ A,
    const void* __restrict__ Bw,
    void* __restrict__ Cout,
    unsigned short* __restrict__ Qb,
    unsigned short* __restrict__ Kb,
    unsigned short* __restrict__ Vb,
    const int* __restrict__ flag,
    int M, int N, int K, int mode, int aFmt, int outFmt, int aOff, int mOff)
{
  __shared__ __align__(16) unsigned short As[BM * LDK];
  __shared__ __align__(16) unsigned short Bs[BN * LDK];

  const int fmt = *flag;
  const int af  = (aFmt  == 2) ? fmt : aFmt;
  const int of  = (outFmt == 2) ? fmt : outFmt;

  const int tid  = threadIdx.x;
  const int wave = tid >> 6;
  const int lane = tid & 63;
  const int m0 = blockIdx.x * BM;
  const int n0 = blockIdx.y * BN;

  const int ar = tid >> 2;
  const int ak = (tid & 3) * 8;
  const int bk = tid >> 3;
  const int bn = (tid & 7) * 8;

  const int lr = lane & 15;
  const int lq = lane >> 4;

  f32x4 acc[4] = {{0,0,0,0},{0,0,0,0},{0,0,0,0},{0,0,0,0}};

  for (int k0 = 0; k0 < K; k0 += BK) {
    U8 a8;
    if (af == 1) {
      a8.v = *(const uint4*)((const unsigned short*)A + (size_t)(aOff + m0 + ar) * K + (k0 + ak));
    } else {
      const float* Af = (const float*)A + (size_t)(aOff + m0 + ar) * K + (k0 + ak);
      float4 x0 = *(const float4*)(Af);
      float4 x1 = *(const float4*)(Af + 4);
      a8.s[0] = f2bf(x0.x); a8.s[1] = f2bf(x0.y); a8.s[2] = f2bf(x0.z); a8.s[3] = f2bf(x0.w);
      a8.s[4] = f2bf(x1.x); a8.s[5] = f2bf(x1.y); a8.s[6] = f2bf(x1.z); a8.s[7] = f2bf(x1.w);
    }
    *(uint4*)(&As[ar * LDK + ak]) = a8.v;

    U8 b8;
    if (fmt == 1) {
      b8.v = *(const uint4*)((const unsigned short*)Bw + (size_t)(k0 + bk) * N + (n0 + bn));
    } else {
      const float* Bf = (const float*)Bw + (size_t)(k0 + bk) * N + (n0 + bn);
      float4 x0 = *(const float4*)(Bf);
      float4 x1 = *(const float4*)(Bf + 4);
      b8.s[0] = f2bf(x0.x); b8.s[1] = f2bf(x0.y); b8.s[2] = f2bf(x0.z); b8.s[3] = f2bf(x0.w);
      b8.s[4] = f2bf(x1.x); b8.s[5] = f2bf(x1.y); b8.s[6] = f2bf(x1.z); b8.s[7] = f2bf(x1.w);
    }
    #pragma unroll
    for (int i = 0; i < 8; i++) Bs[(bn + i) * LDK + bk] = b8.s[i];
    __syncthreads();

    short8 afrag = *(const short8*)(&As[(wave * 16 + lr) * LDK + lq * 8]);
    #pragma unroll
    for (int c = 0; c < 4; c++) {
      short8 bfrag = *(const short8*)(&Bs[(c * 16 + lr) * LDK + lq * 8]);
      acc[c] = __builtin_amdgcn_mfma_f32_16x16x32_bf16(afrag, bfrag, acc[c], 0, 0, 0);
    }
    __syncthreads();
  }

  #pragma unroll
  for (int c = 0; c < 4; c++) {
    #pragma unroll
    for (int i = 0; i < 4; i++) {
      const int m = m0 + wave * 16 + lq * 4 + i;
      const int n = n0 + c * 16 + lr;
      const float v = acc[c][i];
      if (mode == 0) {
        if (of == 0) ((float*)Cout)[(size_t)(mOff + m) * N + n] = v;
        else ((unsigned short*)Cout)[(size_t)(mOff + m) * N + n] = f2bf(v);
      } else {
        const int which = n >> 10;
        const int rem = n & 1023;
        const int h = rem >> 6;
        const int d = rem & 63;
        const int b = m >> 11;
        const int t = m & 2047;
        const size_t idx = ((size_t)(b * Hdim + h) * Tdim + t) * Ddim + d;
        if      (which == 0) Qb[idx] = f2bf(v * SCALE_Q);
        else if (which == 1) Kb[idx] = f2bf(v);
        else                 Vb[idx] = f2bf(v);
      }
    }
  }
}

// ---------------------------------------------------------------------------
// attn128 (R14): R13 structure + two changes:
//  1. XCD-locality swizzle: pair = blockIdx>>6, bh = blockIdx&63. With the
//     HW's round-robin block->XCD mapping (XCD = blockIdx%8), the old
//     bh*8+pair encoding gave XCD = pair%8: each XCD got 64 DIFFERENT heads,
//     zero K/V L2 reuse (FETCH 147MB vs 48MB ideal). New encoding gives
//     XCD = bh%8: all 8 blocks of a head share one XCD; per-XCD K/V working
//     set = 8 heads x 512KB = 4MB = L2 size. Work per block unchanged
//     (uniform 34 kt -> no R9-style tail).
//  2. fminf(s,80) clamp removed: s is in exp2 domain, sigma~1.4, max~8 << 80,
//     clamp never fires on sane data -> bit-identical output, -32 VALU/kt
//     on the bottleneck pipe (VALUBusy 50%). Masked entries use -1e30 and
//     exp2(-1e30)=0 without any clamp.
// ---------------------------------------------------------------------------
__global__ __launch_bounds__(256) void attn128_kernel(
    const unsigned short* __restrict__ Qb,
    const unsigned short* __restrict__ Kb,
    const unsigned short* __restrict__ VbT,   // [head][D][T], required
    unsigned short* __restrict__ Y)
{
  __shared__ __align__(16) unsigned short Ks[2][64 * 64];    // [key][d] swizzled
  __shared__ __align__(16) unsigned short Vt[2][64 * 64];    // [d][key] swizzled
  __shared__ __align__(16) unsigned short Pw[4][32 * 64];    // per-wave P [row][key] swizzled

  const int tid  = threadIdx.x;
  const int wave = tid >> 6;
  const int lane = tid & 63;
  const int col  = lane & 15;
  const int quad = lane >> 4;
  const int cx   = col & 7;
  const int ch0  = (quad ^ cx) * 8;    // physical shorts-offset of logical chunk 'quad'
  const int ch1  = ch0 ^ 32;           // logical chunk quad+4

  // staging lane geometry: one glds16 = 8 rows x 64 shorts; srow = row-in-call
  const int srow = lane >> 3;                       // 0..7
  const int sx   = ((lane & 7) ^ (srow & 7)) * 8;   // pre-swizzled source chunk

  // XCD-locality: blockIdx%8 == bh%8 -> a head's 8 blocks share one XCD L2
  const int pair = blockIdx.x >> 6;
  const int bh   = blockIdx.x & 63;
  const size_t headOff = (size_t)bh * Tdim * Ddim;
  const int b = bh >> 4;
  const int h = bh & 15;

  const short8 onesf = {16256, 16256, 16256, 16256, 16256, 16256, 16256, 16256}; // bf16 1.0 x8

#define ASTAGE(BUF, KB) do { \
    const unsigned short* Ksrc = Kb + headOff + (size_t)((KB) + wave * 16 + srow) * Ddim + sx; \
    glds16(Ksrc,            &Ks[BUF][(wave * 16) * 64]);      \
    glds16(Ksrc + 8 * Ddim, &Ks[BUF][(wave * 16 + 8) * 64]);  \
    const unsigned short* Vsrc = VbT + headOff + (size_t)(wave * 16 + srow) * Tdim + (KB) + sx; \
    glds16(Vsrc,            &Vt[BUF][(wave * 16) * 64]);      \
    glds16(Vsrc + 8 * Tdim, &Vt[BUF][(wave * 16 + 8) * 64]);  \
  } while (0)

  #pragma unroll
  for (int half = 0; half < 2; half++) {
    const int qt = half ? (15 - pair) : pair;
    const int qb = qt * 128;
    const int nkt = (qb >> 6) + 2;
    const int rMin = qb + wave * 32;
    const int rMax = rMin + 31;

    short8 qf[2][2];
    #pragma unroll
    for (int mi = 0; mi < 2; mi++) {
      const unsigned short* Qr = Qb + headOff + (size_t)(rMin + mi * 16 + col) * Ddim;
      qf[mi][0] = *(const short8*)(Qr + quad * 8);
      qf[mi][1] = *(const short8*)(Qr + 32 + quad * 8);
    }

    f32x4 o_acc[2][4];
    f32x4 l_acc[2];
    #pragma unroll
    for (int mi = 0; mi < 2; mi++) {
      l_acc[mi] = (f32x4){0.f, 0.f, 0.f, 0.f};
      #pragma unroll
      for (int n = 0; n < 4; n++) o_acc[mi][n] = (f32x4){0.f, 0.f, 0.f, 0.f};
    }

    ASTAGE(0, 0);
    for (int kt = 0; kt < nkt; kt++) {
      const int cur = kt & 1;
      if (kt + 1 < nkt) {
        ASTAGE(cur ^ 1, (kt + 1) * 64);                  // prefetch next tile
        asm volatile("s_waitcnt vmcnt(4)" ::: "memory"); // drain current tile only
      } else {
        asm volatile("s_waitcnt vmcnt(0)" ::: "memory"); // last tile: drain all
      }
      __builtin_amdgcn_s_barrier();
      __builtin_amdgcn_sched_barrier(0);

      const int ktb = kt * 64;
      if (ktb <= rMax) {
        // --- S^T = K @ Q^T : s_acc[c][mi], register idx = key, lane col = qrow
        f32x4 s_acc[4][2];
        #pragma unroll
        for (int c = 0; c < 4; c++) {
          const unsigned short* Kl = &Ks[cur][(c * 16 + col) * 64];
          short8 kf0 = *(const short8*)(Kl + ch0);
          short8 kf1 = *(const short8*)(Kl + ch1);
          #pragma unroll
          for (int mi = 0; mi < 2; mi++) {
            f32x4 z = {0.f, 0.f, 0.f, 0.f};
            z = __builtin_amdgcn_mfma_f32_16x16x32_bf16(kf0, qf[mi][0], z, 0, 0, 0);
            s_acc[c][mi] = __builtin_amdgcn_mfma_f32_16x16x32_bf16(kf1, qf[mi][1], z, 0, 0, 0);
          }
        }

        // causal mask: key > qrow -> -inf  (key = ktb+c*16+quad*4+i, qrow = rMin+mi*16+col)
        if (ktb + 63 > rMin) {
          #pragma unroll
          for (int c = 0; c < 4; c++)
            #pragma unroll
            for (int mi = 0; mi < 2; mi++)
              #pragma unroll
              for (int i = 0; i < 4; i++)
                if (ktb + c * 16 + quad * 4 + i > rMin + mi * 16 + col)
                  s_acc[c][mi][i] = -1e30f;
        }

        // --- softmax (exp2 domain, no clamp) + packed b64 P stores (swizzled)
        #pragma unroll
        for (int mi = 0; mi < 2; mi++)
          #pragma unroll
          for (int c = 0; c < 4; c++) {
            const float p0 = fexp2(s_acc[c][mi][0]);
            const float p1 = fexp2(s_acc[c][mi][1]);
            const float p2 = fexp2(s_acc[c][mi][2]);
            const float p3 = fexp2(s_acc[c][mi][3]);
            const unsigned int u0 = pk_bf16(p0, p1);
            const unsigned int u1 = pk_bf16(p2, p3);
            // logical 16B-chunk (2c + quad>>1), physical = logical ^ cx; 8B half = quad&1
            const int po = (((c * 2 + (quad >> 1)) ^ cx) * 8) + (quad & 1) * 4;
            *(uint2*)&Pw[wave][(mi * 16 + col) * 64 + po] = make_uint2(u0, u1);
          }

        short8 pf[2][2];
        #pragma unroll
        for (int mi = 0; mi < 2; mi++) {
          pf[mi][0] = *(const short8*)(&Pw[wave][(mi * 16 + col) * 64 + ch0]);
          pf[mi][1] = *(const short8*)(&Pw[wave][(mi * 16 + col) * 64 + ch1]);
          // row-sum via ones-MFMA: lands in o_acc-compatible C layout
          l_acc[mi] = __builtin_amdgcn_mfma_f32_16x16x32_bf16(pf[mi][0], onesf, l_acc[mi], 0, 0, 0);
          l_acc[mi] = __builtin_amdgcn_mfma_f32_16x16x32_bf16(pf[mi][1], onesf, l_acc[mi], 0, 0, 0);
        }
        #pragma unroll
        for (int n = 0; n < 4; n++) {
          const unsigned short* Vl = &Vt[cur][(n * 16 + col) * 64];
          short8 vf0 = *(const short8*)(Vl + ch0);
          short8 vf1 = *(const short8*)(Vl + ch1);
          #pragma unroll
          for (int mi = 0; mi < 2; mi++) {
            o_acc[mi][n] = __builtin_amdgcn_mfma_f32_16x16x32_bf16(pf[mi][0], vf0, o_acc[mi][n], 0, 0, 0);
            o_acc[mi][n] = __builtin_amdgcn_mfma_f32_16x16x32_bf16(pf[mi][1], vf1, o_acc[mi][n], 0, 0, 0);
          }
        }
      }
      __builtin_amdgcn_sched_barrier(0);
      __builtin_amdgcn_s_barrier();     // readers done before next STAGE overwrites
    }

    #pragma unroll
    for (int mi = 0; mi < 2; mi++)
      #pragma unroll
      for (int i = 0; i < 4; i++) {
        const float inv = 1.f / l_acc[mi][i];
        const int qrow = rMin + mi * 16 + quad * 4 + i;
        unsigned short* dst = Y + (size_t)(b * Tdim + qrow) * Cdim + h * Ddim;
        #pragma unroll
        for (int n = 0; n < 4; n++)
          dst[n * 16 + col] = f2bf(o_acc[mi][n][i] * inv);
      }
  }
#undef ASTAGE
}

// ---------------------------------------------------------------------------
// attn128_legacy (R10-proven): used by fallback tiers (no VbT workspace).
// ---------------------------------------------------------------------------
__global__ __launch_bounds__(256) void attn128_legacy_kernel(
    const unsigned short* __restrict__ Qb,
    const unsigned short* __restrict__ Kb,
    const unsigned short* __restrict__ Vb,
    const unsigned short* __restrict__ VbT,   // [head][D][T] or nullptr
    unsigned short* __restrict__ Y)
{
  __shared__ __align__(16) unsigned short Ks[64 * 72];       // [key][d]
  __shared__ __align__(16) unsigned short Vt[64 * 72];       // [d][key]
  __shared__ __align__(16) unsigned short Pw[4][32 * 72];    // per-wave P [row][key]

  const int tid  = threadIdx.x;
  const int wave = tid >> 6;
  const int lane = tid & 63;
  const int col  = lane & 15;
  const int quad = lane >> 4;

  const int pair = blockIdx.x & 7;
  const int bh   = blockIdx.x >> 3;
  const size_t headOff = (size_t)bh * Tdim * Ddim;

  const int sr = tid >> 2;
  const int sc = (tid & 3) * 16;

  const int b = bh >> 4;
  const int h = bh & 15;

  const short8 onesf = {16256, 16256, 16256, 16256, 16256, 16256, 16256, 16256};

  #pragma unroll
  for (int half = 0; half < 2; half++) {
    const int qt = half ? (15 - pair) : pair;
    const int qb = qt * 128;
    const int nkt = (qb >> 6) + 2;
    const int rMin = qb + wave * 32;
    const int rMax = rMin + 31;

    short8 qf[2][2];
    #pragma unroll
    for (int mi = 0; mi < 2; mi++) {
      const unsigned short* Qr = Qb + headOff + (size_t)(rMin + mi * 16 + col) * Ddim;
      qf[mi][0] = *(const short8*)(Qr + quad * 8);
      qf[mi][1] = *(const short8*)(Qr + 32 + quad * 8);
    }

    f32x4 o_acc[2][4];
    f32x4 l_acc[2];
    #pragma unroll
    for (int mi = 0; mi < 2; mi++) {
      l_acc[mi] = (f32x4){0.f, 0.f, 0.f, 0.f};
      #pragma unroll
      for (int n = 0; n < 4; n++) o_acc[mi][n] = (f32x4){0.f, 0.f, 0.f, 0.f};
    }

    uint4 kr0, kr1, vr0, vr1;
    {
      const unsigned short* Kr = Kb + headOff + (size_t)sr * Ddim + sc;
      kr0 = *(const uint4*)(Kr);
      kr1 = *(const uint4*)(Kr + 8);
      if (VbT) {
        const unsigned short* Vr = VbT + headOff + (size_t)sr * Tdim + sc;
        vr0 = *(const uint4*)(Vr);
        vr1 = *(const uint4*)(Vr + 8);
      } else {
        const unsigned short* Vr = Vb + headOff + (size_t)sr * Ddim + sc;
        vr0 = *(const uint4*)(Vr);
        vr1 = *(const uint4*)(Vr + 8);
      }
    }

    for (int kt = 0; kt < nkt; kt++) {
      __syncthreads();
      *(uint4*)&Ks[sr * 72 + sc]     = kr0;
      *(uint4*)&Ks[sr * 72 + sc + 8] = kr1;
      if (VbT) {
        *(uint4*)&Vt[sr * 72 + sc]     = vr0;
        *(uint4*)&Vt[sr * 72 + sc + 8] = vr1;
      } else {
        U8 v0, v1; v0.v = vr0; v1.v = vr1;
        #pragma unroll
        for (int j = 0; j < 8; j++) {
          Vt[(sc + j) * 72 + sr]     = v0.s[j];
          Vt[(sc + 8 + j) * 72 + sr] = v1.s[j];
        }
      }
      __syncthreads();

      if (kt + 1 < nkt) {
        const int kb = (kt + 1) * 64;
        const unsigned short* Kr = Kb + headOff + (size_t)(kb + sr) * Ddim + sc;
        kr0 = *(const uint4*)(Kr);
        kr1 = *(const uint4*)(Kr + 8);
        if (VbT) {
          const unsigned short* Vr = VbT + headOff + (size_t)sr * Tdim + kb + sc;
          vr0 = *(const uint4*)(Vr);
          vr1 = *(const uint4*)(Vr + 8);
        } else {
          const unsigned short* Vr = Vb + headOff + (size_t)(kb + sr) * Ddim + sc;
          vr0 = *(const uint4*)(Vr);
          vr1 = *(const uint4*)(Vr + 8);
        }
      }

      const int ktb = kt * 64;
      if (ktb <= rMax) {
        f32x4 s_acc[4][2];
        #pragma unroll
        for (int c = 0; c < 4; c++) {
          const unsigned short* Kl = &Ks[(c * 16 + col) * 72];
          short8 kf0 = *(const short8*)(Kl + quad * 8);
          short8 kf1 = *(const short8*)(Kl + 32 + quad * 8);
          #pragma unroll
          for (int mi = 0; mi < 2; mi++) {
            f32x4 z = {0.f, 0.f, 0.f, 0.f};
            z = __builtin_amdgcn_mfma_f32_16x16x32_bf16(kf0, qf[mi][0], z, 0, 0, 0);
            s_acc[c][mi] = __builtin_amdgcn_mfma_f32_16x16x32_bf16(kf1, qf[mi][1], z, 0, 0, 0);
          }
        }

        if (ktb + 63 > rMin) {
          #pragma unroll
          for (int c = 0; c < 4; c++)
            #pragma unroll
            for (int mi = 0; mi < 2; mi++)
              #pragma unroll
              for (int i = 0; i < 4; i++)
                if (ktb + c * 16 + quad * 4 + i > rMin + mi * 16 + col)
                  s_acc[c][mi][i] = -1e30f;
        }

        #pragma unroll
        for (int mi = 0; mi < 2; mi++)
          #pragma unroll
          for (int c = 0; c < 4; c++) {
            const float p0 = fexp2(fminf(s_acc[c][mi][0], 80.f));
            const float p1 = fexp2(fminf(s_acc[c][mi][1], 80.f));
            const float p2 = fexp2(fminf(s_acc[c][mi][2], 80.f));
            const float p3 = fexp2(fminf(s_acc[c][mi][3], 80.f));
            const unsigned int u0 = pk_bf16(p0, p1);
            const unsigned int u1 = pk_bf16(p2, p3);
            uint2* dst = (uint2*)&Pw[wave][(mi * 16 + col) * 72 + c * 16 + quad * 4];
            *dst = make_uint2(u0, u1);
          }

        short8 pf[2][2];
        #pragma unroll
        for (int mi = 0; mi < 2; mi++) {
          pf[mi][0] = *(const short8*)(&Pw[wave][(mi * 16 + col) * 72 + quad * 8]);
          pf[mi][1] = *(const short8*)(&Pw[wave][(mi * 16 + col) * 72 + 32 + quad * 8]);
          l_acc[mi] = __builtin_amdgcn_mfma_f32_16x16x32_bf16(pf[mi][0], onesf, l_acc[mi], 0, 0, 0);
          l_acc[mi] = __builtin_amdgcn_mfma_f32_16x16x32_bf16(pf[mi][1], onesf, l_acc[mi], 0, 0, 0);
        }
        #pragma unroll
        for (int n = 0; n < 4; n++) {
          const unsigned short* Vl = &Vt[(n * 16 + col) * 72];
          short8 vf0 = *(const short8*)(Vl + quad * 8);
          short8 vf1 = *(const short8*)(Vl + 32 + quad * 8);
          #pragma unroll
          for (int mi = 0; mi < 2; mi++) {
            o_acc[mi][n] = __builtin_amdgcn_mfma_f32_16x16x32_bf16(pf[mi][0], vf0, o_acc[mi][n], 0, 0, 0);
            o_acc[mi][n] = __builtin_amdgcn_mfma_f32_16x16x32_bf16(pf[mi][1], vf1, o_acc[mi][n], 0, 0, 0);
          }
        }
      }
    }

    #pragma unroll
    for (int mi = 0; mi < 2; mi++)
      #pragma unroll
      for (int i = 0; i < 4; i++) {
        const float inv = 1.f / l_acc[mi][i];
        const int qrow = rMin + mi * 16 + quad * 4 + i;
        unsigned short* dst = Y + (size_t)(b * Tdim + qrow) * Cdim + h * Ddim;
        #pragma unroll
        for (int n = 0; n < 4; n++)
          dst[n * 16 + col] = f2bf(o_acc[mi][n][i] * inv);
      }
  }
}

// ---------------------------------------------------------------------------
// launch. ws layout unchanged.
// FULL2 tier: prep -> gemm128d(qkv, V->VbT transposed) -> attn128 -> gemm128d.
// ---------------------------------------------------------------------------
extern "C" void kernel_launch(void* const* d_in, const int* in_sizes, int n_in,
                              void* d_out, int out_size, void* d_ws, size_t ws_size,
                              hipStream_t stream) {
  const void* x      = d_in[0];
  const void* w_qkv  = d_in[1];
  const void* w_proj = d_in[2];

  int* flag = (int*)d_ws;
  unsigned short* wsb = (unsigned short*)((char*)d_ws + 1024);

  const size_t HS = (size_t)Bdim * Hdim * Tdim * Ddim;   // 8,388,608 elems
  const size_t FULL  = 1024 + 2 * (4 * HS + (size_t)3072 * 1024 + (size_t)1024 * 1024);
  const size_t FULL2 = FULL + 2 * HS;
  const size_t MONO  = 1024 + 2 * (4 * HS);

  dim3 blk(256);

  if (ws_size >= FULL) {
    unsigned short* Qb  = wsb;
    unsigned short* Kb  = Qb + HS;
    unsigned short* Vb  = Kb + HS;
    unsigned short* XY  = Vb + HS;            // X16 then Y2 (bf16 [B*T, C])
    unsigned short* WqT = XY + HS;
    unsigned short* WpT = WqT + (size_t)3072 * 1024;
    unsigned short* VbT = WpT + (size_t)1024 * 1024;
    const int M = Bdim * Tdim;                // 8192

    prep_kernel<<<dim3(5120), blk, 0, stream>>>(x, w_qkv, w_proj, XY, WqT, WpT, flag);

    if (ws_size >= FULL2) {
      // V written directly transposed into VbT by the GEMM epilogue
      gemm128d_kernel<<<dim3(M / 128, 3072 / 128), blk, 0, stream>>>(
          XY, WqT, nullptr, Qb, Kb, VbT, flag, M, 3072, Cdim, 1, 1);
      attn128_kernel<<<dim3(Bdim * Hdim * 8), blk, 0, stream>>>(Qb, Kb, VbT, XY);
    } else {
      gemm128d_kernel<<<dim3(M / 128, 3072 / 128), blk, 0, stream>>>(
          XY, WqT, nullptr, Qb, Kb, Vb, flag, M, 3072, Cdim, 1, 0);
      attn128_legacy_kernel<<<dim3(Bdim * Hdim * 8), blk, 0, stream>>>(Qb, Kb, Vb, nullptr, XY);
    }

    gemm128d_kernel<<<dim3(M / 128, Cdim / 128), blk, 0, stream>>>(
        XY, WpT, d_out, nullptr, nullptr, nullptr, flag, M, Cdim, Cdim, 0, 0);
  } else if (ws_size >= MONO) {
    // MONO: R3-proven per-batch flow (gemm64 converts A inline).
    detect_kernel<<<1, 64, 0, stream>>>((const unsigned int*)x, flag);
    const size_t HSb = (size_t)Hdim * Tdim * Ddim;
    unsigned short* Qb2 = wsb;
    unsigned short* Kb2 = Qb2 + HSb;
    unsigned short* Vb2 = Kb2 + HSb;
    unsigned short* Y2  = Vb2 + HSb;
    for (int b = 0; b < Bdim; b++) {
      gemm64_kernel<<<dim3(Tdim / BM, 3072 / BN), blk, 0, stream>>>(
          x, w_qkv, nullptr, Qb2, Kb2, Vb2, flag,
          Tdim, 3072, Cdim, 1, 2, 2, b * Tdim, 0);
      attn128_legacy_kernel<<<dim3(Hdim * 8), blk, 0, stream>>>(Qb2, Kb2, Vb2, nullptr, Y2);
      gemm64_kernel<<<dim3(Tdim / BM, Cdim / BN), blk, 0, stream>>>(
          Y2, w_proj, d_out, nullptr, nullptr, nullptr, flag,
          Tdim, Cdim, Cdim, 0, 1, 2, 0, b * Tdim);
    }
  } else {   // per-batch fallback (16 MiB + 1 KiB), R3-proven
    detect_kernel<<<1, 64, 0, stream>>>((const unsigned int*)x, flag);
    const size_t HSb = (size_t)Hdim * Tdim * Ddim;
    unsigned short* Qb = wsb;
    unsigned short* Kb = Qb + HSb;
    unsigned short* Vb = Kb + HSb;
    unsigned short* Y2 = Vb + HSb;

    for (int b = 0; b < Bdim; b++) {
      gemm64_kernel<<<dim3(Tdim / BM, 3072 / BN), blk, 0, stream>>>(
          x, w_qkv, nullptr, Qb, Kb, Vb, flag,
          Tdim, 3072, Cdim, 1, 2, 2, b * Tdim, 0);

      attn128_legacy_kernel<<<dim3(Hdim * 8), blk, 0, stream>>>(Qb, Kb, Vb, nullptr, Y2);

      gemm64_kernel<<<dim3(Tdim / BM, Cdim / BN), blk, 0, stream>>>(
          Y2, w_proj, d_out, nullptr, nullptr, nullptr, flag,
          Tdim, Cdim, Cdim, 0, 1, 2, 0, b * Tdim);
    }
  }
}

// Round 7
// 245.478 us; speedup vs baseline: 1.0276x; 1.0185x over previous
//
#include <hip/hip_runtime.h>
#include <hip/hip_bf16.h>

// Problem constants (reference: B,T,C = 4,2048,1024; H=16; D=64)
#define Bdim 4
#define Tdim 2048
#define Cdim 1024
#define Hdim 16
#define Ddim 64
// D^-0.5 * log2(e) = 0.125 * 1.4426950408889634, folded into Q at QKV-GEMM
// epilogue so the attn softmax can use exp2 directly.
#define SCALE_Q 0.18033688011112042f

using f32x4  = __attribute__((ext_vector_type(4))) float;
using short8 = __attribute__((ext_vector_type(8))) short;   // 8 bf16 in 4 VGPRs

union U8 { uint4 v; unsigned short s[8]; };

__device__ __forceinline__ unsigned short f2bf(float f) {  // RNE
  union { float f; unsigned int i; } x; x.f = f;
  unsigned int lsb = (x.i >> 16) & 1u;
  unsigned int r = x.i + 0x7fffu + lsb;
  return (unsigned short)(r >> 16);
}

// 2x f32 -> packed 2x bf16 (RNE). Lowers to v_cvt_pk_bf16_f32 on gfx950.
__device__ __forceinline__ unsigned int pk_bf16(float lo, float hi) {
  union { __hip_bfloat162 h; unsigned int u; } c;
  c.h = __float22bfloat162_rn(make_float2(lo, hi));
  return c.u;
}

__device__ __forceinline__ float fexp2(float x) {
#if __has_builtin(__builtin_amdgcn_exp2f)
  return __builtin_amdgcn_exp2f(x);
#else
  return exp2f(x);
#endif
}

// async global->LDS, 16B per lane. LDS dest is wave-uniform base + lane*16
// (m104/m108): dest layout must be lane-linear. Global source is per-lane,
// so swizzled LDS layouts are achieved by pre-swizzling the global address.
__device__ __forceinline__ void glds16(const unsigned short* g, unsigned short* l) {
  __builtin_amdgcn_global_load_lds(
      (const __attribute__((address_space(1))) void*)g,
      (__attribute__((address_space(3))) void*)l,
      16, 0, 0);
}

__device__ __forceinline__ int detect_fmt(const unsigned int* xw) {
  int cnt = 0;
  for (int i = 0; i < 64; i++) {
    unsigned int e = (xw[i] >> 7) & 0xFFu;
    if (e >= 100u && e <= 140u) cnt++;
  }
  return (cnt >= 40) ? 1 : 0;   // 1 = bf16, 0 = fp32
}

// ---------------------------------------------------------------------------
// detect (kept for MONO / per-batch tiers)
// ---------------------------------------------------------------------------
__global__ void detect_kernel(const unsigned int* __restrict__ x, int* __restrict__ flag) {
  if (threadIdx.x == 0) *flag = detect_fmt(x);
}

// ---------------------------------------------------------------------------
// prep (R8): one launch = detect + cvt_x + cvtT(w_qkv) + cvtT(w_proj).
// ---------------------------------------------------------------------------
__global__ __launch_bounds__(256) void prep_kernel(
    const void* __restrict__ x, const void* __restrict__ wq, const void* __restrict__ wp,
    unsigned short* __restrict__ X16, unsigned short* __restrict__ WqT,
    unsigned short* __restrict__ WpT, int* __restrict__ flag)
{
  __shared__ __align__(16) unsigned short Ts[64][72];
  __shared__ int sfmt;
  if (threadIdx.x == 0) {
    const int f = detect_fmt((const unsigned int*)x);
    sfmt = f;
    if (blockIdx.x == 0) *flag = f;
  }
  __syncthreads();
  const int fmt = sfmt;
  const unsigned bid = blockIdx.x;
  const int tid = threadIdx.x;

  if (bid < 4096u) {                     // ---- cvt_x
    const size_t i = (size_t)bid * 256 + tid;     // < 1,048,576 groups of 8
    if (fmt == 1) {
      *(uint4*)(X16 + i * 8) = *(const uint4*)((const unsigned short*)x + i * 8);
    } else {
      const float* s = (const float*)x + i * 8;
      float4 a = *(const float4*)(s);
      float4 b = *(const float4*)(s + 4);
      U8 o;
      o.s[0]=f2bf(a.x); o.s[1]=f2bf(a.y); o.s[2]=f2bf(a.z); o.s[3]=f2bf(a.w);
      o.s[4]=f2bf(b.x); o.s[5]=f2bf(b.y); o.s[6]=f2bf(b.z); o.s[7]=f2bf(b.w);
      *(uint4*)(X16 + i * 8) = o.v;
    }
    return;
  }

  // ---- cvtT tiles
  const void* W; unsigned short* WT; int N, K, n0, k0;
  if (bid < 4864u) {
    const int t = bid - 4096;
    W = wq; WT = WqT; N = 3072; K = 1024;
    n0 = (t % 48) * 64; k0 = (t / 48) * 64;
  } else {
    const int t = bid - 4864;
    W = wp; WT = WpT; N = 1024; K = 1024;
    n0 = (t & 15) * 64; k0 = (t >> 4) * 64;
  }
  const int r = tid >> 2, c0 = (tid & 3) * 16;

  if (fmt == 0) {
    const float* Wf = (const float*)W + (size_t)(k0 + r) * N + n0 + c0;
    #pragma unroll
    for (int j4 = 0; j4 < 4; j4++) {
      float4 v = *(const float4*)(Wf + j4 * 4);
      Ts[r][c0 + j4*4 + 0] = f2bf(v.x);
      Ts[r][c0 + j4*4 + 1] = f2bf(v.y);
      Ts[r][c0 + j4*4 + 2] = f2bf(v.z);
      Ts[r][c0 + j4*4 + 3] = f2bf(v.w);
    }
  } else {
    const unsigned short* Wh = (const unsigned short*)W + (size_t)(k0 + r) * N + n0 + c0;
    uint4 v0 = *(const uint4*)(Wh);
    uint4 v1 = *(const uint4*)(Wh + 8);
    *(uint4*)&Ts[r][c0] = v0;
    *(uint4*)&Ts[r][c0 + 8] = v1;
  }
  __syncthreads();

  U8 o0, o1;
  #pragma unroll
  for (int j = 0; j < 8; j++) { o0.s[j] = Ts[c0 + j][r]; o1.s[j] = Ts[c0 + 8 + j][r]; }
  unsigned short* dst = WT + (size_t)(n0 + r) * K + k0 + c0;
  *(uint4*)(dst)     = o0.v;
  *(uint4*)(dst + 8) = o1.v;
}

// ---------------------------------------------------------------------------
// gemm128d (R12-proven): 128x128 tile, prefetch pipeline with raw s_barrier +
// counted vmcnt(4). XOR LDS swizzle (conflicts = 0). Unchanged.
// ---------------------------------------------------------------------------
__global__ __launch_bounds__(256) void gemm128d_kernel(
    const unsigned short* __restrict__ A16,
    const unsigned short* __restrict__ BT16,
    void* __restrict__ Cout,
    unsigned short* __restrict__ Qb,
    unsigned short* __restrict__ Kb,
    unsigned short* __restrict__ Vb,     // V dest: [t][d] (vT=0) or [d][t] (vT=1)
    const int* __restrict__ flag,
    int M, int N, int K, int mode, int vT)
{
  __shared__ __align__(16) unsigned short As[2][128 * 32];
  __shared__ __align__(16) unsigned short Bs[2][128 * 32];

  const int fmt = *flag;
  const int tid  = threadIdx.x;
  const int wave = tid >> 6;
  const int lane = tid & 63;
  const int col  = lane & 15;
  const int quad = lane >> 4;
  const int m0 = blockIdx.x * 128;
  const int n0 = blockIdx.y * 128;
  const int wm = (wave >> 1) * 64;
  const int wn = (wave & 1) * 64;

  const int r4 = lane >> 2;                                   // row in 16-group
  const int schunk = ((lane & 3) ^ ((lane >> 3) & 3)) * 8;    // pre-swizzled src chunk
  const int rsw = (quad ^ ((col >> 1) & 3)) * 8;              // frag-read swizzle

  f32x4 acc[4][4];
  #pragma unroll
  for (int i = 0; i < 4; i++)
    #pragma unroll
    for (int j = 0; j < 4; j++) acc[i][j] = (f32x4){0.f, 0.f, 0.f, 0.f};

  const unsigned short* ApA = A16  + (size_t)(m0 + wave * 32 + r4) * K + schunk;
  const unsigned short* ApB = ApA + (size_t)16 * K;
  const unsigned short* BpA = BT16 + (size_t)(n0 + wave * 32 + r4) * K + schunk;
  const unsigned short* BpB = BpA + (size_t)16 * K;

#define STAGE(BUF, KS) do { \
    glds16(ApA + (KS) * 32, &As[BUF][wave * 32 * 32]);        \
    glds16(ApB + (KS) * 32, &As[BUF][(wave * 32 + 16) * 32]); \
    glds16(BpA + (KS) * 32, &Bs[BUF][wave * 32 * 32]);        \
    glds16(BpB + (KS) * 32, &Bs[BUF][(wave * 32 + 16) * 32]); \
  } while (0)

#define COMPUTE(BUF) do { \
    short8 afr[4], bfr[4]; \
    _Pragma("unroll") \
    for (int mi = 0; mi < 4; mi++) \
      afr[mi] = *(const short8*)&As[BUF][(wm + mi * 16 + col) * 32 + rsw]; \
    _Pragma("unroll") \
    for (int ni = 0; ni < 4; ni++) \
      bfr[ni] = *(const short8*)&Bs[BUF][(wn + ni * 16 + col) * 32 + rsw]; \
    _Pragma("unroll") \
    for (int mi = 0; mi < 4; mi++) \
      _Pragma("unroll") \
      for (int ni = 0; ni < 4; ni++) \
        acc[mi][ni] = __builtin_amdgcn_mfma_f32_16x16x32_bf16(afr[mi], bfr[ni], acc[mi][ni], 0, 0, 0); \
  } while (0)

  const int NK = K >> 5;          // 32-k tiles (K=1024 -> 32)
  STAGE(0, 0);
  for (int ks = 0; ks < NK - 1; ++ks) {
    STAGE((ks + 1) & 1, ks + 1);                       // prefetch next tile
    asm volatile("s_waitcnt vmcnt(4)" ::: "memory");   // drain CURRENT tile only
    __builtin_amdgcn_s_barrier();
    __builtin_amdgcn_sched_barrier(0);
    COMPUTE(ks & 1);
    __builtin_amdgcn_sched_barrier(0);
    __builtin_amdgcn_s_barrier();                      // readers done before re-stage
  }
  asm volatile("s_waitcnt vmcnt(0)" ::: "memory");     // last tile: drain all
  __builtin_amdgcn_s_barrier();
  __builtin_amdgcn_sched_barrier(0);
  COMPUTE((NK - 1) & 1);
#undef STAGE
#undef COMPUTE

  if (mode == 1) {       // QKV scatter, hoisted per-subtile
    const int bb = m0 >> 11;          // batch (block never straddles)
    const int tBase = (m0 & 2047) + wm;
    #pragma unroll
    for (int ni = 0; ni < 4; ni++) {
      const int n = n0 + wn + ni * 16 + col;
      const int which = n >> 10;      // N=3072: 0=q 1=k 2=v
      const int rem = n & 1023;
      const int h = rem >> 6;
      const int d = rem & 63;
      if (which == 2 && vT) {
        // transposed V: [h][d][t], t = tBase+mi*16+quad*4+i contiguous -> 8B packed
        unsigned short* base = Vb + (size_t)(bb * Hdim + h) * Tdim * Ddim
                                  + (size_t)d * Tdim + tBase;
        #pragma unroll
        for (int mi = 0; mi < 4; mi++) {
          const int t0 = mi * 16 + quad * 4;
          *(uint2*)(base + t0) = make_uint2(pk_bf16(acc[mi][ni][0], acc[mi][ni][1]),
                                            pk_bf16(acc[mi][ni][2], acc[mi][ni][3]));
        }
      } else {
        unsigned short* dstBase = (which == 0) ? Qb : (which == 1 ? Kb : Vb);
        const float scale = (which == 0) ? SCALE_Q : 1.f;
        dstBase += (size_t)(bb * Hdim + h) * Tdim * Ddim + d;
        #pragma unroll
        for (int mi = 0; mi < 4; mi++)
          #pragma unroll
          for (int i = 0; i < 4; i++) {
            const int t = tBase + mi * 16 + quad * 4 + i;
            dstBase[(size_t)t * Ddim] = f2bf(acc[mi][ni][i] * scale);
          }
      }
    }
  } else {
    #pragma unroll
    for (int mi = 0; mi < 4; mi++)
      #pragma unroll
      for (int ni = 0; ni < 4; ni++)
        #pragma unroll
        for (int i = 0; i < 4; i++) {
          const int m = m0 + wm + mi * 16 + quad * 4 + i;
          const int n = n0 + wn + ni * 16 + col;
          const float v = acc[mi][ni][i];
          if (fmt == 0) ((float*)Cout)[(size_t)m * N + n] = v;
          else ((unsigned short*)Cout)[(size_t)m * N + n] = f2bf(v);
        }
  }
}

// ---------------------------------------------------------------------------
// gemm64 (R3-proven) — small-ws per-batch fallback only.
// ---------------------------------------------------------------------------
#define BM 64
#define BN 64
#define BK 32
#define LDK 40

__global__ __launch_bounds__(256) void gemm64_kernel(
    const void* __restrict__ A,
    const void* __restrict__ Bw,
    void* __restrict__ Cout,
    unsigned short* __restrict__ Qb,
    unsigned short* __restrict__ Kb,
    unsigned short* __restrict__ Vb,
    const int* __restrict__ flag,
    int M, int N, int K, int mode, int aFmt, int outFmt, int aOff, int mOff)
{
  __shared__ __align__(16) unsigned short As[BM * LDK];
  __shared__ __align__(16) unsigned short Bs[BN * LDK];

  const int fmt = *flag;
  const int af  = (aFmt  == 2) ? fmt : aFmt;
  const int of  = (outFmt == 2) ? fmt : outFmt;

  const int tid  = threadIdx.x;
  const int wave = tid >> 6;
  const int lane = tid & 63;
  const int m0 = blockIdx.x * BM;
  const int n0 = blockIdx.y * BN;

  const int ar = tid >> 2;
  const int ak = (tid & 3) * 8;
  const int bk = tid >> 3;
  const int bn = (tid & 7) * 8;

  const int lr = lane & 15;
  const int lq = lane >> 4;

  f32x4 acc[4] = {{0,0,0,0},{0,0,0,0},{0,0,0,0},{0,0,0,0}};

  for (int k0 = 0; k0 < K; k0 += BK) {
    U8 a8;
    if (af == 1) {
      a8.v = *(const uint4*)((const unsigned short*)A + (size_t)(aOff + m0 + ar) * K + (k0 + ak));
    } else {
      const float* Af = (const float*)A + (size_t)(aOff + m0 + ar) * K + (k0 + ak);
      float4 x0 = *(const float4*)(Af);
      float4 x1 = *(const float4*)(Af + 4);
      a8.s[0] = f2bf(x0.x); a8.s[1] = f2bf(x0.y); a8.s[2] = f2bf(x0.z); a8.s[3] = f2bf(x0.w);
      a8.s[4] = f2bf(x1.x); a8.s[5] = f2bf(x1.y); a8.s[6] = f2bf(x1.z); a8.s[7] = f2bf(x1.w);
    }
    *(uint4*)(&As[ar * LDK + ak]) = a8.v;

    U8 b8;
    if (fmt == 1) {
      b8.v = *(const uint4*)((const unsigned short*)Bw + (size_t)(k0 + bk) * N + (n0 + bn));
    } else {
      const float* Bf = (const float*)Bw + (size_t)(k0 + bk) * N + (n0 + bn);
      float4 x0 = *(const float4*)(Bf);
      float4 x1 = *(const float4*)(Bf + 4);
      b8.s[0] = f2bf(x0.x); b8.s[1] = f2bf(x0.y); b8.s[2] = f2bf(x0.z); b8.s[3] = f2bf(x0.w);
      b8.s[4] = f2bf(x1.x); b8.s[5] = f2bf(x1.y); b8.s[6] = f2bf(x1.z); b8.s[7] = f2bf(x1.w);
    }
    #pragma unroll
    for (int i = 0; i < 8; i++) Bs[(bn + i) * LDK + bk] = b8.s[i];
    __syncthreads();

    short8 afrag = *(const short8*)(&As[(wave * 16 + lr) * LDK + lq * 8]);
    #pragma unroll
    for (int c = 0; c < 4; c++) {
      short8 bfrag = *(const short8*)(&Bs[(c * 16 + lr) * LDK + lq * 8]);
      acc[c] = __builtin_amdgcn_mfma_f32_16x16x32_bf16(afrag, bfrag, acc[c], 0, 0, 0);
    }
    __syncthreads();
  }

  #pragma unroll
  for (int c = 0; c < 4; c++) {
    #pragma unroll
    for (int i = 0; i < 4; i++) {
      const int m = m0 + wave * 16 + lq * 4 + i;
      const int n = n0 + c * 16 + lr;
      const float v = acc[c][i];
      if (mode == 0) {
        if (of == 0) ((float*)Cout)[(size_t)(mOff + m) * N + n] = v;
        else ((unsigned short*)Cout)[(size_t)(mOff + m) * N + n] = f2bf(v);
      } else {
        const int which = n >> 10;
        const int rem = n & 1023;
        const int h = rem >> 6;
        const int d = rem & 63;
        const int b = m >> 11;
        const int t = m & 2047;
        const size_t idx = ((size_t)(b * Hdim + h) * Tdim + t) * Ddim + d;
        if      (which == 0) Qb[idx] = f2bf(v * SCALE_Q);
        else if (which == 1) Kb[idx] = f2bf(v);
        else                 Vb[idx] = f2bf(v);
      }
    }
  }
}

// ---------------------------------------------------------------------------
// attn128 (R15): R14 + 3-deep K/V ring buffer -> ONE barrier per kt (was 2).
// Schedule per kt: vmcnt(4) [drain own tile-kt loads] -> s_barrier ->
// STAGE(kt+2) -> COMPUTE(kt).
// Ledger:
//  - vmcnt BEFORE barrier: after the barrier every wave's tile-kt rows are
//    in LDS (each wave drained its own loads, barrier joins all).
//  - STAGE(kt+2) writes buf[(kt+2)%3] = buf[(kt-1)%3]; every wave's
//    COMPUTE(kt-1) precedes its kt-barrier in program order, so all readers
//    of that buffer are done => no trailing barrier needed.
//  - outstanding glds16 at each vmcnt: exactly 8 (tiles kt, kt+1; 4 each);
//    vmcnt(4) drains tile kt. Last kt uses vmcnt(0). nkt>=2 always.
//  - per-half leading s_barrier protects buffers from prev half's readers.
//  - sched_barrier(0) fences ds_reads against hoisting/sinking (rule #18).
// LDS 64KB -> still 2 blocks/CU (grid-capped at 2 anyway).
// ---------------------------------------------------------------------------
__global__ __launch_bounds__(256) void attn128_kernel(
    const unsigned short* __restrict__ Qb,
    const unsigned short* __restrict__ Kb,
    const unsigned short* __restrict__ VbT,   // [head][D][T], required
    unsigned short* __restrict__ Y)
{
  __shared__ __align__(16) unsigned short Ks[3][64 * 64];    // [key][d] swizzled
  __shared__ __align__(16) unsigned short Vt[3][64 * 64];    // [d][key] swizzled
  __shared__ __align__(16) unsigned short Pw[4][32 * 64];    // per-wave P [row][key] swizzled

  const int tid  = threadIdx.x;
  const int wave = tid >> 6;
  const int lane = tid & 63;
  const int col  = lane & 15;
  const int quad = lane >> 4;
  const int cx   = col & 7;
  const int ch0  = (quad ^ cx) * 8;    // physical shorts-offset of logical chunk 'quad'
  const int ch1  = ch0 ^ 32;           // logical chunk quad+4

  // staging lane geometry: one glds16 = 8 rows x 64 shorts; srow = row-in-call
  const int srow = lane >> 3;                       // 0..7
  const int sx   = ((lane & 7) ^ (srow & 7)) * 8;   // pre-swizzled source chunk

  // XCD-locality (R14-proven): blockIdx%8 == bh%8 -> a head's 8 blocks share
  // one XCD L2 (FETCH 147MB -> 29MB)
  const int pair = blockIdx.x >> 6;
  const int bh   = blockIdx.x & 63;
  const size_t headOff = (size_t)bh * Tdim * Ddim;
  const int b = bh >> 4;
  const int h = bh & 15;

  const short8 onesf = {16256, 16256, 16256, 16256, 16256, 16256, 16256, 16256}; // bf16 1.0 x8

#define ASTAGE(BUF, KB) do { \
    const unsigned short* Ksrc = Kb + headOff + (size_t)((KB) + wave * 16 + srow) * Ddim + sx; \
    glds16(Ksrc,            &Ks[BUF][(wave * 16) * 64]);      \
    glds16(Ksrc + 8 * Ddim, &Ks[BUF][(wave * 16 + 8) * 64]);  \
    const unsigned short* Vsrc = VbT + headOff + (size_t)(wave * 16 + srow) * Tdim + (KB) + sx; \
    glds16(Vsrc,            &Vt[BUF][(wave * 16) * 64]);      \
    glds16(Vsrc + 8 * Tdim, &Vt[BUF][(wave * 16 + 8) * 64]);  \
  } while (0)

  #pragma unroll
  for (int half = 0; half < 2; half++) {
    const int qt = half ? (15 - pair) : pair;
    const int qb = qt * 128;
    const int nkt = (qb >> 6) + 2;
    const int rMin = qb + wave * 32;
    const int rMax = rMin + 31;

    short8 qf[2][2];
    #pragma unroll
    for (int mi = 0; mi < 2; mi++) {
      const unsigned short* Qr = Qb + headOff + (size_t)(rMin + mi * 16 + col) * Ddim;
      qf[mi][0] = *(const short8*)(Qr + quad * 8);
      qf[mi][1] = *(const short8*)(Qr + 32 + quad * 8);
    }

    f32x4 o_acc[2][4];
    f32x4 l_acc[2];
    #pragma unroll
    for (int mi = 0; mi < 2; mi++) {
      l_acc[mi] = (f32x4){0.f, 0.f, 0.f, 0.f};
      #pragma unroll
      for (int n = 0; n < 4; n++) o_acc[mi][n] = (f32x4){0.f, 0.f, 0.f, 0.f};
    }

    // protect ring buffers from the previous half's readers
    __builtin_amdgcn_s_barrier();
    ASTAGE(0, 0);          // nkt >= 2 always
    ASTAGE(1, 64);

    for (int kt = 0; kt < nkt; kt++) {
      const int cur = kt % 3;
      if (kt + 1 < nkt) {
        asm volatile("s_waitcnt vmcnt(4)" ::: "memory"); // drain own tile-kt loads
      } else {
        asm volatile("s_waitcnt vmcnt(0)" ::: "memory"); // last tile: drain all
      }
      __builtin_amdgcn_s_barrier();
      __builtin_amdgcn_sched_barrier(0);
      if (kt + 2 < nkt) ASTAGE((kt + 2) % 3, (kt + 2) * 64);   // safe: kt-1 readers done

      const int ktb = kt * 64;
      if (ktb <= rMax) {
        // --- S^T = K @ Q^T : s_acc[c][mi], register idx = key, lane col = qrow
        f32x4 s_acc[4][2];
        #pragma unroll
        for (int c = 0; c < 4; c++) {
          const unsigned short* Kl = &Ks[cur][(c * 16 + col) * 64];
          short8 kf0 = *(const short8*)(Kl + ch0);
          short8 kf1 = *(const short8*)(Kl + ch1);
          #pragma unroll
          for (int mi = 0; mi < 2; mi++) {
            f32x4 z = {0.f, 0.f, 0.f, 0.f};
            z = __builtin_amdgcn_mfma_f32_16x16x32_bf16(kf0, qf[mi][0], z, 0, 0, 0);
            s_acc[c][mi] = __builtin_amdgcn_mfma_f32_16x16x32_bf16(kf1, qf[mi][1], z, 0, 0, 0);
          }
        }

        // causal mask: key > qrow -> -inf  (key = ktb+c*16+quad*4+i, qrow = rMin+mi*16+col)
        if (ktb + 63 > rMin) {
          #pragma unroll
          for (int c = 0; c < 4; c++)
            #pragma unroll
            for (int mi = 0; mi < 2; mi++)
              #pragma unroll
              for (int i = 0; i < 4; i++)
                if (ktb + c * 16 + quad * 4 + i > rMin + mi * 16 + col)
                  s_acc[c][mi][i] = -1e30f;
        }

        // --- softmax (exp2 domain, no clamp) + packed b64 P stores (swizzled)
        #pragma unroll
        for (int mi = 0; mi < 2; mi++)
          #pragma unroll
          for (int c = 0; c < 4; c++) {
            const float p0 = fexp2(s_acc[c][mi][0]);
            const float p1 = fexp2(s_acc[c][mi][1]);
            const float p2 = fexp2(s_acc[c][mi][2]);
            const float p3 = fexp2(s_acc[c][mi][3]);
            const unsigned int u0 = pk_bf16(p0, p1);
            const unsigned int u1 = pk_bf16(p2, p3);
            // logical 16B-chunk (2c + quad>>1), physical = logical ^ cx; 8B half = quad&1
            const int po = (((c * 2 + (quad >> 1)) ^ cx) * 8) + (quad & 1) * 4;
            *(uint2*)&Pw[wave][(mi * 16 + col) * 64 + po] = make_uint2(u0, u1);
          }

        short8 pf[2][2];
        #pragma unroll
        for (int mi = 0; mi < 2; mi++) {
          pf[mi][0] = *(const short8*)(&Pw[wave][(mi * 16 + col) * 64 + ch0]);
          pf[mi][1] = *(const short8*)(&Pw[wave][(mi * 16 + col) * 64 + ch1]);
          // row-sum via ones-MFMA: lands in o_acc-compatible C layout
          l_acc[mi] = __builtin_amdgcn_mfma_f32_16x16x32_bf16(pf[mi][0], onesf, l_acc[mi], 0, 0, 0);
          l_acc[mi] = __builtin_amdgcn_mfma_f32_16x16x32_bf16(pf[mi][1], onesf, l_acc[mi], 0, 0, 0);
        }
        #pragma unroll
        for (int n = 0; n < 4; n++) {
          const unsigned short* Vl = &Vt[cur][(n * 16 + col) * 64];
          short8 vf0 = *(const short8*)(Vl + ch0);
          short8 vf1 = *(const short8*)(Vl + ch1);
          #pragma unroll
          for (int mi = 0; mi < 2; mi++) {
            o_acc[mi][n] = __builtin_amdgcn_mfma_f32_16x16x32_bf16(pf[mi][0], vf0, o_acc[mi][n], 0, 0, 0);
            o_acc[mi][n] = __builtin_amdgcn_mfma_f32_16x16x32_bf16(pf[mi][1], vf1, o_acc[mi][n], 0, 0, 0);
          }
        }
      }
      __builtin_amdgcn_sched_barrier(0);   // keep ds_reads inside their phase
    }

    #pragma unroll
    for (int mi = 0; mi < 2; mi++)
      #pragma unroll
      for (int i = 0; i < 4; i++) {
        const float inv = 1.f / l_acc[mi][i];
        const int qrow = rMin + mi * 16 + quad * 4 + i;
        unsigned short* dst = Y + (size_t)(b * Tdim + qrow) * Cdim + h * Ddim;
        #pragma unroll
        for (int n = 0; n < 4; n++)
          dst[n * 16 + col] = f2bf(o_acc[mi][n][i] * inv);
      }
  }
#undef ASTAGE
}

// ---------------------------------------------------------------------------
// attn128_legacy (R10-proven): used by fallback tiers (no VbT workspace).
// ---------------------------------------------------------------------------
__global__ __launch_bounds__(256) void attn128_legacy_kernel(
    const unsigned short* __restrict__ Qb,
    const unsigned short* __restrict__ Kb,
    const unsigned short* __restrict__ Vb,
    const unsigned short* __restrict__ VbT,   // [head][D][T] or nullptr
    unsigned short* __restrict__ Y)
{
  __shared__ __align__(16) unsigned short Ks[64 * 72];       // [key][d]
  __shared__ __align__(16) unsigned short Vt[64 * 72];       // [d][key]
  __shared__ __align__(16) unsigned short Pw[4][32 * 72];    // per-wave P [row][key]

  const int tid  = threadIdx.x;
  const int wave = tid >> 6;
  const int lane = tid & 63;
  const int col  = lane & 15;
  const int quad = lane >> 4;

  const int pair = blockIdx.x & 7;
  const int bh   = blockIdx.x >> 3;
  const size_t headOff = (size_t)bh * Tdim * Ddim;

  const int sr = tid >> 2;
  const int sc = (tid & 3) * 16;

  const int b = bh >> 4;
  const int h = bh & 15;

  const short8 onesf = {16256, 16256, 16256, 16256, 16256, 16256, 16256, 16256};

  #pragma unroll
  for (int half = 0; half < 2; half++) {
    const int qt = half ? (15 - pair) : pair;
    const int qb = qt * 128;
    const int nkt = (qb >> 6) + 2;
    const int rMin = qb + wave * 32;
    const int rMax = rMin + 31;

    short8 qf[2][2];
    #pragma unroll
    for (int mi = 0; mi < 2; mi++) {
      const unsigned short* Qr = Qb + headOff + (size_t)(rMin + mi * 16 + col) * Ddim;
      qf[mi][0] = *(const short8*)(Qr + quad * 8);
      qf[mi][1] = *(const short8*)(Qr + 32 + quad * 8);
    }

    f32x4 o_acc[2][4];
    f32x4 l_acc[2];
    #pragma unroll
    for (int mi = 0; mi < 2; mi++) {
      l_acc[mi] = (f32x4){0.f, 0.f, 0.f, 0.f};
      #pragma unroll
      for (int n = 0; n < 4; n++) o_acc[mi][n] = (f32x4){0.f, 0.f, 0.f, 0.f};
    }

    uint4 kr0, kr1, vr0, vr1;
    {
      const unsigned short* Kr = Kb + headOff + (size_t)sr * Ddim + sc;
      kr0 = *(const uint4*)(Kr);
      kr1 = *(const uint4*)(Kr + 8);
      if (VbT) {
        const unsigned short* Vr = VbT + headOff + (size_t)sr * Tdim + sc;
        vr0 = *(const uint4*)(Vr);
        vr1 = *(const uint4*)(Vr + 8);
      } else {
        const unsigned short* Vr = Vb + headOff + (size_t)sr * Ddim + sc;
        vr0 = *(const uint4*)(Vr);
        vr1 = *(const uint4*)(Vr + 8);
      }
    }

    for (int kt = 0; kt < nkt; kt++) {
      __syncthreads();
      *(uint4*)&Ks[sr * 72 + sc]     = kr0;
      *(uint4*)&Ks[sr * 72 + sc + 8] = kr1;
      if (VbT) {
        *(uint4*)&Vt[sr * 72 + sc]     = vr0;
        *(uint4*)&Vt[sr * 72 + sc + 8] = vr1;
      } else {
        U8 v0, v1; v0.v = vr0; v1.v = vr1;
        #pragma unroll
        for (int j = 0; j < 8; j++) {
          Vt[(sc + j) * 72 + sr]     = v0.s[j];
          Vt[(sc + 8 + j) * 72 + sr] = v1.s[j];
        }
      }
      __syncthreads();

      if (kt + 1 < nkt) {
        const int kb = (kt + 1) * 64;
        const unsigned short* Kr = Kb + headOff + (size_t)(kb + sr) * Ddim + sc;
        kr0 = *(const uint4*)(Kr);
        kr1 = *(const uint4*)(Kr + 8);
        if (VbT) {
          const unsigned short* Vr = VbT + headOff + (size_t)sr * Tdim + kb + sc;
          vr0 = *(const uint4*)(Vr);
          vr1 = *(const uint4*)(Vr + 8);
        } else {
          const unsigned short* Vr = Vb + headOff + (size_t)(kb + sr) * Ddim + sc;
          vr0 = *(const uint4*)(Vr);
          vr1 = *(const uint4*)(Vr + 8);
        }
      }

      const int ktb = kt * 64;
      if (ktb <= rMax) {
        f32x4 s_acc[4][2];
        #pragma unroll
        for (int c = 0; c < 4; c++) {
          const unsigned short* Kl = &Ks[(c * 16 + col) * 72];
          short8 kf0 = *(const short8*)(Kl + quad * 8);
          short8 kf1 = *(const short8*)(Kl + 32 + quad * 8);
          #pragma unroll
          for (int mi = 0; mi < 2; mi++) {
            f32x4 z = {0.f, 0.f, 0.f, 0.f};
            z = __builtin_amdgcn_mfma_f32_16x16x32_bf16(kf0, qf[mi][0], z, 0, 0, 0);
            s_acc[c][mi] = __builtin_amdgcn_mfma_f32_16x16x32_bf16(kf1, qf[mi][1], z, 0, 0, 0);
          }
        }

        if (ktb + 63 > rMin) {
          #pragma unroll
          for (int c = 0; c < 4; c++)
            #pragma unroll
            for (int mi = 0; mi < 2; mi++)
              #pragma unroll
              for (int i = 0; i < 4; i++)
                if (ktb + c * 16 + quad * 4 + i > rMin + mi * 16 + col)
                  s_acc[c][mi][i] = -1e30f;
        }

        #pragma unroll
        for (int mi = 0; mi < 2; mi++)
          #pragma unroll
          for (int c = 0; c < 4; c++) {
            const float p0 = fexp2(fminf(s_acc[c][mi][0], 80.f));
            const float p1 = fexp2(fminf(s_acc[c][mi][1], 80.f));
            const float p2 = fexp2(fminf(s_acc[c][mi][2], 80.f));
            const float p3 = fexp2(fminf(s_acc[c][mi][3], 80.f));
            const unsigned int u0 = pk_bf16(p0, p1);
            const unsigned int u1 = pk_bf16(p2, p3);
            uint2* dst = (uint2*)&Pw[wave][(mi * 16 + col) * 72 + c * 16 + quad * 4];
            *dst = make_uint2(u0, u1);
          }

        short8 pf[2][2];
        #pragma unroll
        for (int mi = 0; mi < 2; mi++) {
          pf[mi][0] = *(const short8*)(&Pw[wave][(mi * 16 + col) * 72 + quad * 8]);
          pf[mi][1] = *(const short8*)(&Pw[wave][(mi * 16 + col) * 72 + 32 + quad * 8]);
          l_acc[mi] = __builtin_amdgcn_mfma_f32_16x16x32_bf16(pf[mi][0], onesf, l_acc[mi], 0, 0, 0);
          l_acc[mi] = __builtin_amdgcn_mfma_f32_16x16x32_bf16(pf[mi][1], onesf, l_acc[mi], 0, 0, 0);
        }
        #pragma unroll
        for (int n = 0; n < 4; n++) {
          const unsigned short* Vl = &Vt[(n * 16 + col) * 72];
          short8 vf0 = *(const short8*)(Vl + quad * 8);
          short8 vf1 = *(const short8*)(Vl + 32 + quad * 8);
          #pragma unroll
          for (int mi = 0; mi < 2; mi++) {
            o_acc[mi][n] = __builtin_amdgcn_mfma_f32_16x16x32_bf16(pf[mi][0], vf0, o_acc[mi][n], 0, 0, 0);
            o_acc[mi][n] = __builtin_amdgcn_mfma_f32_16x16x32_bf16(pf[mi][1], vf1, o_acc[mi][n], 0, 0, 0);
          }
        }
      }
    }

    #pragma unroll
    for (int mi = 0; mi < 2; mi++)
      #pragma unroll
      for (int i = 0; i < 4; i++) {
        const float inv = 1.f / l_acc[mi][i];
        const int qrow = rMin + mi * 16 + quad * 4 + i;
        unsigned short* dst = Y + (size_t)(b * Tdim + qrow) * Cdim + h * Ddim;
        #pragma unroll
        for (int n = 0; n < 4; n++)
          dst[n * 16 + col] = f2bf(o_acc[mi][n][i] * inv);
      }
  }
}

// ---------------------------------------------------------------------------
// launch. ws layout unchanged.
// FULL2 tier: prep -> gemm128d(qkv, V->VbT transposed) -> attn128 -> gemm128d.
// ---------------------------------------------------------------------------
extern "C" void kernel_launch(void* const* d_in, const int* in_sizes, int n_in,
                              void* d_out, int out_size, void* d_ws, size_t ws_size,
                              hipStream_t stream) {
  const void* x      = d_in[0];
  const void* w_qkv  = d_in[1];
  const void* w_proj = d_in[2];

  int* flag = (int*)d_ws;
  unsigned short* wsb = (unsigned short*)((char*)d_ws + 1024);

  const size_t HS = (size_t)Bdim * Hdim * Tdim * Ddim;   // 8,388,608 elems
  const size_t FULL  = 1024 + 2 * (4 * HS + (size_t)3072 * 1024 + (size_t)1024 * 1024);
  const size_t FULL2 = FULL + 2 * HS;
  const size_t MONO  = 1024 + 2 * (4 * HS);

  dim3 blk(256);

  if (ws_size >= FULL) {
    unsigned short* Qb  = wsb;
    unsigned short* Kb  = Qb + HS;
    unsigned short* Vb  = Kb + HS;
    unsigned short* XY  = Vb + HS;            // X16 then Y2 (bf16 [B*T, C])
    unsigned short* WqT = XY + HS;
    unsigned short* WpT = WqT + (size_t)3072 * 1024;
    unsigned short* VbT = WpT + (size_t)1024 * 1024;
    const int M = Bdim * Tdim;                // 8192

    prep_kernel<<<dim3(5120), blk, 0, stream>>>(x, w_qkv, w_proj, XY, WqT, WpT, flag);

    if (ws_size >= FULL2) {
      // V written directly transposed into VbT by the GEMM epilogue
      gemm128d_kernel<<<dim3(M / 128, 3072 / 128), blk, 0, stream>>>(
          XY, WqT, nullptr, Qb, Kb, VbT, flag, M, 3072, Cdim, 1, 1);
      attn128_kernel<<<dim3(Bdim * Hdim * 8), blk, 0, stream>>>(Qb, Kb, VbT, XY);
    } else {
      gemm128d_kernel<<<dim3(M / 128, 3072 / 128), blk, 0, stream>>>(
          XY, WqT, nullptr, Qb, Kb, Vb, flag, M, 3072, Cdim, 1, 0);
      attn128_legacy_kernel<<<dim3(Bdim * Hdim * 8), blk, 0, stream>>>(Qb, Kb, Vb, nullptr, XY);
    }

    gemm128d_kernel<<<dim3(M / 128, Cdim / 128), blk, 0, stream>>>(
        XY, WpT, d_out, nullptr, nullptr, nullptr, flag, M, Cdim, Cdim, 0, 0);
  } else if (ws_size >= MONO) {
    // MONO: R3-proven per-batch flow (gemm64 converts A inline).
    detect_kernel<<<1, 64, 0, stream>>>((const unsigned int*)x, flag);
    const size_t HSb = (size_t)Hdim * Tdim * Ddim;
    unsigned short* Qb2 = wsb;
    unsigned short* Kb2 = Qb2 + HSb;
    unsigned short* Vb2 = Kb2 + HSb;
    unsigned short* Y2  = Vb2 + HSb;
    for (int b = 0; b < Bdim; b++) {
      gemm64_kernel<<<dim3(Tdim / BM, 3072 / BN), blk, 0, stream>>>(
          x, w_qkv, nullptr, Qb2, Kb2, Vb2, flag,
          Tdim, 3072, Cdim, 1, 2, 2, b * Tdim, 0);
      attn128_legacy_kernel<<<dim3(Hdim * 8), blk, 0, stream>>>(Qb2, Kb2, Vb2, nullptr, Y2);
      gemm64_kernel<<<dim3(Tdim / BM, Cdim / BN), blk, 0, stream>>>(
          Y2, w_proj, d_out, nullptr, nullptr, nullptr, flag,
          Tdim, Cdim, Cdim, 0, 1, 2, 0, b * Tdim);
    }
  } else {   // per-batch fallback (16 MiB + 1 KiB), R3-proven
    detect_kernel<<<1, 64, 0, stream>>>((const unsigned int*)x, flag);
    const size_t HSb = (size_t)Hdim * Tdim * Ddim;
    unsigned short* Qb = wsb;
    unsigned short* Kb = Qb + HSb;
    unsigned short* Vb = Kb + HSb;
    unsigned short* Y2 = Vb + HSb;

    for (int b = 0; b < Bdim; b++) {
      gemm64_kernel<<<dim3(Tdim / BM, 3072 / BN), blk, 0, stream>>>(
          x, w_qkv, nullptr, Qb, Kb, Vb, flag,
          Tdim, 3072, Cdim, 1, 2, 2, b * Tdim, 0);

      attn128_legacy_kernel<<<dim3(Hdim * 8), blk, 0, stream>>>(Qb, Kb, Vb, nullptr, Y2);

      gemm64_kernel<<<dim3(Tdim / BM, Cdim / BN), blk, 0, stream>>>(
          Y2, w_proj, d_out, nullptr, nullptr, nullptr, flag,
          Tdim, Cdim, Cdim, 0, 1, 2, 0, b * Tdim);
    }
  }
}

// Round 8
// 244.215 us; speedup vs baseline: 1.0329x; 1.0052x over previous
//
#include <hip/hip_runtime.h>
#include <hip/hip_bf16.h>

// Problem constants (reference: B,T,C = 4,2048,1024; H=16; D=64)
#define Bdim 4
#define Tdim 2048
#define Cdim 1024
#define Hdim 16
#define Ddim 64
// D^-0.5 * log2(e) = 0.125 * 1.4426950408889634, folded into Q at QKV-GEMM
// epilogue so the attn softmax can use exp2 directly.
#define SCALE_Q 0.18033688011112042f

using f32x4  = __attribute__((ext_vector_type(4))) float;
using short8 = __attribute__((ext_vector_type(8))) short;   // 8 bf16 in 4 VGPRs

union U8 { uint4 v; unsigned short s[8]; };

__device__ __forceinline__ unsigned short f2bf(float f) {  // RNE
  union { float f; unsigned int i; } x; x.f = f;
  unsigned int lsb = (x.i >> 16) & 1u;
  unsigned int r = x.i + 0x7fffu + lsb;
  return (unsigned short)(r >> 16);
}

// 2x f32 -> packed 2x bf16 (RNE). Lowers to v_cvt_pk_bf16_f32 on gfx950.
__device__ __forceinline__ unsigned int pk_bf16(float lo, float hi) {
  union { __hip_bfloat162 h; unsigned int u; } c;
  c.h = __float22bfloat162_rn(make_float2(lo, hi));
  return c.u;
}

__device__ __forceinline__ float fexp2(float x) {
#if __has_builtin(__builtin_amdgcn_exp2f)
  return __builtin_amdgcn_exp2f(x);
#else
  return exp2f(x);
#endif
}

// async global->LDS, 16B per lane. LDS dest is wave-uniform base + lane*16
// (m104/m108): dest layout must be lane-linear. Global source is per-lane,
// so swizzled LDS layouts are achieved by pre-swizzling the global address.
__device__ __forceinline__ void glds16(const unsigned short* g, unsigned short* l) {
  __builtin_amdgcn_global_load_lds(
      (const __attribute__((address_space(1))) void*)g,
      (__attribute__((address_space(3))) void*)l,
      16, 0, 0);
}

__device__ __forceinline__ int detect_fmt(const unsigned int* xw) {
  int cnt = 0;
  for (int i = 0; i < 64; i++) {
    unsigned int e = (xw[i] >> 7) & 0xFFu;
    if (e >= 100u && e <= 140u) cnt++;
  }
  return (cnt >= 40) ? 1 : 0;   // 1 = bf16, 0 = fp32
}

// ---------------------------------------------------------------------------
// detect (kept for MONO / per-batch tiers)
// ---------------------------------------------------------------------------
__global__ void detect_kernel(const unsigned int* __restrict__ x, int* __restrict__ flag) {
  if (threadIdx.x == 0) *flag = detect_fmt(x);
}

// ---------------------------------------------------------------------------
// prep (R8): one launch = detect + cvt_x + cvtT(w_qkv) + cvtT(w_proj).
// ---------------------------------------------------------------------------
__global__ __launch_bounds__(256) void prep_kernel(
    const void* __restrict__ x, const void* __restrict__ wq, const void* __restrict__ wp,
    unsigned short* __restrict__ X16, unsigned short* __restrict__ WqT,
    unsigned short* __restrict__ WpT, int* __restrict__ flag)
{
  __shared__ __align__(16) unsigned short Ts[64][72];
  __shared__ int sfmt;
  if (threadIdx.x == 0) {
    const int f = detect_fmt((const unsigned int*)x);
    sfmt = f;
    if (blockIdx.x == 0) *flag = f;
  }
  __syncthreads();
  const int fmt = sfmt;
  const unsigned bid = blockIdx.x;
  const int tid = threadIdx.x;

  if (bid < 4096u) {                     // ---- cvt_x
    const size_t i = (size_t)bid * 256 + tid;     // < 1,048,576 groups of 8
    if (fmt == 1) {
      *(uint4*)(X16 + i * 8) = *(const uint4*)((const unsigned short*)x + i * 8);
    } else {
      const float* s = (const float*)x + i * 8;
      float4 a = *(const float4*)(s);
      float4 b = *(const float4*)(s + 4);
      U8 o;
      o.s[0]=f2bf(a.x); o.s[1]=f2bf(a.y); o.s[2]=f2bf(a.z); o.s[3]=f2bf(a.w);
      o.s[4]=f2bf(b.x); o.s[5]=f2bf(b.y); o.s[6]=f2bf(b.z); o.s[7]=f2bf(b.w);
      *(uint4*)(X16 + i * 8) = o.v;
    }
    return;
  }

  // ---- cvtT tiles
  const void* W; unsigned short* WT; int N, K, n0, k0;
  if (bid < 4864u) {
    const int t = bid - 4096;
    W = wq; WT = WqT; N = 3072; K = 1024;
    n0 = (t % 48) * 64; k0 = (t / 48) * 64;
  } else {
    const int t = bid - 4864;
    W = wp; WT = WpT; N = 1024; K = 1024;
    n0 = (t & 15) * 64; k0 = (t >> 4) * 64;
  }
  const int r = tid >> 2, c0 = (tid & 3) * 16;

  if (fmt == 0) {
    const float* Wf = (const float*)W + (size_t)(k0 + r) * N + n0 + c0;
    #pragma unroll
    for (int j4 = 0; j4 < 4; j4++) {
      float4 v = *(const float4*)(Wf + j4 * 4);
      Ts[r][c0 + j4*4 + 0] = f2bf(v.x);
      Ts[r][c0 + j4*4 + 1] = f2bf(v.y);
      Ts[r][c0 + j4*4 + 2] = f2bf(v.z);
      Ts[r][c0 + j4*4 + 3] = f2bf(v.w);
    }
  } else {
    const unsigned short* Wh = (const unsigned short*)W + (size_t)(k0 + r) * N + n0 + c0;
    uint4 v0 = *(const uint4*)(Wh);
    uint4 v1 = *(const uint4*)(Wh + 8);
    *(uint4*)&Ts[r][c0] = v0;
    *(uint4*)&Ts[r][c0 + 8] = v1;
  }
  __syncthreads();

  U8 o0, o1;
  #pragma unroll
  for (int j = 0; j < 8; j++) { o0.s[j] = Ts[c0 + j][r]; o1.s[j] = Ts[c0 + 8 + j][r]; }
  unsigned short* dst = WT + (size_t)(n0 + r) * K + k0 + c0;
  *(uint4*)(dst)     = o0.v;
  *(uint4*)(dst + 8) = o1.v;
}

// ---------------------------------------------------------------------------
// gemm128d (R12-proven): 128x128 tile, prefetch pipeline with raw s_barrier +
// counted vmcnt(4). XOR LDS swizzle (conflicts = 0). Unchanged.
// ---------------------------------------------------------------------------
__global__ __launch_bounds__(256) void gemm128d_kernel(
    const unsigned short* __restrict__ A16,
    const unsigned short* __restrict__ BT16,
    void* __restrict__ Cout,
    unsigned short* __restrict__ Qb,
    unsigned short* __restrict__ Kb,
    unsigned short* __restrict__ Vb,     // V dest: [t][d] (vT=0) or [d][t] (vT=1)
    const int* __restrict__ flag,
    int M, int N, int K, int mode, int vT)
{
  __shared__ __align__(16) unsigned short As[2][128 * 32];
  __shared__ __align__(16) unsigned short Bs[2][128 * 32];

  const int fmt = *flag;
  const int tid  = threadIdx.x;
  const int wave = tid >> 6;
  const int lane = tid & 63;
  const int col  = lane & 15;
  const int quad = lane >> 4;
  const int m0 = blockIdx.x * 128;
  const int n0 = blockIdx.y * 128;
  const int wm = (wave >> 1) * 64;
  const int wn = (wave & 1) * 64;

  const int r4 = lane >> 2;                                   // row in 16-group
  const int schunk = ((lane & 3) ^ ((lane >> 3) & 3)) * 8;    // pre-swizzled src chunk
  const int rsw = (quad ^ ((col >> 1) & 3)) * 8;              // frag-read swizzle

  f32x4 acc[4][4];
  #pragma unroll
  for (int i = 0; i < 4; i++)
    #pragma unroll
    for (int j = 0; j < 4; j++) acc[i][j] = (f32x4){0.f, 0.f, 0.f, 0.f};

  const unsigned short* ApA = A16  + (size_t)(m0 + wave * 32 + r4) * K + schunk;
  const unsigned short* ApB = ApA + (size_t)16 * K;
  const unsigned short* BpA = BT16 + (size_t)(n0 + wave * 32 + r4) * K + schunk;
  const unsigned short* BpB = BpA + (size_t)16 * K;

#define STAGE(BUF, KS) do { \
    glds16(ApA + (KS) * 32, &As[BUF][wave * 32 * 32]);        \
    glds16(ApB + (KS) * 32, &As[BUF][(wave * 32 + 16) * 32]); \
    glds16(BpA + (KS) * 32, &Bs[BUF][wave * 32 * 32]);        \
    glds16(BpB + (KS) * 32, &Bs[BUF][(wave * 32 + 16) * 32]); \
  } while (0)

#define COMPUTE(BUF) do { \
    short8 afr[4], bfr[4]; \
    _Pragma("unroll") \
    for (int mi = 0; mi < 4; mi++) \
      afr[mi] = *(const short8*)&As[BUF][(wm + mi * 16 + col) * 32 + rsw]; \
    _Pragma("unroll") \
    for (int ni = 0; ni < 4; ni++) \
      bfr[ni] = *(const short8*)&Bs[BUF][(wn + ni * 16 + col) * 32 + rsw]; \
    _Pragma("unroll") \
    for (int mi = 0; mi < 4; mi++) \
      _Pragma("unroll") \
      for (int ni = 0; ni < 4; ni++) \
        acc[mi][ni] = __builtin_amdgcn_mfma_f32_16x16x32_bf16(afr[mi], bfr[ni], acc[mi][ni], 0, 0, 0); \
  } while (0)

  const int NK = K >> 5;          // 32-k tiles (K=1024 -> 32)
  STAGE(0, 0);
  for (int ks = 0; ks < NK - 1; ++ks) {
    STAGE((ks + 1) & 1, ks + 1);                       // prefetch next tile
    asm volatile("s_waitcnt vmcnt(4)" ::: "memory");   // drain CURRENT tile only
    __builtin_amdgcn_s_barrier();
    __builtin_amdgcn_sched_barrier(0);
    COMPUTE(ks & 1);
    __builtin_amdgcn_sched_barrier(0);
    __builtin_amdgcn_s_barrier();                      // readers done before re-stage
  }
  asm volatile("s_waitcnt vmcnt(0)" ::: "memory");     // last tile: drain all
  __builtin_amdgcn_s_barrier();
  __builtin_amdgcn_sched_barrier(0);
  COMPUTE((NK - 1) & 1);
#undef STAGE
#undef COMPUTE

  if (mode == 1) {       // QKV scatter, hoisted per-subtile
    const int bb = m0 >> 11;          // batch (block never straddles)
    const int tBase = (m0 & 2047) + wm;
    #pragma unroll
    for (int ni = 0; ni < 4; ni++) {
      const int n = n0 + wn + ni * 16 + col;
      const int which = n >> 10;      // N=3072: 0=q 1=k 2=v
      const int rem = n & 1023;
      const int h = rem >> 6;
      const int d = rem & 63;
      if (which == 2 && vT) {
        // transposed V: [h][d][t], t = tBase+mi*16+quad*4+i contiguous -> 8B packed
        unsigned short* base = Vb + (size_t)(bb * Hdim + h) * Tdim * Ddim
                                  + (size_t)d * Tdim + tBase;
        #pragma unroll
        for (int mi = 0; mi < 4; mi++) {
          const int t0 = mi * 16 + quad * 4;
          *(uint2*)(base + t0) = make_uint2(pk_bf16(acc[mi][ni][0], acc[mi][ni][1]),
                                            pk_bf16(acc[mi][ni][2], acc[mi][ni][3]));
        }
      } else {
        unsigned short* dstBase = (which == 0) ? Qb : (which == 1 ? Kb : Vb);
        const float scale = (which == 0) ? SCALE_Q : 1.f;
        dstBase += (size_t)(bb * Hdim + h) * Tdim * Ddim + d;
        #pragma unroll
        for (int mi = 0; mi < 4; mi++)
          #pragma unroll
          for (int i = 0; i < 4; i++) {
            const int t = tBase + mi * 16 + quad * 4 + i;
            dstBase[(size_t)t * Ddim] = f2bf(acc[mi][ni][i] * scale);
          }
      }
    }
  } else {
    #pragma unroll
    for (int mi = 0; mi < 4; mi++)
      #pragma unroll
      for (int ni = 0; ni < 4; ni++)
        #pragma unroll
        for (int i = 0; i < 4; i++) {
          const int m = m0 + wm + mi * 16 + quad * 4 + i;
          const int n = n0 + wn + ni * 16 + col;
          const float v = acc[mi][ni][i];
          if (fmt == 0) ((float*)Cout)[(size_t)m * N + n] = v;
          else ((unsigned short*)Cout)[(size_t)m * N + n] = f2bf(v);
        }
  }
}

// ---------------------------------------------------------------------------
// gemm64 (R3-proven) — small-ws per-batch fallback only.
// ---------------------------------------------------------------------------
#define BM 64
#define BN 64
#define BK 32
#define LDK 40

__global__ __launch_bounds__(256) void gemm64_kernel(
    const void* __restrict__ A,
    const void* __restrict__ Bw,
    void* __restrict__ Cout,
    unsigned short* __restrict__ Qb,
    unsigned short* __restrict__ Kb,
    unsigned short* __restrict__ Vb,
    const int* __restrict__ flag,
    int M, int N, int K, int mode, int aFmt, int outFmt, int aOff, int mOff)
{
  __shared__ __align__(16) unsigned short As[BM * LDK];
  __shared__ __align__(16) unsigned short Bs[BN * LDK];

  const int fmt = *flag;
  const int af  = (aFmt  == 2) ? fmt : aFmt;
  const int of  = (outFmt == 2) ? fmt : outFmt;

  const int tid  = threadIdx.x;
  const int wave = tid >> 6;
  const int lane = tid & 63;
  const int m0 = blockIdx.x * BM;
  const int n0 = blockIdx.y * BN;

  const int ar = tid >> 2;
  const int ak = (tid & 3) * 8;
  const int bk = tid >> 3;
  const int bn = (tid & 7) * 8;

  const int lr = lane & 15;
  const int lq = lane >> 4;

  f32x4 acc[4] = {{0,0,0,0},{0,0,0,0},{0,0,0,0},{0,0,0,0}};

  for (int k0 = 0; k0 < K; k0 += BK) {
    U8 a8;
    if (af == 1) {
      a8.v = *(const uint4*)((const unsigned short*)A + (size_t)(aOff + m0 + ar) * K + (k0 + ak));
    } else {
      const float* Af = (const float*)A + (size_t)(aOff + m0 + ar) * K + (k0 + ak);
      float4 x0 = *(const float4*)(Af);
      float4 x1 = *(const float4*)(Af + 4);
      a8.s[0] = f2bf(x0.x); a8.s[1] = f2bf(x0.y); a8.s[2] = f2bf(x0.z); a8.s[3] = f2bf(x0.w);
      a8.s[4] = f2bf(x1.x); a8.s[5] = f2bf(x1.y); a8.s[6] = f2bf(x1.z); a8.s[7] = f2bf(x1.w);
    }
    *(uint4*)(&As[ar * LDK + ak]) = a8.v;

    U8 b8;
    if (fmt == 1) {
      b8.v = *(const uint4*)((const unsigned short*)Bw + (size_t)(k0 + bk) * N + (n0 + bn));
    } else {
      const float* Bf = (const float*)Bw + (size_t)(k0 + bk) * N + (n0 + bn);
      float4 x0 = *(const float4*)(Bf);
      float4 x1 = *(const float4*)(Bf + 4);
      b8.s[0] = f2bf(x0.x); b8.s[1] = f2bf(x0.y); b8.s[2] = f2bf(x0.z); b8.s[3] = f2bf(x0.w);
      b8.s[4] = f2bf(x1.x); b8.s[5] = f2bf(x1.y); b8.s[6] = f2bf(x1.z); b8.s[7] = f2bf(x1.w);
    }
    #pragma unroll
    for (int i = 0; i < 8; i++) Bs[(bn + i) * LDK + bk] = b8.s[i];
    __syncthreads();

    short8 afrag = *(const short8*)(&As[(wave * 16 + lr) * LDK + lq * 8]);
    #pragma unroll
    for (int c = 0; c < 4; c++) {
      short8 bfrag = *(const short8*)(&Bs[(c * 16 + lr) * LDK + lq * 8]);
      acc[c] = __builtin_amdgcn_mfma_f32_16x16x32_bf16(afrag, bfrag, acc[c], 0, 0, 0);
    }
    __syncthreads();
  }

  #pragma unroll
  for (int c = 0; c < 4; c++) {
    #pragma unroll
    for (int i = 0; i < 4; i++) {
      const int m = m0 + wave * 16 + lq * 4 + i;
      const int n = n0 + c * 16 + lr;
      const float v = acc[c][i];
      if (mode == 0) {
        if (of == 0) ((float*)Cout)[(size_t)(mOff + m) * N + n] = v;
        else ((unsigned short*)Cout)[(size_t)(mOff + m) * N + n] = f2bf(v);
      } else {
        const int which = n >> 10;
        const int rem = n & 1023;
        const int h = rem >> 6;
        const int d = rem & 63;
        const int b = m >> 11;
        const int t = m & 2047;
        const size_t idx = ((size_t)(b * Hdim + h) * Tdim + t) * Ddim + d;
        if      (which == 0) Qb[idx] = f2bf(v * SCALE_Q);
        else if (which == 1) Kb[idx] = f2bf(v);
        else                 Vb[idx] = f2bf(v);
      }
    }
  }
}

// ---------------------------------------------------------------------------
// attn64 (R16): QBLK=64, pair (qt, 31-qt) per block -> uniform 33 kt/block,
// grid 1024 = 4 blocks/CU; LDS 40KB (2x8K K + 2x8K V + 4x1K P shorts) -> LDS
// allows exactly 4 blocks/CU. Occupancy cap 2 -> 4 waves/SIMD: attacks the
// R15-diagnosed dependency-latency bound (barrier removal was null; the
// serial QK->exp2->P->PV chain needs more waves to hide).
// Carried over proven: glds16 dbuf + vmcnt(4) counted drain (R12/R14),
// XOR-chunk LDS swizzles (R13), XCD locality blockIdx&63=bh (R14, FETCH
// 147->29MB), swapped QK^T / exp2 / ones-MFMA l / packed P (R10).
// Mask simplifies: only tile kt==nkt-1 is diagonal (uniform branch).
// ---------------------------------------------------------------------------
__global__ __launch_bounds__(256) void attn64_kernel(
    const unsigned short* __restrict__ Qb,
    const unsigned short* __restrict__ Kb,
    const unsigned short* __restrict__ VbT,   // [head][D][T], required
    unsigned short* __restrict__ Y)
{
  __shared__ __align__(16) unsigned short Ks[2][64 * 64];    // [key][d] swizzled
  __shared__ __align__(16) unsigned short Vt[2][64 * 64];    // [d][key] swizzled
  __shared__ __align__(16) unsigned short Pw[4][16 * 64];    // per-wave P [row][key] swizzled

  const int tid  = threadIdx.x;
  const int wave = tid >> 6;
  const int lane = tid & 63;
  const int col  = lane & 15;
  const int quad = lane >> 4;
  const int cx   = col & 7;
  const int ch0  = (quad ^ cx) * 8;    // physical shorts-offset of logical chunk 'quad'
  const int ch1  = ch0 ^ 32;           // logical chunk quad+4

  // staging lane geometry: one glds16 = 8 rows x 64 shorts; srow = row-in-call
  const int srow = lane >> 3;                       // 0..7
  const int sx   = ((lane & 7) ^ (srow & 7)) * 8;   // pre-swizzled source chunk

  // XCD-locality (R14-proven): blockIdx&63 = bh -> XCD = bh%8; a head's 16
  // blocks share one XCD L2.
  const int pair = blockIdx.x >> 6;    // 0..15
  const int bh   = blockIdx.x & 63;
  const size_t headOff = (size_t)bh * Tdim * Ddim;
  const int b = bh >> 4;
  const int h = bh & 15;

  const short8 onesf = {16256, 16256, 16256, 16256, 16256, 16256, 16256, 16256}; // bf16 1.0 x8

#define ASTAGE(BUF, KB) do { \
    const unsigned short* Ksrc = Kb + headOff + (size_t)((KB) + wave * 16 + srow) * Ddim + sx; \
    glds16(Ksrc,            &Ks[BUF][(wave * 16) * 64]);      \
    glds16(Ksrc + 8 * Ddim, &Ks[BUF][(wave * 16 + 8) * 64]);  \
    const unsigned short* Vsrc = VbT + headOff + (size_t)(wave * 16 + srow) * Tdim + (KB) + sx; \
    glds16(Vsrc,            &Vt[BUF][(wave * 16) * 64]);      \
    glds16(Vsrc + 8 * Tdim, &Vt[BUF][(wave * 16 + 8) * 64]);  \
  } while (0)

  #pragma unroll
  for (int half = 0; half < 2; half++) {
    const int qt = half ? (31 - pair) : pair;    // work (qt+1): pair+1 / 32-pair -> 33 total
    const int qb = qt * 64;
    const int nkt = qt + 1;
    const int rMin = qb + wave * 16;             // this wave's 16 q-rows

    short8 qf[2];
    {
      const unsigned short* Qr = Qb + headOff + (size_t)(rMin + col) * Ddim;
      qf[0] = *(const short8*)(Qr + quad * 8);
      qf[1] = *(const short8*)(Qr + 32 + quad * 8);
    }

    f32x4 o_acc[4];
    f32x4 l_acc = (f32x4){0.f, 0.f, 0.f, 0.f};
    #pragma unroll
    for (int n = 0; n < 4; n++) o_acc[n] = (f32x4){0.f, 0.f, 0.f, 0.f};

    ASTAGE(0, 0);
    for (int kt = 0; kt < nkt; kt++) {
      const int cur = kt & 1;
      if (kt + 1 < nkt) {
        ASTAGE(cur ^ 1, (kt + 1) * 64);                  // prefetch next tile
        asm volatile("s_waitcnt vmcnt(4)" ::: "memory"); // drain current tile only
      } else {
        asm volatile("s_waitcnt vmcnt(0)" ::: "memory"); // last tile: drain all
      }
      __builtin_amdgcn_s_barrier();
      __builtin_amdgcn_sched_barrier(0);

      // --- S^T = K @ Q^T : s_acc[c], register idx = key, lane col = qrow
      f32x4 s_acc[4];
      #pragma unroll
      for (int c = 0; c < 4; c++) {
        const unsigned short* Kl = &Ks[cur][(c * 16 + col) * 64];
        short8 kf0 = *(const short8*)(Kl + ch0);
        short8 kf1 = *(const short8*)(Kl + ch1);
        f32x4 z = {0.f, 0.f, 0.f, 0.f};
        z = __builtin_amdgcn_mfma_f32_16x16x32_bf16(kf0, qf[0], z, 0, 0, 0);
        s_acc[c] = __builtin_amdgcn_mfma_f32_16x16x32_bf16(kf1, qf[1], z, 0, 0, 0);
      }

      // causal mask: only last tile is diagonal (earlier tiles: all keys < qb)
      if (kt == nkt - 1) {
        #pragma unroll
        for (int c = 0; c < 4; c++)
          #pragma unroll
          for (int i = 0; i < 4; i++)
            if (qb + c * 16 + quad * 4 + i > rMin + col)
              s_acc[c][i] = -1e30f;
      }

      // --- softmax (exp2 domain, no clamp) + packed b64 P stores (swizzled)
      #pragma unroll
      for (int c = 0; c < 4; c++) {
        const float p0 = fexp2(s_acc[c][0]);
        const float p1 = fexp2(s_acc[c][1]);
        const float p2 = fexp2(s_acc[c][2]);
        const float p3 = fexp2(s_acc[c][3]);
        const unsigned int u0 = pk_bf16(p0, p1);
        const unsigned int u1 = pk_bf16(p2, p3);
        // logical 16B-chunk (2c + quad>>1), physical = logical ^ cx; 8B half = quad&1
        const int po = (((c * 2 + (quad >> 1)) ^ cx) * 8) + (quad & 1) * 4;
        *(uint2*)&Pw[wave][col * 64 + po] = make_uint2(u0, u1);
      }

      short8 pf0 = *(const short8*)(&Pw[wave][col * 64 + ch0]);
      short8 pf1 = *(const short8*)(&Pw[wave][col * 64 + ch1]);
      // row-sum via ones-MFMA: lands in o_acc-compatible C layout
      l_acc = __builtin_amdgcn_mfma_f32_16x16x32_bf16(pf0, onesf, l_acc, 0, 0, 0);
      l_acc = __builtin_amdgcn_mfma_f32_16x16x32_bf16(pf1, onesf, l_acc, 0, 0, 0);
      #pragma unroll
      for (int n = 0; n < 4; n++) {
        const unsigned short* Vl = &Vt[cur][(n * 16 + col) * 64];
        short8 vf0 = *(const short8*)(Vl + ch0);
        short8 vf1 = *(const short8*)(Vl + ch1);
        o_acc[n] = __builtin_amdgcn_mfma_f32_16x16x32_bf16(pf0, vf0, o_acc[n], 0, 0, 0);
        o_acc[n] = __builtin_amdgcn_mfma_f32_16x16x32_bf16(pf1, vf1, o_acc[n], 0, 0, 0);
      }

      __builtin_amdgcn_sched_barrier(0);
      __builtin_amdgcn_s_barrier();     // readers done before next ASTAGE overwrites
    }

    #pragma unroll
    for (int i = 0; i < 4; i++) {
      const float inv = 1.f / l_acc[i];
      const int qrow = rMin + quad * 4 + i;
      unsigned short* dst = Y + (size_t)(b * Tdim + qrow) * Cdim + h * Ddim;
      #pragma unroll
      for (int n = 0; n < 4; n++)
        dst[n * 16 + col] = f2bf(o_acc[n][i] * inv);
    }
  }
#undef ASTAGE
}

// ---------------------------------------------------------------------------
// attn128_legacy (R10-proven): used by fallback tiers (no VbT workspace).
// ---------------------------------------------------------------------------
__global__ __launch_bounds__(256) void attn128_legacy_kernel(
    const unsigned short* __restrict__ Qb,
    const unsigned short* __restrict__ Kb,
    const unsigned short* __restrict__ Vb,
    const unsigned short* __restrict__ VbT,   // [head][D][T] or nullptr
    unsigned short* __restrict__ Y)
{
  __shared__ __align__(16) unsigned short Ks[64 * 72];       // [key][d]
  __shared__ __align__(16) unsigned short Vt[64 * 72];       // [d][key]
  __shared__ __align__(16) unsigned short Pw[4][32 * 72];    // per-wave P [row][key]

  const int tid  = threadIdx.x;
  const int wave = tid >> 6;
  const int lane = tid & 63;
  const int col  = lane & 15;
  const int quad = lane >> 4;

  const int pair = blockIdx.x & 7;
  const int bh   = blockIdx.x >> 3;
  const size_t headOff = (size_t)bh * Tdim * Ddim;

  const int sr = tid >> 2;
  const int sc = (tid & 3) * 16;

  const int b = bh >> 4;
  const int h = bh & 15;

  const short8 onesf = {16256, 16256, 16256, 16256, 16256, 16256, 16256, 16256};

  #pragma unroll
  for (int half = 0; half < 2; half++) {
    const int qt = half ? (15 - pair) : pair;
    const int qb = qt * 128;
    const int nkt = (qb >> 6) + 2;
    const int rMin = qb + wave * 32;
    const int rMax = rMin + 31;

    short8 qf[2][2];
    #pragma unroll
    for (int mi = 0; mi < 2; mi++) {
      const unsigned short* Qr = Qb + headOff + (size_t)(rMin + mi * 16 + col) * Ddim;
      qf[mi][0] = *(const short8*)(Qr + quad * 8);
      qf[mi][1] = *(const short8*)(Qr + 32 + quad * 8);
    }

    f32x4 o_acc[2][4];
    f32x4 l_acc[2];
    #pragma unroll
    for (int mi = 0; mi < 2; mi++) {
      l_acc[mi] = (f32x4){0.f, 0.f, 0.f, 0.f};
      #pragma unroll
      for (int n = 0; n < 4; n++) o_acc[mi][n] = (f32x4){0.f, 0.f, 0.f, 0.f};
    }

    uint4 kr0, kr1, vr0, vr1;
    {
      const unsigned short* Kr = Kb + headOff + (size_t)sr * Ddim + sc;
      kr0 = *(const uint4*)(Kr);
      kr1 = *(const uint4*)(Kr + 8);
      if (VbT) {
        const unsigned short* Vr = VbT + headOff + (size_t)sr * Tdim + sc;
        vr0 = *(const uint4*)(Vr);
        vr1 = *(const uint4*)(Vr + 8);
      } else {
        const unsigned short* Vr = Vb + headOff + (size_t)sr * Ddim + sc;
        vr0 = *(const uint4*)(Vr);
        vr1 = *(const uint4*)(Vr + 8);
      }
    }

    for (int kt = 0; kt < nkt; kt++) {
      __syncthreads();
      *(uint4*)&Ks[sr * 72 + sc]     = kr0;
      *(uint4*)&Ks[sr * 72 + sc + 8] = kr1;
      if (VbT) {
        *(uint4*)&Vt[sr * 72 + sc]     = vr0;
        *(uint4*)&Vt[sr * 72 + sc + 8] = vr1;
      } else {
        U8 v0, v1; v0.v = vr0; v1.v = vr1;
        #pragma unroll
        for (int j = 0; j < 8; j++) {
          Vt[(sc + j) * 72 + sr]     = v0.s[j];
          Vt[(sc + 8 + j) * 72 + sr] = v1.s[j];
        }
      }
      __syncthreads();

      if (kt + 1 < nkt) {
        const int kb = (kt + 1) * 64;
        const unsigned short* Kr = Kb + headOff + (size_t)(kb + sr) * Ddim + sc;
        kr0 = *(const uint4*)(Kr);
        kr1 = *(const uint4*)(Kr + 8);
        if (VbT) {
          const unsigned short* Vr = VbT + headOff + (size_t)sr * Tdim + kb + sc;
          vr0 = *(const uint4*)(Vr);
          vr1 = *(const uint4*)(Vr + 8);
        } else {
          const unsigned short* Vr = Vb + headOff + (size_t)(kb + sr) * Ddim + sc;
          vr0 = *(const uint4*)(Vr);
          vr1 = *(const uint4*)(Vr + 8);
        }
      }

      const int ktb = kt * 64;
      if (ktb <= rMax) {
        f32x4 s_acc[4][2];
        #pragma unroll
        for (int c = 0; c < 4; c++) {
          const unsigned short* Kl = &Ks[(c * 16 + col) * 72];
          short8 kf0 = *(const short8*)(Kl + quad * 8);
          short8 kf1 = *(const short8*)(Kl + 32 + quad * 8);
          #pragma unroll
          for (int mi = 0; mi < 2; mi++) {
            f32x4 z = {0.f, 0.f, 0.f, 0.f};
            z = __builtin_amdgcn_mfma_f32_16x16x32_bf16(kf0, qf[mi][0], z, 0, 0, 0);
            s_acc[c][mi] = __builtin_amdgcn_mfma_f32_16x16x32_bf16(kf1, qf[mi][1], z, 0, 0, 0);
          }
        }

        if (ktb + 63 > rMin) {
          #pragma unroll
          for (int c = 0; c < 4; c++)
            #pragma unroll
            for (int mi = 0; mi < 2; mi++)
              #pragma unroll
              for (int i = 0; i < 4; i++)
                if (ktb + c * 16 + quad * 4 + i > rMin + mi * 16 + col)
                  s_acc[c][mi][i] = -1e30f;
        }

        #pragma unroll
        for (int mi = 0; mi < 2; mi++)
          #pragma unroll
          for (int c = 0; c < 4; c++) {
            const float p0 = fexp2(fminf(s_acc[c][mi][0], 80.f));
            const float p1 = fexp2(fminf(s_acc[c][mi][1], 80.f));
            const float p2 = fexp2(fminf(s_acc[c][mi][2], 80.f));
            const float p3 = fexp2(fminf(s_acc[c][mi][3], 80.f));
            const unsigned int u0 = pk_bf16(p0, p1);
            const unsigned int u1 = pk_bf16(p2, p3);
            uint2* dst = (uint2*)&Pw[wave][(mi * 16 + col) * 72 + c * 16 + quad * 4];
            *dst = make_uint2(u0, u1);
          }

        short8 pf[2][2];
        #pragma unroll
        for (int mi = 0; mi < 2; mi++) {
          pf[mi][0] = *(const short8*)(&Pw[wave][(mi * 16 + col) * 72 + quad * 8]);
          pf[mi][1] = *(const short8*)(&Pw[wave][(mi * 16 + col) * 72 + 32 + quad * 8]);
          l_acc[mi] = __builtin_amdgcn_mfma_f32_16x16x32_bf16(pf[mi][0], onesf, l_acc[mi], 0, 0, 0);
          l_acc[mi] = __builtin_amdgcn_mfma_f32_16x16x32_bf16(pf[mi][1], onesf, l_acc[mi], 0, 0, 0);
        }
        #pragma unroll
        for (int n = 0; n < 4; n++) {
          const unsigned short* Vl = &Vt[(n * 16 + col) * 72];
          short8 vf0 = *(const short8*)(Vl + quad * 8);
          short8 vf1 = *(const short8*)(Vl + 32 + quad * 8);
          #pragma unroll
          for (int mi = 0; mi < 2; mi++) {
            o_acc[mi][n] = __builtin_amdgcn_mfma_f32_16x16x32_bf16(pf[mi][0], vf0, o_acc[mi][n], 0, 0, 0);
            o_acc[mi][n] = __builtin_amdgcn_mfma_f32_16x16x32_bf16(pf[mi][1], vf1, o_acc[mi][n], 0, 0, 0);
          }
        }
      }
    }

    #pragma unroll
    for (int mi = 0; mi < 2; mi++)
      #pragma unroll
      for (int i = 0; i < 4; i++) {
        const float inv = 1.f / l_acc[mi][i];
        const int qrow = rMin + mi * 16 + quad * 4 + i;
        unsigned short* dst = Y + (size_t)(b * Tdim + qrow) * Cdim + h * Ddim;
        #pragma unroll
        for (int n = 0; n < 4; n++)
          dst[n * 16 + col] = f2bf(o_acc[mi][n][i] * inv);
      }
  }
}

// ---------------------------------------------------------------------------
// launch. ws layout unchanged.
// FULL2 tier: prep -> gemm128d(qkv, V->VbT transposed) -> attn64 -> gemm128d.
// ---------------------------------------------------------------------------
extern "C" void kernel_launch(void* const* d_in, const int* in_sizes, int n_in,
                              void* d_out, int out_size, void* d_ws, size_t ws_size,
                              hipStream_t stream) {
  const void* x      = d_in[0];
  const void* w_qkv  = d_in[1];
  const void* w_proj = d_in[2];

  int* flag = (int*)d_ws;
  unsigned short* wsb = (unsigned short*)((char*)d_ws + 1024);

  const size_t HS = (size_t)Bdim * Hdim * Tdim * Ddim;   // 8,388,608 elems
  const size_t FULL  = 1024 + 2 * (4 * HS + (size_t)3072 * 1024 + (size_t)1024 * 1024);
  const size_t FULL2 = FULL + 2 * HS;
  const size_t MONO  = 1024 + 2 * (4 * HS);

  dim3 blk(256);

  if (ws_size >= FULL) {
    unsigned short* Qb  = wsb;
    unsigned short* Kb  = Qb + HS;
    unsigned short* Vb  = Kb + HS;
    unsigned short* XY  = Vb + HS;            // X16 then Y2 (bf16 [B*T, C])
    unsigned short* WqT = XY + HS;
    unsigned short* WpT = WqT + (size_t)3072 * 1024;
    unsigned short* VbT = WpT + (size_t)1024 * 1024;
    const int M = Bdim * Tdim;                // 8192

    prep_kernel<<<dim3(5120), blk, 0, stream>>>(x, w_qkv, w_proj, XY, WqT, WpT, flag);

    if (ws_size >= FULL2) {
      // V written directly transposed into VbT by the GEMM epilogue
      gemm128d_kernel<<<dim3(M / 128, 3072 / 128), blk, 0, stream>>>(
          XY, WqT, nullptr, Qb, Kb, VbT, flag, M, 3072, Cdim, 1, 1);
      attn64_kernel<<<dim3(16 * 64), blk, 0, stream>>>(Qb, Kb, VbT, XY);
    } else {
      gemm128d_kernel<<<dim3(M / 128, 3072 / 128), blk, 0, stream>>>(
          XY, WqT, nullptr, Qb, Kb, Vb, flag, M, 3072, Cdim, 1, 0);
      attn128_legacy_kernel<<<dim3(Bdim * Hdim * 8), blk, 0, stream>>>(Qb, Kb, Vb, nullptr, XY);
    }

    gemm128d_kernel<<<dim3(M / 128, Cdim / 128), blk, 0, stream>>>(
        XY, WpT, d_out, nullptr, nullptr, nullptr, flag, M, Cdim, Cdim, 0, 0);
  } else if (ws_size >= MONO) {
    // MONO: R3-proven per-batch flow (gemm64 converts A inline).
    detect_kernel<<<1, 64, 0, stream>>>((const unsigned int*)x, flag);
    const size_t HSb = (size_t)Hdim * Tdim * Ddim;
    unsigned short* Qb2 = wsb;
    unsigned short* Kb2 = Qb2 + HSb;
    unsigned short* Vb2 = Kb2 + HSb;
    unsigned short* Y2  = Vb2 + HSb;
    for (int b = 0; b < Bdim; b++) {
      gemm64_kernel<<<dim3(Tdim / BM, 3072 / BN), blk, 0, stream>>>(
          x, w_qkv, nullptr, Qb2, Kb2, Vb2, flag,
          Tdim, 3072, Cdim, 1, 2, 2, b * Tdim, 0);
      attn128_legacy_kernel<<<dim3(Hdim * 8), blk, 0, stream>>>(Qb2, Kb2, Vb2, nullptr, Y2);
      gemm64_kernel<<<dim3(Tdim / BM, Cdim / BN), blk, 0, stream>>>(
          Y2, w_proj, d_out, nullptr, nullptr, nullptr, flag,
          Tdim, Cdim, Cdim, 0, 1, 2, 0, b * Tdim);
    }
  } else {   // per-batch fallback (16 MiB + 1 KiB), R3-proven
    detect_kernel<<<1, 64, 0, stream>>>((const unsigned int*)x, flag);
    const size_t HSb = (size_t)Hdim * Tdim * Ddim;
    unsigned short* Qb = wsb;
    unsigned short* Kb = Qb + HSb;
    unsigned short* Vb = Kb + HSb;
    unsigned short* Y2 = Vb + HSb;

    for (int b = 0; b < Bdim; b++) {
      gemm64_kernel<<<dim3(Tdim / BM, 3072 / BN), blk, 0, stream>>>(
          x, w_qkv, nullptr, Qb, Kb, Vb, flag,
          Tdim, 3072, Cdim, 1, 2, 2, b * Tdim, 0);

      attn128_legacy_kernel<<<dim3(Hdim * 8), blk, 0, stream>>>(Qb, Kb, Vb, nullptr, Y2);

      gemm64_kernel<<<dim3(Tdim / BM, Cdim / BN), blk, 0, stream>>>(
          Y2, w_proj, d_out, nullptr, nullptr, nullptr, flag,
          Tdim, Cdim, Cdim, 0, 1, 2, 0, b * Tdim);
    }
  }
}

// Round 9
// 237.159 us; speedup vs baseline: 1.0636x; 1.0298x over previous
//
#include <hip/hip_runtime.h>
#include <hip/hip_bf16.h>

// Problem constants (reference: B,T,C = 4,2048,1024; H=16; D=64)
#define Bdim 4
#define Tdim 2048
#define Cdim 1024
#define Hdim 16
#define Ddim 64
// D^-0.5 * log2(e) = 0.125 * 1.4426950408889634, folded into Q at QKV-GEMM
// epilogue so the attn softmax can use exp2 directly.
#define SCALE_Q 0.18033688011112042f

using f32x4  = __attribute__((ext_vector_type(4))) float;
using short8 = __attribute__((ext_vector_type(8))) short;   // 8 bf16 in 4 VGPRs

union U8 { uint4 v; unsigned short s[8]; };

__device__ __forceinline__ unsigned short f2bf(float f) {  // RNE
  union { float f; unsigned int i; } x; x.f = f;
  unsigned int lsb = (x.i >> 16) & 1u;
  unsigned int r = x.i + 0x7fffu + lsb;
  return (unsigned short)(r >> 16);
}

// 2x f32 -> packed 2x bf16 (RNE). Lowers to v_cvt_pk_bf16_f32 on gfx950.
__device__ __forceinline__ unsigned int pk_bf16(float lo, float hi) {
  union { __hip_bfloat162 h; unsigned int u; } c;
  c.h = __float22bfloat162_rn(make_float2(lo, hi));
  return c.u;
}

__device__ __forceinline__ float fexp2(float x) {
#if __has_builtin(__builtin_amdgcn_exp2f)
  return __builtin_amdgcn_exp2f(x);
#else
  return exp2f(x);
#endif
}

// async global->LDS, 16B per lane. LDS dest is wave-uniform base + lane*16
// (m104/m108): dest layout must be lane-linear. Global source is per-lane,
// so swizzled LDS layouts are achieved by pre-swizzling the global address.
__device__ __forceinline__ void glds16(const unsigned short* g, unsigned short* l) {
  __builtin_amdgcn_global_load_lds(
      (const __attribute__((address_space(1))) void*)g,
      (__attribute__((address_space(3))) void*)l,
      16, 0, 0);
}

__device__ __forceinline__ int detect_fmt(const unsigned int* xw) {
  int cnt = 0;
  for (int i = 0; i < 64; i++) {
    unsigned int e = (xw[i] >> 7) & 0xFFu;
    if (e >= 100u && e <= 140u) cnt++;
  }
  return (cnt >= 40) ? 1 : 0;   // 1 = bf16, 0 = fp32
}

// ---------------------------------------------------------------------------
// detect (kept for MONO / per-batch tiers)
// ---------------------------------------------------------------------------
__global__ void detect_kernel(const unsigned int* __restrict__ x, int* __restrict__ flag) {
  if (threadIdx.x == 0) *flag = detect_fmt(x);
}

// ---------------------------------------------------------------------------
// prep (R8): one launch = detect + cvt_x + cvtT(w_qkv) + cvtT(w_proj).
// ---------------------------------------------------------------------------
__global__ __launch_bounds__(256) void prep_kernel(
    const void* __restrict__ x, const void* __restrict__ wq, const void* __restrict__ wp,
    unsigned short* __restrict__ X16, unsigned short* __restrict__ WqT,
    unsigned short* __restrict__ WpT, int* __restrict__ flag)
{
  __shared__ __align__(16) unsigned short Ts[64][72];
  __shared__ int sfmt;
  if (threadIdx.x == 0) {
    const int f = detect_fmt((const unsigned int*)x);
    sfmt = f;
    if (blockIdx.x == 0) *flag = f;
  }
  __syncthreads();
  const int fmt = sfmt;
  const unsigned bid = blockIdx.x;
  const int tid = threadIdx.x;

  if (bid < 4096u) {                     // ---- cvt_x
    const size_t i = (size_t)bid * 256 + tid;     // < 1,048,576 groups of 8
    if (fmt == 1) {
      *(uint4*)(X16 + i * 8) = *(const uint4*)((const unsigned short*)x + i * 8);
    } else {
      const float* s = (const float*)x + i * 8;
      float4 a = *(const float4*)(s);
      float4 b = *(const float4*)(s + 4);
      U8 o;
      o.s[0]=f2bf(a.x); o.s[1]=f2bf(a.y); o.s[2]=f2bf(a.z); o.s[3]=f2bf(a.w);
      o.s[4]=f2bf(b.x); o.s[5]=f2bf(b.y); o.s[6]=f2bf(b.z); o.s[7]=f2bf(b.w);
      *(uint4*)(X16 + i * 8) = o.v;
    }
    return;
  }

  // ---- cvtT tiles
  const void* W; unsigned short* WT; int N, K, n0, k0;
  if (bid < 4864u) {
    const int t = bid - 4096;
    W = wq; WT = WqT; N = 3072; K = 1024;
    n0 = (t % 48) * 64; k0 = (t / 48) * 64;
  } else {
    const int t = bid - 4864;
    W = wp; WT = WpT; N = 1024; K = 1024;
    n0 = (t & 15) * 64; k0 = (t >> 4) * 64;
  }
  const int r = tid >> 2, c0 = (tid & 3) * 16;

  if (fmt == 0) {
    const float* Wf = (const float*)W + (size_t)(k0 + r) * N + n0 + c0;
    #pragma unroll
    for (int j4 = 0; j4 < 4; j4++) {
      float4 v = *(const float4*)(Wf + j4 * 4);
      Ts[r][c0 + j4*4 + 0] = f2bf(v.x);
      Ts[r][c0 + j4*4 + 1] = f2bf(v.y);
      Ts[r][c0 + j4*4 + 2] = f2bf(v.z);
      Ts[r][c0 + j4*4 + 3] = f2bf(v.w);
    }
  } else {
    const unsigned short* Wh = (const unsigned short*)W + (size_t)(k0 + r) * N + n0 + c0;
    uint4 v0 = *(const uint4*)(Wh);
    uint4 v1 = *(const uint4*)(Wh + 8);
    *(uint4*)&Ts[r][c0] = v0;
    *(uint4*)&Ts[r][c0 + 8] = v1;
  }
  __syncthreads();

  U8 o0, o1;
  #pragma unroll
  for (int j = 0; j < 8; j++) { o0.s[j] = Ts[c0 + j][r]; o1.s[j] = Ts[c0 + 8 + j][r]; }
  unsigned short* dst = WT + (size_t)(n0 + r) * K + k0 + c0;
  *(uint4*)(dst)     = o0.v;
  *(uint4*)(dst + 8) = o1.v;
}

// ---------------------------------------------------------------------------
// gemm128e (R17): gemm128d with BK=64 per barrier-pair (half the barriers /
// waits; double the prefetch window). Per 64-k tile: STAGE next tile
// (8 glds16/thread) -> vmcnt(8) [drains exactly the CURRENT tile's 8 loads,
// keeps the 8 prefetch loads in flight] -> s_barrier -> 32 MFMA (2 ks-subtiles
// x 16) -> s_barrier. LDS [buf][ks][128x32] keeps the proven zero-conflict
// 64B-row XOR swizzle for both glds16 staging (pre-swizzled global source)
// and frag ds_read_b128. LDS 64KB -> 2 blocks/CU (matches measured ~2.2
// effective occupancy, so no loss). Ledger identical in form to gemm128d:
// STAGE(n+1)->buf ob, last reader iter n-1's COMPUTE behind its trailing
// barrier; counts exact (8 glds16/tile, nothing else in flight); last iter
// vmcnt(0).
// ---------------------------------------------------------------------------
__global__ __launch_bounds__(256) void gemm128e_kernel(
    const unsigned short* __restrict__ A16,
    const unsigned short* __restrict__ BT16,
    void* __restrict__ Cout,
    unsigned short* __restrict__ Qb,
    unsigned short* __restrict__ Kb,
    unsigned short* __restrict__ Vb,     // V dest: [t][d] (vT=0) or [d][t] (vT=1)
    const int* __restrict__ flag,
    int M, int N, int K, int mode, int vT)
{
  __shared__ __align__(16) unsigned short As[2][2][128 * 32];  // [buf][ks][r*32+c]
  __shared__ __align__(16) unsigned short Bs[2][2][128 * 32];

  const int fmt = *flag;
  const int tid  = threadIdx.x;
  const int wave = tid >> 6;
  const int lane = tid & 63;
  const int col  = lane & 15;
  const int quad = lane >> 4;
  const int m0 = blockIdx.x * 128;
  const int n0 = blockIdx.y * 128;
  const int wm = (wave >> 1) * 64;
  const int wn = (wave & 1) * 64;

  // block-wide staging geometry: one glds16 call = 256 thr x 16B = 64 rows x 64B
  const int srow = tid >> 2;                                  // 0..63
  const int sgc  = ((tid & 3) ^ ((tid >> 3) & 3)) * 8;        // pre-swizzled src chunk
  const int wvoff = (tid >> 6) * 512;                         // wave-uniform dest offset
  const int rsw = (quad ^ ((col >> 1) & 3)) * 8;              // frag-read swizzle

  f32x4 acc[4][4];
  #pragma unroll
  for (int i = 0; i < 4; i++)
    #pragma unroll
    for (int j = 0; j < 4; j++) acc[i][j] = (f32x4){0.f, 0.f, 0.f, 0.f};

  const unsigned short* aB  = A16  + (size_t)(m0 + srow) * K + sgc;
  const unsigned short* aB2 = aB + (size_t)64 * K;
  const unsigned short* bB  = BT16 + (size_t)(n0 + srow) * K + sgc;
  const unsigned short* bB2 = bB + (size_t)64 * K;

#define STAGE(BUF, KT) do { \
    glds16(aB  + (KT) * 64,      &As[BUF][0][wvoff]);        \
    glds16(aB  + (KT) * 64 + 32, &As[BUF][1][wvoff]);        \
    glds16(aB2 + (KT) * 64,      &As[BUF][0][2048 + wvoff]); \
    glds16(aB2 + (KT) * 64 + 32, &As[BUF][1][2048 + wvoff]); \
    glds16(bB  + (KT) * 64,      &Bs[BUF][0][wvoff]);        \
    glds16(bB  + (KT) * 64 + 32, &Bs[BUF][1][wvoff]);        \
    glds16(bB2 + (KT) * 64,      &Bs[BUF][0][2048 + wvoff]); \
    glds16(bB2 + (KT) * 64 + 32, &Bs[BUF][1][2048 + wvoff]); \
  } while (0)

#define COMPUTE(BUF) do { \
    short8 afr[4][2], bfr[4][2]; \
    _Pragma("unroll") \
    for (int mi = 0; mi < 4; mi++) { \
      afr[mi][0] = *(const short8*)&As[BUF][0][(wm + mi * 16 + col) * 32 + rsw]; \
      afr[mi][1] = *(const short8*)&As[BUF][1][(wm + mi * 16 + col) * 32 + rsw]; \
    } \
    _Pragma("unroll") \
    for (int ni = 0; ni < 4; ni++) { \
      bfr[ni][0] = *(const short8*)&Bs[BUF][0][(wn + ni * 16 + col) * 32 + rsw]; \
      bfr[ni][1] = *(const short8*)&Bs[BUF][1][(wn + ni * 16 + col) * 32 + rsw]; \
    } \
    _Pragma("unroll") \
    for (int mi = 0; mi < 4; mi++) \
      _Pragma("unroll") \
      for (int ni = 0; ni < 4; ni++) { \
        acc[mi][ni] = __builtin_amdgcn_mfma_f32_16x16x32_bf16(afr[mi][0], bfr[ni][0], acc[mi][ni], 0, 0, 0); \
        acc[mi][ni] = __builtin_amdgcn_mfma_f32_16x16x32_bf16(afr[mi][1], bfr[ni][1], acc[mi][ni], 0, 0, 0); \
      } \
  } while (0)

  const int NK = K >> 6;          // 64-k tiles (K=1024 -> 16)
  STAGE(0, 0);
  for (int n = 0; n < NK - 1; ++n) {
    STAGE((n + 1) & 1, n + 1);                         // prefetch next tile
    asm volatile("s_waitcnt vmcnt(8)" ::: "memory");   // drain CURRENT tile only
    __builtin_amdgcn_s_barrier();
    __builtin_amdgcn_sched_barrier(0);
    COMPUTE(n & 1);
    __builtin_amdgcn_sched_barrier(0);
    __builtin_amdgcn_s_barrier();                      // readers done before re-stage
  }
  asm volatile("s_waitcnt vmcnt(0)" ::: "memory");     // last tile: drain all
  __builtin_amdgcn_s_barrier();
  __builtin_amdgcn_sched_barrier(0);
  COMPUTE((NK - 1) & 1);
#undef STAGE
#undef COMPUTE

  if (mode == 1) {       // QKV scatter, hoisted per-subtile
    const int bb = m0 >> 11;          // batch (block never straddles)
    const int tBase = (m0 & 2047) + wm;
    #pragma unroll
    for (int ni = 0; ni < 4; ni++) {
      const int n = n0 + wn + ni * 16 + col;
      const int which = n >> 10;      // N=3072: 0=q 1=k 2=v
      const int rem = n & 1023;
      const int h = rem >> 6;
      const int d = rem & 63;
      if (which == 2 && vT) {
        // transposed V: [h][d][t], t = tBase+mi*16+quad*4+i contiguous -> 8B packed
        unsigned short* base = Vb + (size_t)(bb * Hdim + h) * Tdim * Ddim
                                  + (size_t)d * Tdim + tBase;
        #pragma unroll
        for (int mi = 0; mi < 4; mi++) {
          const int t0 = mi * 16 + quad * 4;
          *(uint2*)(base + t0) = make_uint2(pk_bf16(acc[mi][ni][0], acc[mi][ni][1]),
                                            pk_bf16(acc[mi][ni][2], acc[mi][ni][3]));
        }
      } else {
        unsigned short* dstBase = (which == 0) ? Qb : (which == 1 ? Kb : Vb);
        const float scale = (which == 0) ? SCALE_Q : 1.f;
        dstBase += (size_t)(bb * Hdim + h) * Tdim * Ddim + d;
        #pragma unroll
        for (int mi = 0; mi < 4; mi++)
          #pragma unroll
          for (int i = 0; i < 4; i++) {
            const int t = tBase + mi * 16 + quad * 4 + i;
            dstBase[(size_t)t * Ddim] = f2bf(acc[mi][ni][i] * scale);
          }
      }
    }
  } else {
    #pragma unroll
    for (int mi = 0; mi < 4; mi++)
      #pragma unroll
      for (int ni = 0; ni < 4; ni++)
        #pragma unroll
        for (int i = 0; i < 4; i++) {
          const int m = m0 + wm + mi * 16 + quad * 4 + i;
          const int n = n0 + wn + ni * 16 + col;
          const float v = acc[mi][ni][i];
          if (fmt == 0) ((float*)Cout)[(size_t)m * N + n] = v;
          else ((unsigned short*)Cout)[(size_t)m * N + n] = f2bf(v);
        }
  }
}

// ---------------------------------------------------------------------------
// gemm64 (R3-proven) — small-ws per-batch fallback only.
// ---------------------------------------------------------------------------
#define BM 64
#define BN 64
#define BK 32
#define LDK 40

__global__ __launch_bounds__(256) void gemm64_kernel(
    const void* __restrict__ A,
    const void* __restrict__ Bw,
    void* __restrict__ Cout,
    unsigned short* __restrict__ Qb,
    unsigned short* __restrict__ Kb,
    unsigned short* __restrict__ Vb,
    const int* __restrict__ flag,
    int M, int N, int K, int mode, int aFmt, int outFmt, int aOff, int mOff)
{
  __shared__ __align__(16) unsigned short As[BM * LDK];
  __shared__ __align__(16) unsigned short Bs[BN * LDK];

  const int fmt = *flag;
  const int af  = (aFmt  == 2) ? fmt : aFmt;
  const int of  = (outFmt == 2) ? fmt : outFmt;

  const int tid  = threadIdx.x;
  const int wave = tid >> 6;
  const int lane = tid & 63;
  const int m0 = blockIdx.x * BM;
  const int n0 = blockIdx.y * BN;

  const int ar = tid >> 2;
  const int ak = (tid & 3) * 8;
  const int bk = tid >> 3;
  const int bn = (tid & 7) * 8;

  const int lr = lane & 15;
  const int lq = lane >> 4;

  f32x4 acc[4] = {{0,0,0,0},{0,0,0,0},{0,0,0,0},{0,0,0,0}};

  for (int k0 = 0; k0 < K; k0 += BK) {
    U8 a8;
    if (af == 1) {
      a8.v = *(const uint4*)((const unsigned short*)A + (size_t)(aOff + m0 + ar) * K + (k0 + ak));
    } else {
      const float* Af = (const float*)A + (size_t)(aOff + m0 + ar) * K + (k0 + ak);
      float4 x0 = *(const float4*)(Af);
      float4 x1 = *(const float4*)(Af + 4);
      a8.s[0] = f2bf(x0.x); a8.s[1] = f2bf(x0.y); a8.s[2] = f2bf(x0.z); a8.s[3] = f2bf(x0.w);
      a8.s[4] = f2bf(x1.x); a8.s[5] = f2bf(x1.y); a8.s[6] = f2bf(x1.z); a8.s[7] = f2bf(x1.w);
    }
    *(uint4*)(&As[ar * LDK + ak]) = a8.v;

    U8 b8;
    if (fmt == 1) {
      b8.v = *(const uint4*)((const unsigned short*)Bw + (size_t)(k0 + bk) * N + (n0 + bn));
    } else {
      const float* Bf = (const float*)Bw + (size_t)(k0 + bk) * N + (n0 + bn);
      float4 x0 = *(const float4*)(Bf);
      float4 x1 = *(const float4*)(Bf + 4);
      b8.s[0] = f2bf(x0.x); b8.s[1] = f2bf(x0.y); b8.s[2] = f2bf(x0.z); b8.s[3] = f2bf(x0.w);
      b8.s[4] = f2bf(x1.x); b8.s[5] = f2bf(x1.y); b8.s[6] = f2bf(x1.z); b8.s[7] = f2bf(x1.w);
    }
    #pragma unroll
    for (int i = 0; i < 8; i++) Bs[(bn + i) * LDK + bk] = b8.s[i];
    __syncthreads();

    short8 afrag = *(const short8*)(&As[(wave * 16 + lr) * LDK + lq * 8]);
    #pragma unroll
    for (int c = 0; c < 4; c++) {
      short8 bfrag = *(const short8*)(&Bs[(c * 16 + lr) * LDK + lq * 8]);
      acc[c] = __builtin_amdgcn_mfma_f32_16x16x32_bf16(afrag, bfrag, acc[c], 0, 0, 0);
    }
    __syncthreads();
  }

  #pragma unroll
  for (int c = 0; c < 4; c++) {
    #pragma unroll
    for (int i = 0; i < 4; i++) {
      const int m = m0 + wave * 16 + lq * 4 + i;
      const int n = n0 + c * 16 + lr;
      const float v = acc[c][i];
      if (mode == 0) {
        if (of == 0) ((float*)Cout)[(size_t)(mOff + m) * N + n] = v;
        else ((unsigned short*)Cout)[(size_t)(mOff + m) * N + n] = f2bf(v);
      } else {
        const int which = n >> 10;
        const int rem = n & 1023;
        const int h = rem >> 6;
        const int d = rem & 63;
        const int b = m >> 11;
        const int t = m & 2047;
        const size_t idx = ((size_t)(b * Hdim + h) * Tdim + t) * Ddim + d;
        if      (which == 0) Qb[idx] = f2bf(v * SCALE_Q);
        else if (which == 1) Kb[idx] = f2bf(v);
        else                 Vb[idx] = f2bf(v);
      }
    }
  }
}

// ---------------------------------------------------------------------------
// attn64 (R16-proven): QBLK=64, pair (qt, 31-qt) per block -> uniform 33
// kt/block, grid 1024 = 4 blocks/CU; LDS 40KB. Unchanged.
// ---------------------------------------------------------------------------
__global__ __launch_bounds__(256) void attn64_kernel(
    const unsigned short* __restrict__ Qb,
    const unsigned short* __restrict__ Kb,
    const unsigned short* __restrict__ VbT,   // [head][D][T], required
    unsigned short* __restrict__ Y)
{
  __shared__ __align__(16) unsigned short Ks[2][64 * 64];    // [key][d] swizzled
  __shared__ __align__(16) unsigned short Vt[2][64 * 64];    // [d][key] swizzled
  __shared__ __align__(16) unsigned short Pw[4][16 * 64];    // per-wave P [row][key] swizzled

  const int tid  = threadIdx.x;
  const int wave = tid >> 6;
  const int lane = tid & 63;
  const int col  = lane & 15;
  const int quad = lane >> 4;
  const int cx   = col & 7;
  const int ch0  = (quad ^ cx) * 8;    // physical shorts-offset of logical chunk 'quad'
  const int ch1  = ch0 ^ 32;           // logical chunk quad+4

  // staging lane geometry: one glds16 = 8 rows x 64 shorts; srow = row-in-call
  const int srow = lane >> 3;                       // 0..7
  const int sx   = ((lane & 7) ^ (srow & 7)) * 8;   // pre-swizzled source chunk

  // XCD-locality (R14-proven): blockIdx&63 = bh -> XCD = bh%8; a head's 16
  // blocks share one XCD L2.
  const int pair = blockIdx.x >> 6;    // 0..15
  const int bh   = blockIdx.x & 63;
  const size_t headOff = (size_t)bh * Tdim * Ddim;
  const int b = bh >> 4;
  const int h = bh & 15;

  const short8 onesf = {16256, 16256, 16256, 16256, 16256, 16256, 16256, 16256}; // bf16 1.0 x8

#define ASTAGE(BUF, KB) do { \
    const unsigned short* Ksrc = Kb + headOff + (size_t)((KB) + wave * 16 + srow) * Ddim + sx; \
    glds16(Ksrc,            &Ks[BUF][(wave * 16) * 64]);      \
    glds16(Ksrc + 8 * Ddim, &Ks[BUF][(wave * 16 + 8) * 64]);  \
    const unsigned short* Vsrc = VbT + headOff + (size_t)(wave * 16 + srow) * Tdim + (KB) + sx; \
    glds16(Vsrc,            &Vt[BUF][(wave * 16) * 64]);      \
    glds16(Vsrc + 8 * Tdim, &Vt[BUF][(wave * 16 + 8) * 64]);  \
  } while (0)

  #pragma unroll
  for (int half = 0; half < 2; half++) {
    const int qt = half ? (31 - pair) : pair;    // work (qt+1): pair+1 / 32-pair -> 33 total
    const int qb = qt * 64;
    const int nkt = qt + 1;
    const int rMin = qb + wave * 16;             // this wave's 16 q-rows

    short8 qf[2];
    {
      const unsigned short* Qr = Qb + headOff + (size_t)(rMin + col) * Ddim;
      qf[0] = *(const short8*)(Qr + quad * 8);
      qf[1] = *(const short8*)(Qr + 32 + quad * 8);
    }

    f32x4 o_acc[4];
    f32x4 l_acc = (f32x4){0.f, 0.f, 0.f, 0.f};
    #pragma unroll
    for (int n = 0; n < 4; n++) o_acc[n] = (f32x4){0.f, 0.f, 0.f, 0.f};

    ASTAGE(0, 0);
    for (int kt = 0; kt < nkt; kt++) {
      const int cur = kt & 1;
      if (kt + 1 < nkt) {
        ASTAGE(cur ^ 1, (kt + 1) * 64);                  // prefetch next tile
        asm volatile("s_waitcnt vmcnt(4)" ::: "memory"); // drain current tile only
      } else {
        asm volatile("s_waitcnt vmcnt(0)" ::: "memory"); // last tile: drain all
      }
      __builtin_amdgcn_s_barrier();
      __builtin_amdgcn_sched_barrier(0);

      // --- S^T = K @ Q^T : s_acc[c], register idx = key, lane col = qrow
      f32x4 s_acc[4];
      #pragma unroll
      for (int c = 0; c < 4; c++) {
        const unsigned short* Kl = &Ks[cur][(c * 16 + col) * 64];
        short8 kf0 = *(const short8*)(Kl + ch0);
        short8 kf1 = *(const short8*)(Kl + ch1);
        f32x4 z = {0.f, 0.f, 0.f, 0.f};
        z = __builtin_amdgcn_mfma_f32_16x16x32_bf16(kf0, qf[0], z, 0, 0, 0);
        s_acc[c] = __builtin_amdgcn_mfma_f32_16x16x32_bf16(kf1, qf[1], z, 0, 0, 0);
      }

      // causal mask: only last tile is diagonal (earlier tiles: all keys < qb)
      if (kt == nkt - 1) {
        #pragma unroll
        for (int c = 0; c < 4; c++)
          #pragma unroll
          for (int i = 0; i < 4; i++)
            if (qb + c * 16 + quad * 4 + i > rMin + col)
              s_acc[c][i] = -1e30f;
      }

      // --- softmax (exp2 domain, no clamp) + packed b64 P stores (swizzled)
      #pragma unroll
      for (int c = 0; c < 4; c++) {
        const float p0 = fexp2(s_acc[c][0]);
        const float p1 = fexp2(s_acc[c][1]);
        const float p2 = fexp2(s_acc[c][2]);
        const float p3 = fexp2(s_acc[c][3]);
        const unsigned int u0 = pk_bf16(p0, p1);
        const unsigned int u1 = pk_bf16(p2, p3);
        // logical 16B-chunk (2c + quad>>1), physical = logical ^ cx; 8B half = quad&1
        const int po = (((c * 2 + (quad >> 1)) ^ cx) * 8) + (quad & 1) * 4;
        *(uint2*)&Pw[wave][col * 64 + po] = make_uint2(u0, u1);
      }

      short8 pf0 = *(const short8*)(&Pw[wave][col * 64 + ch0]);
      short8 pf1 = *(const short8*)(&Pw[wave][col * 64 + ch1]);
      // row-sum via ones-MFMA: lands in o_acc-compatible C layout
      l_acc = __builtin_amdgcn_mfma_f32_16x16x32_bf16(pf0, onesf, l_acc, 0, 0, 0);
      l_acc = __builtin_amdgcn_mfma_f32_16x16x32_bf16(pf1, onesf, l_acc, 0, 0, 0);
      #pragma unroll
      for (int n = 0; n < 4; n++) {
        const unsigned short* Vl = &Vt[cur][(n * 16 + col) * 64];
        short8 vf0 = *(const short8*)(Vl + ch0);
        short8 vf1 = *(const short8*)(Vl + ch1);
        o_acc[n] = __builtin_amdgcn_mfma_f32_16x16x32_bf16(pf0, vf0, o_acc[n], 0, 0, 0);
        o_acc[n] = __builtin_amdgcn_mfma_f32_16x16x32_bf16(pf1, vf1, o_acc[n], 0, 0, 0);
      }

      __builtin_amdgcn_sched_barrier(0);
      __builtin_amdgcn_s_barrier();     // readers done before next ASTAGE overwrites
    }

    #pragma unroll
    for (int i = 0; i < 4; i++) {
      const float inv = 1.f / l_acc[i];
      const int qrow = rMin + quad * 4 + i;
      unsigned short* dst = Y + (size_t)(b * Tdim + qrow) * Cdim + h * Ddim;
      #pragma unroll
      for (int n = 0; n < 4; n++)
        dst[n * 16 + col] = f2bf(o_acc[n][i] * inv);
    }
  }
#undef ASTAGE
}

// ---------------------------------------------------------------------------
// attn128_legacy (R10-proven): used by fallback tiers (no VbT workspace).
// ---------------------------------------------------------------------------
__global__ __launch_bounds__(256) void attn128_legacy_kernel(
    const unsigned short* __restrict__ Qb,
    const unsigned short* __restrict__ Kb,
    const unsigned short* __restrict__ Vb,
    const unsigned short* __restrict__ VbT,   // [head][D][T] or nullptr
    unsigned short* __restrict__ Y)
{
  __shared__ __align__(16) unsigned short Ks[64 * 72];       // [key][d]
  __shared__ __align__(16) unsigned short Vt[64 * 72];       // [d][key]
  __shared__ __align__(16) unsigned short Pw[4][32 * 72];    // per-wave P [row][key]

  const int tid  = threadIdx.x;
  const int wave = tid >> 6;
  const int lane = tid & 63;
  const int col  = lane & 15;
  const int quad = lane >> 4;

  const int pair = blockIdx.x & 7;
  const int bh   = blockIdx.x >> 3;
  const size_t headOff = (size_t)bh * Tdim * Ddim;

  const int sr = tid >> 2;
  const int sc = (tid & 3) * 16;

  const int b = bh >> 4;
  const int h = bh & 15;

  const short8 onesf = {16256, 16256, 16256, 16256, 16256, 16256, 16256, 16256};

  #pragma unroll
  for (int half = 0; half < 2; half++) {
    const int qt = half ? (15 - pair) : pair;
    const int qb = qt * 128;
    const int nkt = (qb >> 6) + 2;
    const int rMin = qb + wave * 32;
    const int rMax = rMin + 31;

    short8 qf[2][2];
    #pragma unroll
    for (int mi = 0; mi < 2; mi++) {
      const unsigned short* Qr = Qb + headOff + (size_t)(rMin + mi * 16 + col) * Ddim;
      qf[mi][0] = *(const short8*)(Qr + quad * 8);
      qf[mi][1] = *(const short8*)(Qr + 32 + quad * 8);
    }

    f32x4 o_acc[2][4];
    f32x4 l_acc[2];
    #pragma unroll
    for (int mi = 0; mi < 2; mi++) {
      l_acc[mi] = (f32x4){0.f, 0.f, 0.f, 0.f};
      #pragma unroll
      for (int n = 0; n < 4; n++) o_acc[mi][n] = (f32x4){0.f, 0.f, 0.f, 0.f};
    }

    uint4 kr0, kr1, vr0, vr1;
    {
      const unsigned short* Kr = Kb + headOff + (size_t)sr * Ddim + sc;
      kr0 = *(const uint4*)(Kr);
      kr1 = *(const uint4*)(Kr + 8);
      if (VbT) {
        const unsigned short* Vr = VbT + headOff + (size_t)sr * Tdim + sc;
        vr0 = *(const uint4*)(Vr);
        vr1 = *(const uint4*)(Vr + 8);
      } else {
        const unsigned short* Vr = Vb + headOff + (size_t)sr * Ddim + sc;
        vr0 = *(const uint4*)(Vr);
        vr1 = *(const uint4*)(Vr + 8);
      }
    }

    for (int kt = 0; kt < nkt; kt++) {
      __syncthreads();
      *(uint4*)&Ks[sr * 72 + sc]     = kr0;
      *(uint4*)&Ks[sr * 72 + sc + 8] = kr1;
      if (VbT) {
        *(uint4*)&Vt[sr * 72 + sc]     = vr0;
        *(uint4*)&Vt[sr * 72 + sc + 8] = vr1;
      } else {
        U8 v0, v1; v0.v = vr0; v1.v = vr1;
        #pragma unroll
        for (int j = 0; j < 8; j++) {
          Vt[(sc + j) * 72 + sr]     = v0.s[j];
          Vt[(sc + 8 + j) * 72 + sr] = v1.s[j];
        }
      }
      __syncthreads();

      if (kt + 1 < nkt) {
        const int kb = (kt + 1) * 64;
        const unsigned short* Kr = Kb + headOff + (size_t)(kb + sr) * Ddim + sc;
        kr0 = *(const uint4*)(Kr);
        kr1 = *(const uint4*)(Kr + 8);
        if (VbT) {
          const unsigned short* Vr = VbT + headOff + (size_t)sr * Tdim + kb + sc;
          vr0 = *(const uint4*)(Vr);
          vr1 = *(const uint4*)(Vr + 8);
        } else {
          const unsigned short* Vr = Vb + headOff + (size_t)(kb + sr) * Ddim + sc;
          vr0 = *(const uint4*)(Vr);
          vr1 = *(const uint4*)(Vr + 8);
        }
      }

      const int ktb = kt * 64;
      if (ktb <= rMax) {
        f32x4 s_acc[4][2];
        #pragma unroll
        for (int c = 0; c < 4; c++) {
          const unsigned short* Kl = &Ks[(c * 16 + col) * 72];
          short8 kf0 = *(const short8*)(Kl + quad * 8);
          short8 kf1 = *(const short8*)(Kl + 32 + quad * 8);
          #pragma unroll
          for (int mi = 0; mi < 2; mi++) {
            f32x4 z = {0.f, 0.f, 0.f, 0.f};
            z = __builtin_amdgcn_mfma_f32_16x16x32_bf16(kf0, qf[mi][0], z, 0, 0, 0);
            s_acc[c][mi] = __builtin_amdgcn_mfma_f32_16x16x32_bf16(kf1, qf[mi][1], z, 0, 0, 0);
          }
        }

        if (ktb + 63 > rMin) {
          #pragma unroll
          for (int c = 0; c < 4; c++)
            #pragma unroll
            for (int mi = 0; mi < 2; mi++)
              #pragma unroll
              for (int i = 0; i < 4; i++)
                if (ktb + c * 16 + quad * 4 + i > rMin + mi * 16 + col)
                  s_acc[c][mi][i] = -1e30f;
        }

        #pragma unroll
        for (int mi = 0; mi < 2; mi++)
          #pragma unroll
          for (int c = 0; c < 4; c++) {
            const float p0 = fexp2(fminf(s_acc[c][mi][0], 80.f));
            const float p1 = fexp2(fminf(s_acc[c][mi][1], 80.f));
            const float p2 = fexp2(fminf(s_acc[c][mi][2], 80.f));
            const float p3 = fexp2(fminf(s_acc[c][mi][3], 80.f));
            const unsigned int u0 = pk_bf16(p0, p1);
            const unsigned int u1 = pk_bf16(p2, p3);
            uint2* dst = (uint2*)&Pw[wave][(mi * 16 + col) * 72 + c * 16 + quad * 4];
            *dst = make_uint2(u0, u1);
          }

        short8 pf[2][2];
        #pragma unroll
        for (int mi = 0; mi < 2; mi++) {
          pf[mi][0] = *(const short8*)(&Pw[wave][(mi * 16 + col) * 72 + quad * 8]);
          pf[mi][1] = *(const short8*)(&Pw[wave][(mi * 16 + col) * 72 + 32 + quad * 8]);
          l_acc[mi] = __builtin_amdgcn_mfma_f32_16x16x32_bf16(pf[mi][0], onesf, l_acc[mi], 0, 0, 0);
          l_acc[mi] = __builtin_amdgcn_mfma_f32_16x16x32_bf16(pf[mi][1], onesf, l_acc[mi], 0, 0, 0);
        }
        #pragma unroll
        for (int n = 0; n < 4; n++) {
          const unsigned short* Vl = &Vt[(n * 16 + col) * 72];
          short8 vf0 = *(const short8*)(Vl + quad * 8);
          short8 vf1 = *(const short8*)(Vl + 32 + quad * 8);
          #pragma unroll
          for (int mi = 0; mi < 2; mi++) {
            o_acc[mi][n] = __builtin_amdgcn_mfma_f32_16x16x32_bf16(pf[mi][0], vf0, o_acc[mi][n], 0, 0, 0);
            o_acc[mi][n] = __builtin_amdgcn_mfma_f32_16x16x32_bf16(pf[mi][1], vf1, o_acc[mi][n], 0, 0, 0);
          }
        }
      }
    }

    #pragma unroll
    for (int mi = 0; mi < 2; mi++)
      #pragma unroll
      for (int i = 0; i < 4; i++) {
        const float inv = 1.f / l_acc[mi][i];
        const int qrow = rMin + mi * 16 + quad * 4 + i;
        unsigned short* dst = Y + (size_t)(b * Tdim + qrow) * Cdim + h * Ddim;
        #pragma unroll
        for (int n = 0; n < 4; n++)
          dst[n * 16 + col] = f2bf(o_acc[mi][n][i] * inv);
      }
  }
}

// ---------------------------------------------------------------------------
// launch. ws layout unchanged.
// FULL2 tier: prep -> gemm128e(qkv, V->VbT transposed) -> attn64 -> gemm128e.
// ---------------------------------------------------------------------------
extern "C" void kernel_launch(void* const* d_in, const int* in_sizes, int n_in,
                              void* d_out, int out_size, void* d_ws, size_t ws_size,
                              hipStream_t stream) {
  const void* x      = d_in[0];
  const void* w_qkv  = d_in[1];
  const void* w_proj = d_in[2];

  int* flag = (int*)d_ws;
  unsigned short* wsb = (unsigned short*)((char*)d_ws + 1024);

  const size_t HS = (size_t)Bdim * Hdim * Tdim * Ddim;   // 8,388,608 elems
  const size_t FULL  = 1024 + 2 * (4 * HS + (size_t)3072 * 1024 + (size_t)1024 * 1024);
  const size_t FULL2 = FULL + 2 * HS;
  const size_t MONO  = 1024 + 2 * (4 * HS);

  dim3 blk(256);

  if (ws_size >= FULL) {
    unsigned short* Qb  = wsb;
    unsigned short* Kb  = Qb + HS;
    unsigned short* Vb  = Kb + HS;
    unsigned short* XY  = Vb + HS;            // X16 then Y2 (bf16 [B*T, C])
    unsigned short* WqT = XY + HS;
    unsigned short* WpT = WqT + (size_t)3072 * 1024;
    unsigned short* VbT = WpT + (size_t)1024 * 1024;
    const int M = Bdim * Tdim;                // 8192

    prep_kernel<<<dim3(5120), blk, 0, stream>>>(x, w_qkv, w_proj, XY, WqT, WpT, flag);

    if (ws_size >= FULL2) {
      // V written directly transposed into VbT by the GEMM epilogue
      gemm128e_kernel<<<dim3(M / 128, 3072 / 128), blk, 0, stream>>>(
          XY, WqT, nullptr, Qb, Kb, VbT, flag, M, 3072, Cdim, 1, 1);
      attn64_kernel<<<dim3(16 * 64), blk, 0, stream>>>(Qb, Kb, VbT, XY);
    } else {
      gemm128e_kernel<<<dim3(M / 128, 3072 / 128), blk, 0, stream>>>(
          XY, WqT, nullptr, Qb, Kb, Vb, flag, M, 3072, Cdim, 1, 0);
      attn128_legacy_kernel<<<dim3(Bdim * Hdim * 8), blk, 0, stream>>>(Qb, Kb, Vb, nullptr, XY);
    }

    gemm128e_kernel<<<dim3(M / 128, Cdim / 128), blk, 0, stream>>>(
        XY, WpT, d_out, nullptr, nullptr, nullptr, flag, M, Cdim, Cdim, 0, 0);
  } else if (ws_size >= MONO) {
    // MONO: R3-proven per-batch flow (gemm64 converts A inline).
    detect_kernel<<<1, 64, 0, stream>>>((const unsigned int*)x, flag);
    const size_t HSb = (size_t)Hdim * Tdim * Ddim;
    unsigned short* Qb2 = wsb;
    unsigned short* Kb2 = Qb2 + HSb;
    unsigned short* Vb2 = Kb2 + HSb;
    unsigned short* Y2  = Vb2 + HSb;
    for (int b = 0; b < Bdim; b++) {
      gemm64_kernel<<<dim3(Tdim / BM, 3072 / BN), blk, 0, stream>>>(
          x, w_qkv, nullptr, Qb2, Kb2, Vb2, flag,
          Tdim, 3072, Cdim, 1, 2, 2, b * Tdim, 0);
      attn128_legacy_kernel<<<dim3(Hdim * 8), blk, 0, stream>>>(Qb2, Kb2, Vb2, nullptr, Y2);
      gemm64_kernel<<<dim3(Tdim / BM, Cdim / BN), blk, 0, stream>>>(
          Y2, w_proj, d_out, nullptr, nullptr, nullptr, flag,
          Tdim, Cdim, Cdim, 0, 1, 2, 0, b * Tdim);
    }
  } else {   // per-batch fallback (16 MiB + 1 KiB), R3-proven
    detect_kernel<<<1, 64, 0, stream>>>((const unsigned int*)x, flag);
    const size_t HSb = (size_t)Hdim * Tdim * Ddim;
    unsigned short* Qb = wsb;
    unsigned short* Kb = Qb + HSb;
    unsigned short* Vb = Kb + HSb;
    unsigned short* Y2 = Vb + HSb;

    for (int b = 0; b < Bdim; b++) {
      gemm64_kernel<<<dim3(Tdim / BM, 3072 / BN), blk, 0, stream>>>(
          x, w_qkv, nullptr, Qb, Kb, Vb, flag,
          Tdim, 3072, Cdim, 1, 2, 2, b * Tdim, 0);

      attn128_legacy_kernel<<<dim3(Hdim * 8), blk, 0, stream>>>(Qb, Kb, Vb, nullptr, Y2);

      gemm64_kernel<<<dim3(Tdim / BM, Cdim / BN), blk, 0, stream>>>(
          Y2, w_proj, d_out, nullptr, nullptr, nullptr, flag,
          Tdim, Cdim, Cdim, 0, 1, 2, 0, b * Tdim);
    }
  }
}